// Round 8
// baseline (13129.437 us; speedup 1.0000x reference)
//
#include <hip/hip_runtime.h>

#define B   32
#define T   64
#define D   512
#define H   512
#define H2  1024
#define G4  4096
#define V   2048
#define DEC_IN 2560

__device__ __forceinline__ float sigm(float x) { return 1.f / (1.f + expf(-x)); }

__device__ __forceinline__ unsigned fenc(float f) {
  unsigned u = __float_as_uint(f);
  return (u & 0x80000000u) ? ~u : (u | 0x80000000u);
}

// ---- store-based parallel grid barrier (R6-proven) ----
__device__ __forceinline__ void pbar(unsigned* slots, unsigned* flag, int myid, int nblk) {
  __syncthreads();
  if (threadIdx.x == 0)
    __hip_atomic_store(slots + myid, 1u, __ATOMIC_RELEASE, __HIP_MEMORY_SCOPE_AGENT);
  if (myid == 0) {
    for (int s = threadIdx.x; s < nblk; s += 256) {
      while (!__hip_atomic_load(slots + s, __ATOMIC_RELAXED, __HIP_MEMORY_SCOPE_AGENT))
        __builtin_amdgcn_s_sleep(1);
    }
    __syncthreads();
    if (threadIdx.x == 0)
      __hip_atomic_store(flag, 1u, __ATOMIC_RELEASE, __HIP_MEMORY_SCOPE_AGENT);
  }
  if (threadIdx.x == 0) {
    while (!__hip_atomic_load(flag, __ATOMIC_RELAXED, __HIP_MEMORY_SCOPE_AGENT))
      __builtin_amdgcn_s_sleep(1);
    (void)__hip_atomic_load(flag, __ATOMIC_ACQUIRE, __HIP_MEMORY_SCOPE_AGENT);
  }
  __syncthreads();
}

// ---------------- generic fp32 GEMM ----------------
__global__ __launch_bounds__(256) void gemm_nt(
    const float* __restrict__ A, int lda,
    const float* __restrict__ W, int ldw,
    float* __restrict__ C, int ldc,
    const float* __restrict__ bias0, const float* __restrict__ bias1,
    int K)
{
  __shared__ float As[16][132];
  __shared__ float Ws[16][68];
  const int tid = threadIdx.x;
  const int nb = blockIdx.x * 64;
  const int mb = blockIdx.y * 128;
  const int tx = tid & 15;
  const int ty = tid >> 4;
  float acc[8][4] = {};

  const int am = tid >> 1, ak = (tid & 1) * 8;
  const int wn = tid >> 2, wk = (tid & 3) * 4;
  const float* aptr = A + (size_t)(mb + am) * lda + ak;
  const float* wptr = W + (size_t)(nb + wn) * ldw + wk;

  for (int k0 = 0; k0 < K; k0 += 16) {
    float4 u = *(const float4*)(aptr + k0);
    float4 v = *(const float4*)(aptr + k0 + 4);
    float4 w = *(const float4*)(wptr + k0);
    As[ak+0][am] = u.x; As[ak+1][am] = u.y; As[ak+2][am] = u.z; As[ak+3][am] = u.w;
    As[ak+4][am] = v.x; As[ak+5][am] = v.y; As[ak+6][am] = v.z; As[ak+7][am] = v.w;
    Ws[wk+0][wn] = w.x; Ws[wk+1][wn] = w.y; Ws[wk+2][wn] = w.z; Ws[wk+3][wn] = w.w;
    __syncthreads();
    #pragma unroll
    for (int k = 0; k < 16; ++k) {
      float4 a0 = *(const float4*)&As[k][ty*8];
      float4 a1 = *(const float4*)&As[k][ty*8+4];
      float4 wv = *(const float4*)&Ws[k][tx*4];
      float av[8] = {a0.x,a0.y,a0.z,a0.w,a1.x,a1.y,a1.z,a1.w};
      #pragma unroll
      for (int i = 0; i < 8; ++i) {
        acc[i][0] += av[i]*wv.x; acc[i][1] += av[i]*wv.y;
        acc[i][2] += av[i]*wv.z; acc[i][3] += av[i]*wv.w;
      }
    }
    __syncthreads();
  }
  float b4[4];
  #pragma unroll
  for (int j = 0; j < 4; ++j) {
    float bv = 0.f;
    if (bias0) bv += bias0[nb + tx*4 + j];
    if (bias1) bv += bias1[nb + tx*4 + j];
    b4[j] = bv;
  }
  #pragma unroll
  for (int i = 0; i < 8; ++i) {
    float4 o;
    o.x = acc[i][0] + b4[0]; o.y = acc[i][1] + b4[1];
    o.z = acc[i][2] + b4[2]; o.w = acc[i][3] + b4[3];
    *(float4*)&C[(size_t)(mb + ty*8 + i) * ldc + nb + tx*4] = o;
  }
}

// ---------------- prologue attention (32 blocks, one-time) ----------------
__device__ void attend_t(int b, const float* __restrict__ hvec, float* __restrict__ ctxdst,
                         const float* __restrict__ outbuf, const float* __restrict__ projo,
                         const int* __restrict__ mask, float* scratch, int tid)
{
  float* scp = scratch;        // 256
  float* scv = scratch + 256;  // 64
  const int tq = tid >> 2, dq = tid & 3;
  const float4* hv = (const float4*)(hvec + dq*256);
  const float4* pv = (const float4*)(projo + (size_t)(b*T + tq)*H2 + dq*256);
  float p = 0.f;
  #pragma unroll 8
  for (int k4 = 0; k4 < 64; ++k4) {
    float4 a = hv[k4], q = pv[k4];
    p += a.x*q.x + a.y*q.y + a.z*q.z + a.w*q.w;
  }
  scp[tid] = p;
  __syncthreads();
  if (tid < 64) {
    float v = scp[tid*4] + scp[tid*4+1] + scp[tid*4+2] + scp[tid*4+3];
    float mx = v;
    #pragma unroll
    for (int d = 32; d; d >>= 1) mx = fmaxf(mx, __shfl_xor(mx, d, 64));
    float e = expf(v - mx);
    float sm = e;
    #pragma unroll
    for (int d = 32; d; d >>= 1) sm += __shfl_xor(sm, d, 64);
    scv[tid] = e * (1.f / sm) * (float)mask[b*T + tid];
  }
  __syncthreads();
  float a0 = 0, a1 = 0, a2 = 0, a3 = 0;
  #pragma unroll 8
  for (int tt = 0; tt < 64; ++tt) {
    float pp = scv[tt];
    float4 o4 = *(const float4*)(outbuf + (size_t)(b*T + tt)*H2 + tid*4);
    a0 += pp*o4.x; a1 += pp*o4.y; a2 += pp*o4.z; a3 += pp*o4.w;
  }
  int k0 = tid*4;
  ctxdst[(k0+0)*32 + b] = a0;
  ctxdst[(k0+1)*32 + b] = a1;
  ctxdst[(k0+2)*32 + b] = a2;
  ctxdst[(k0+3)*32 + b] = a3;
}

// ---------------- persistent encoder (unchanged from R6/R7) ----------
__global__ __launch_bounds__(256, 1) void encoder_persistent(
    const float* __restrict__ xg_f, const float* __restrict__ xg_b,
    const float* __restrict__ Whh_f, const float* __restrict__ Whh_b,
    const int* __restrict__ mask,
    float* __restrict__ hencT,    // [dir][2][512][32]
    float* __restrict__ outbuf,
    unsigned* __restrict__ eslots, unsigned* __restrict__ eflags)
{
  __shared__ float S_lds[2][128*36];
  __shared__ float pacc[2048];
  __shared__ float g_lds[512];
  const int blk = blockIdx.x, tid = threadIdx.x;
  const int lane = tid & 63, wv = tid >> 6;
  const int dir = blk >> 7, nd = blk & 127;
  const int hibase = nd * 4;
  const int jj = tid & 7, kk = tid >> 3;
  const float* xg  = dir ? xg_b : xg_f;
  const float* Whh = dir ? Whh_b : Whh_f;
  float* hbase = hencT + dir * 32768;

  float wge[2][16];
  #pragma unroll
  for (int p = 0; p < 2; ++p) {
    int jl = jj*2 + p;
    int j = (jl>>2)*512 + hibase + (jl&3);
    #pragma unroll
    for (int sc = 0; sc < 4; ++sc)
      #pragma unroll
      for (int i = 0; i < 4; ++i)
        wge[p][sc*4+i] = Whh[(size_t)j*512 + sc*128 + i*32 + kk];
  }
  float c_reg = 0.f;
  const int kr = tid >> 1, bh = (tid & 1) * 16;

  for (int tt = 0; tt < 64; ++tt) {
    const int t = dir ? (63 - tt) : tt;
    const float* hc = hbase + (tt & 1) * 16384;
    float* hn = hbase + ((tt + 1) & 1) * 16384;

    float a0[32], a1[32];
    #pragma unroll
    for (int q = 0; q < 32; ++q) { a0[q] = 0.f; a1[q] = 0.f; }

    float4 rr0, rr1, rr2, rr3;
    {
      const float4* p = (const float4*)(hc + kr*32 + bh);
      rr0 = p[0]; rr1 = p[1]; rr2 = p[2]; rr3 = p[3];
      float* d = &S_lds[0][kr*36 + bh];
      *(float4*)d = rr0; *(float4*)(d+4) = rr1; *(float4*)(d+8) = rr2; *(float4*)(d+12) = rr3;
    }
    __syncthreads();
    #pragma unroll
    for (int sc = 0; sc < 4; ++sc) {
      if (sc < 3) {
        const float4* p = (const float4*)(hc + (sc+1)*4096 + kr*32 + bh);
        rr0 = p[0]; rr1 = p[1]; rr2 = p[2]; rr3 = p[3];
      }
      const float* Sb = &S_lds[sc & 1][0];
      #pragma unroll
      for (int i = 0; i < 4; ++i) {
        const float* sp = Sb + (i*32 + kk)*36;
        float w0 = wge[0][sc*4+i], w1 = wge[1][sc*4+i];
        #pragma unroll
        for (int q = 0; q < 8; ++q) {
          float4 s4 = *(const float4*)(sp + q*4);
          a0[q*4+0] += w0*s4.x; a0[q*4+1] += w0*s4.y; a0[q*4+2] += w0*s4.z; a0[q*4+3] += w0*s4.w;
          a1[q*4+0] += w1*s4.x; a1[q*4+1] += w1*s4.y; a1[q*4+2] += w1*s4.z; a1[q*4+3] += w1*s4.w;
        }
      }
      if (sc < 3) {
        float* d = &S_lds[(sc+1) & 1][kr*36 + bh];
        *(float4*)d = rr0; *(float4*)(d+4) = rr1; *(float4*)(d+8) = rr2; *(float4*)(d+12) = rr3;
      }
      __syncthreads();
    }
    #pragma unroll
    for (int dd = 8; dd <= 32; dd <<= 1) {
      #pragma unroll
      for (int q = 0; q < 32; ++q) {
        a0[q] += __shfl_down(a0[q], dd, 64);
        a1[q] += __shfl_down(a1[q], dd, 64);
      }
    }
    if (lane < 8) {
      float* pw = &pacc[wv*512 + lane*64];
      #pragma unroll
      for (int q = 0; q < 32; ++q) { pw[q] = a0[q]; pw[32+q] = a1[q]; }
    }
    __syncthreads();
    #pragma unroll
    for (int r = 0; r < 2; ++r) {
      int o = tid + r*256;
      int jl = o >> 5, b = o & 31;
      int off = (jl>>1)*64 + (jl&1)*32 + b;
      float v = pacc[off] + pacc[512+off] + pacc[1024+off] + pacc[1536+off];
      v += xg[(size_t)(b*T + t)*2048 + (jl>>2)*512 + hibase + (jl&3)];
      g_lds[jl*32 + b] = v;
    }
    __syncthreads();
    if (tid < 128) {
      int hil = tid >> 5, b = tid & 31;
      float gi = g_lds[(0*4+hil)*32 + b];
      float gf = g_lds[(1*4+hil)*32 + b];
      float gg = g_lds[(2*4+hil)*32 + b];
      float go = g_lds[(3*4+hil)*32 + b];
      c_reg = sigm(gf)*c_reg + sigm(gi)*tanhf(gg);
      float h = sigm(go)*tanhf(c_reg);
      int hi = hibase + hil;
      hn[hi*32 + b] = h;
      outbuf[(size_t)(b*T + t)*H2 + dir*512 + hi] = h * (float)mask[b*T + t];
    }
    pbar(eslots + (dir*64 + tt)*128, eflags + (dir*64 + tt)*16, nd, 128);
  }
}

// ---- decoder macros ----
#define ST(qq, OFF) { *(float4*)&S2[(OFF) + sr*36 + scol] = qq##a; \
  *(float4*)&S2[(OFF) + sr*36 + scol + 4] = qq##b; }
// load slice s (64 rows) from single base (rows are [s*64+sr])
#define GLD(qq, s, BASE) { const float* bs = (BASE) + ((s)*64 + sr)*32; \
  qq##a = *(const float4*)(bs + scol); qq##b = *(const float4*)(bs + scol + 4); }
// load slice s from concatenated [h | ctx]
#define SLD(qq, s) { int krr = (s)*64 + sr; \
  const float* bs = (krr < 1024) ? (hTa + krr*32) : (ctxa + (krr-1024)*32); \
  qq##a = *(const float4*)(bs + scol); qq##b = *(const float4*)(bs + scol + 4); }
// gates compute: weight col base KC (absolute k of slice start), LDS buf OFF
#define COMPG(KC, OFF) { const float* Sb = &S2[(OFF)]; \
  _Pragma("unroll") for (int i = 0; i < 2; ++i) { \
    float w0 = Wg[jl0*2052 + (KC) + i*32 + kk]; \
    float w1 = Wg[jl1*2052 + (KC) + i*32 + kk]; \
    const float* sp = Sb + (i*32 + kk)*36; \
    _Pragma("unroll") for (int q = 0; q < 8; ++q) { \
      float4 s4 = *(const float4*)(sp + q*4); \
      ga0[q*4+0] += w0*s4.x; ga0[q*4+1] += w0*s4.y; ga0[q*4+2] += w0*s4.z; ga0[q*4+3] += w0*s4.w; \
      ga1[q*4+0] += w1*s4.x; ga1[q*4+1] += w1*s4.y; ga1[q*4+2] += w1*s4.z; ga1[q*4+3] += w1*s4.w; } } }
// scores compute
#define COMPS(sl, OFF) { const float* sp = &S2[(OFF)] + kq*36; \
  float w0 = ws0[sl], w1 = ws1[sl]; \
  _Pragma("unroll") for (int q = 0; q < 8; ++q) { \
    float4 s4 = *(const float4*)(sp + q*4); \
    sa0[q*4+0] += w0*s4.x; sa0[q*4+1] += w0*s4.y; sa0[q*4+2] += w0*s4.z; sa0[q*4+3] += w0*s4.w; \
    sa1[q*4+0] += w1*s4.x; sa1[q*4+1] += w1*s4.y; sa1[q*4+2] += w1*s4.z; sa1[q*4+3] += w1*s4.w; } }
// 16-slice gates half: stage from BASE, weight cols KOFF..KOFF+1023
#define GATES_HALF(BASE, KOFF) { \
  float4 q0a,q0b,q1a,q1b,q2a,q2b,q3a,q3b; \
  GLD(q0, 0, BASE) GLD(q1, 1, BASE) GLD(q2, 2, BASE) GLD(q3, 3, BASE) \
  ST(q0, 0) \
  __syncthreads(); \
  for (int g = 0; g < 4; ++g) { \
    const int sl = g*4; \
    if (sl+4 < 16) GLD(q0, sl+4, BASE) \
    COMPG((KOFF) + sl*64, 0) \
    ST(q1, 2304) \
    __syncthreads(); \
    if (sl+5 < 16) GLD(q1, sl+5, BASE) \
    COMPG((KOFF) + (sl+1)*64, 2304) \
    ST(q2, 0) \
    __syncthreads(); \
    if (sl+6 < 16) GLD(q2, sl+6, BASE) \
    COMPG((KOFF) + (sl+2)*64, 0) \
    ST(q3, 2304) \
    __syncthreads(); \
    if (sl+7 < 16) GLD(q3, sl+7, BASE) \
    COMPG((KOFF) + (sl+3)*64, 2304) \
    if (sl+4 < 16) ST(q0, 0) \
    __syncthreads(); \
  } }
// cross-wave reduce + ext + LSTM cell; writes h to HTDST and hrow
#define REDUCE_CELL(HTDST) { \
  _Pragma("unroll") for (int dd = 8; dd <= 32; dd <<= 1) { \
    _Pragma("unroll") for (int q = 0; q < 32; ++q) { \
      ga0[q] += __shfl_down(ga0[q], dd, 64); \
      ga1[q] += __shfl_down(ga1[q], dd, 64); } } \
  if (lane < 8) { float* pw = &pacc[wv*512 + lane*64]; \
    _Pragma("unroll") for (int q = 0; q < 32; ++q) { pw[q] = ga0[q]; pw[32+q] = ga1[q]; } } \
  __syncthreads(); \
  _Pragma("unroll") for (int r = 0; r < 2; ++r) { \
    int o = tid + r*256; int jl = o >> 5, b = o & 31; \
    int off = (jl>>1)*64 + (jl&1)*32 + b; \
    float vsum = pacc[off] + pacc[512+off] + pacc[1024+off] + pacc[1536+off]; \
    vsum += (r == 0) ? extA : extB; \
    g_lds[jl*32 + b] = vsum; } \
  __syncthreads(); \
  if (tid < 128) { int hil = tid >> 5, b = tid & 31; \
    float gi = g_lds[(0*4+hil)*32 + b]; float gf = g_lds[(1*4+hil)*32 + b]; \
    float gg = g_lds[(2*4+hil)*32 + b]; float go = g_lds[(3*4+hil)*32 + b]; \
    c_reg = sigm(gf)*c_reg + sigm(gi)*tanhf(gg); \
    float h = sigm(go)*tanhf(c_reg); \
    int hi = hibase + hil; \
    (HTDST)[hi*32 + b] = h; hrow[b*1024 + hi] = h; } }

// ---------------- persistent decoder: 3-interval schedule ----------------
// Dynamic LDS (floats): Wg 16x2052=32832 | S2 2x64x36=4608 | pacc 2048 | g_lds 512 = 160000 B
__global__ __launch_bounds__(256, 1) void decoder_persistent(
    const float* __restrict__ basep, const float* __restrict__ tagp,
    const float* __restrict__ dWhh,  const float* __restrict__ dWih,
    const float* __restrict__ Wout,  const float* __restrict__ bout,
    const float* __restrict__ projo, const float* __restrict__ outbuf,
    const int* __restrict__ mask,
    float* __restrict__ hT,          // [2][1024][32]
    float* __restrict__ ctxT,        // [2][1024][32]
    float* __restrict__ hrow,        // [32][1024]
    float* __restrict__ dparts,      // [32][8][64] attention partial dots
    unsigned long long* __restrict__ argslot,
    unsigned* __restrict__ dslots, unsigned* __restrict__ dflags,
    float* __restrict__ out)
{
  extern __shared__ float dyn[];
  float* Wg    = dyn;           // 32832
  float* S2    = dyn + 32832;   // 4608
  float* pacc  = dyn + 37440;   // 2048
  float* g_lds = dyn + 39488;   // 512

  const int blk = blockIdx.x, tid = threadIdx.x;
  const int lane = tid & 63, wv = tid >> 6;
  const int hibase = blk * 4;
  const int jj = tid & 7, kk = tid >> 3;     // gates mapping
  const int jl0 = jj*2, jl1 = jj*2 + 1;
  const int vv = tid & 3, kq = tid >> 2;     // scores mapping
  const int vbase = blk * 8;
  const int ab = blk >> 3, aslice = blk & 7; // attention mapping: batch, 128-dim slice
  const int sr = tid >> 2, scol = (tid & 3) * 8;  // staging row/col

  // ---- preload gates weights into LDS (once) ----
  for (int jl = 0; jl < 16; ++jl) {
    int j = (jl>>2)*1024 + hibase + (jl&3);
    #pragma unroll
    for (int r = 0; r < 2; ++r) {
      int c = tid*4 + r*1024;
      float4 w;
      if (c < 1024) w = *(const float4*)(dWhh + (size_t)j*1024 + c);
      else          w = *(const float4*)(dWih + (size_t)j*2560 + 512 + (c - 1024));
      *(float4*)&Wg[jl*2052 + c] = w;
    }
  }
  // ---- scores weights in registers (64 floats/thread) ----
  float ws0[32], ws1[32];
  {
    int v0 = vbase + vv*2;
    #pragma unroll
    for (int s2 = 0; s2 < 32; ++s2) {
      ws0[s2] = Wout[(size_t)(v0+0)*2048 + s2*64 + kq];
      ws1[s2] = Wout[(size_t)(v0+1)*2048 + s2*64 + kq];
    }
  }

  float c_reg = 0.f;
  int bslot = 0;

  // ---- prologue 1: ctx(0) = attend(last_output)  (32 blocks, old path) ----
  if (blk < 32) {
    int b = blk;
    int len = -1;
    for (int i = 0; i < T; ++i) len += mask[b*T + i];
    attend_t(b, outbuf + (size_t)(b*T + len)*H2, ctxT, outbuf, projo, mask, pacc, tid);
  }
  pbar(dslots + (bslot)*256, dflags + (bslot)*16, blk, 256); bslot++;

  // ---- prologue 2: gates(0) = base(0) + Wctx*ctx(0)  (h(-1)=0 -> h-half exactly 0) ----
  {
    const int b_own = tid & 31;
    const int jlA = tid >> 5, jlB = jlA + 8;
    const int jA = (jlA>>2)*1024 + hibase + (jlA&3);
    const int jB = (jlB>>2)*1024 + hibase + (jlB&3);
    float extA = basep[(size_t)(b_own*T + 0)*G4 + jA];
    float extB = basep[(size_t)(b_own*T + 0)*G4 + jB];
    float ga0[32], ga1[32];
    #pragma unroll
    for (int q = 0; q < 32; ++q) { ga0[q] = 0.f; ga1[q] = 0.f; }
    GATES_HALF(ctxT, 1024)            // ctx(0) is in ctxT[0]
    REDUCE_CELL(hT)                   // h(0) -> hT[0], hrow
  }
  pbar(dslots + (bslot)*256, dflags + (bslot)*16, blk, 256); bslot++;

  // ---- main loop ----
  for (int t = 0; t < T; ++t) {
    const float* hTa  = hT   + (t & 1)*32768;     // h(t)
    const float* ctxa = ctxT + (t & 1)*32768;     // ctx(t)
    float*       ctxn = ctxT + ((t+1) & 1)*32768; // ctx(t+1)
    float*       hTn  = hT   + ((t+1) & 1)*32768; // h(t+1)

    // ===== I_a: attend-dots(t) + scores(t) + argmax =====
    if (t < 63) {   // partial dots: sc_part[ab][aslice][t'] = <h(t)[slice], projo[ab,t',slice]>
      const int tl = tid >> 2, dq = tid & 3;
      const float* hp = hrow + ab*1024 + aslice*128 + dq*32;
      const float* pp = projo + (size_t)(ab*T + tl)*H2 + aslice*128 + dq*32;
      float s = 0.f;
      #pragma unroll
      for (int i = 0; i < 8; ++i) {
        float4 a = *(const float4*)(hp + i*4);
        float4 b4 = *(const float4*)(pp + i*4);
        s += a.x*b4.x + a.y*b4.y + a.z*b4.z + a.w*b4.w;
      }
      s += __shfl_xor(s, 1, 64);
      s += __shfl_xor(s, 2, 64);
      if (dq == 0) dparts[(ab*8 + aslice)*64 + tl] = s;
    }
    {
      float sa0[32], sa1[32];
      #pragma unroll
      for (int q = 0; q < 32; ++q) { sa0[q] = 0.f; sa1[q] = 0.f; }
      {
        float4 q0a,q0b,q1a,q1b,q2a,q2b,q3a,q3b;
        SLD(q0, 0) SLD(q1, 1) SLD(q2, 2) SLD(q3, 3)
        ST(q0, 0)
        __syncthreads();
        #pragma unroll
        for (int g = 0; g < 8; ++g) {
          const int sl = g*4;
          if (sl+4 < 32) SLD(q0, sl+4)
          COMPS(sl, 0)
          ST(q1, 2304)
          __syncthreads();
          if (sl+5 < 32) SLD(q1, sl+5)
          COMPS(sl+1, 2304)
          ST(q2, 0)
          __syncthreads();
          if (sl+6 < 32) SLD(q2, sl+6)
          COMPS(sl+2, 0)
          ST(q3, 2304)
          __syncthreads();
          if (sl+7 < 32) SLD(q3, sl+7)
          COMPS(sl+3, 2304)
          if (sl+4 < 32) ST(q0, 0)
          __syncthreads();
        }
      }
      #pragma unroll
      for (int dd = 4; dd <= 32; dd <<= 1) {
        #pragma unroll
        for (int q = 0; q < 32; ++q) {
          sa0[q] += __shfl_down(sa0[q], dd, 64);
          sa1[q] += __shfl_down(sa1[q], dd, 64);
        }
      }
      if (lane < 4) {
        float* pw = &pacc[wv*256 + lane*64];
        #pragma unroll
        for (int q = 0; q < 32; ++q) { pw[q] = sa0[q]; pw[32+q] = sa1[q]; }
      }
      __syncthreads();
      {
        int vl = tid & 7, b = tid >> 3;
        int off = (vl>>1)*64 + (vl&1)*32 + b;
        float s = pacc[off] + pacc[256+off] + pacc[512+off] + pacc[768+off];
        s += bout[vbase + vl];
        out[(size_t)(b*T + t)*V + vbase + vl] = s;
        g_lds[vl*32 + b] = s;
      }
      __syncthreads();
      if (tid < 32) {
        int b = tid;
        float best = g_lds[b]; int bi = 0;
        #pragma unroll
        for (int vl = 1; vl < 8; ++vl) {
          float s = g_lds[vl*32 + b];
          if (s > best) { best = s; bi = vl; }
        }
        unsigned long long e = ((unsigned long long)fenc(best) << 32)
                             | (unsigned long long)(unsigned)(~(unsigned)(vbase + bi));
        atomicMax(&argslot[(t%3)*32 + b], e);
      }
    }
    pbar(dslots + (bslot)*256, dflags + (bslot)*16, blk, 256); bslot++;
    if (t == 63) break;

    // ===== I_b: attend-finish -> ctx(t+1) ; gates_A(t+1) = base+tag+Whh*h(t) =====
    // ext gather for step t+1 (issued early; tag(t) from argslot[t%3])
    const int b_own = tid & 31;
    const int jlA = tid >> 5, jlB = jlA + 8;
    const int jA = (jlA>>2)*1024 + hibase + (jlA&3);
    const int jB = (jlB>>2)*1024 + hibase + (jlB&3);
    float extA = basep[(size_t)(b_own*T + (t+1))*G4 + jA];
    float extB = basep[(size_t)(b_own*T + (t+1))*G4 + jB];
    {
      unsigned tg = ~(unsigned)argslot[(t%3)*32 + b_own];
      extA += tagp[(size_t)tg*G4 + jA];
      extB += tagp[(size_t)tg*G4 + jB];
    }
    {  // attend finish: sum partials, softmax, PV over this block's 128-dim slice
      float* scv = pacc;        // 64
      float* p2  = pacc + 64;   // 128
      if (tid < 64) {
        float s = 0.f;
        #pragma unroll
        for (int sfr = 0; sfr < 8; ++sfr) s += dparts[(ab*8 + sfr)*64 + tid];
        float mx = s;
        #pragma unroll
        for (int d = 32; d; d >>= 1) mx = fmaxf(mx, __shfl_xor(mx, d, 64));
        float e = expf(s - mx);
        float sm = e;
        #pragma unroll
        for (int d = 32; d; d >>= 1) sm += __shfl_xor(sm, d, 64);
        scv[tid] = e * (1.f / sm) * (float)mask[ab*T + tid];
      }
      __syncthreads();
      const int dl = tid & 127, th = tid >> 7;
      const int dg = aslice*128 + dl;
      float acc = 0.f;
      #pragma unroll 8
      for (int q = 0; q < 32; ++q) {
        int tt = th*32 + q;
        acc += scv[tt] * outbuf[(size_t)(ab*T + tt)*H2 + dg];
      }
      if (th == 1) p2[dl] = acc;
      __syncthreads();
      if (th == 0) ctxn[dg*32 + ab] = acc + p2[dl];
      __syncthreads();
    }
    float ga0[32], ga1[32];
    #pragma unroll
    for (int q = 0; q < 32; ++q) { ga0[q] = 0.f; ga1[q] = 0.f; }
    GATES_HALF(hTa, 0)
    if (blk == 255 && tid < 32) argslot[((t+2)%3)*32 + tid] = 0ull;  // reset future slot
    pbar(dslots + (bslot)*256, dflags + (bslot)*16, blk, 256); bslot++;

    // ===== I_c: gates_B += Wctx*ctx(t+1) ; reduce ; cell -> h(t+1) =====
    GATES_HALF(ctxn, 1024)
    REDUCE_CELL(hTn)
    pbar(dslots + (bslot)*256, dflags + (bslot)*16, blk, 256); bslot++;
  }
}

// ---------------- host launch ----------------
extern "C" void kernel_launch(void* const* d_in, const int* in_sizes, int n_in,
                              void* d_out, int out_size, void* d_ws, size_t ws_size,
                              hipStream_t stream)
{
  (void)in_sizes; (void)n_in; (void)out_size; (void)ws_size;
  const float* emb    = (const float*)d_in[0];
  const int*   mask   = (const int*)d_in[1];
  const float* Wih_f  = (const float*)d_in[2];
  const float* Whh_f  = (const float*)d_in[3];
  const float* bih_f  = (const float*)d_in[4];
  const float* bhh_f  = (const float*)d_in[5];
  const float* Wih_b  = (const float*)d_in[6];
  const float* Whh_b  = (const float*)d_in[7];
  const float* bih_b  = (const float*)d_in[8];
  const float* bhh_b  = (const float*)d_in[9];
  const float* attnW  = (const float*)d_in[10];
  const float* tagemb = (const float*)d_in[12];
  const float* dWih   = (const float*)d_in[13];
  const float* dWhh   = (const float*)d_in[14];
  const float* dbih   = (const float*)d_in[15];
  const float* dbhh   = (const float*)d_in[16];
  const float* Wout   = (const float*)d_in[17];
  const float* bout   = (const float*)d_in[18];
  float* out = (float*)d_out;

  float* ws = (float*)d_ws;
  float* xg_f   = ws + 0;          // 4194304
  float* xg_b   = ws + 4194304;    // 4194304
  float* outbuf = ws + 8388608;    // 2097152
  float* projo  = ws + 10485760;   // 2097152
  float* basep  = ws + 12582912;   // 8388608
  float* tagp   = ws + 20971520;   // 8388608
  // --- zeroed state block ---
  float* hT     = ws + 29360128;   // 65536  [2][1024][32]
  float* ctxT   = ws + 29425664;   // 65536  [2][1024][32]
  float* hrow   = ws + 29491200;   // 32768
  float* hencT  = ws + 29523968;   // 65536  [2][2][512][32]
  float* dparts = ws + 29589504;   // 16384  [32][8][64]
  unsigned long long* argslot = (unsigned long long*)(ws + 29605888);  // 96 u64 (192 fl)
  unsigned* dslots = (unsigned*)(ws + 29606080);   // 192*256 = 49152 u32
  unsigned* dflags = (unsigned*)(ws + 29655232);   // 192*16  = 3072 u32
  unsigned* eslots = (unsigned*)(ws + 29658304);   // 128*128 = 16384 u32
  unsigned* eflags = (unsigned*)(ws + 29674688);   // 128*16  = 2048 u32
  // end: 29676736 floats

  // allow 160000 B dynamic LDS for the decoder
  (void)hipFuncSetAttribute((const void*)decoder_persistent,
                            hipFuncAttributeMaxDynamicSharedMemorySize, 160000);

  // zero all persistent-kernel state every call (graph-replay deterministic)
  hipMemsetAsync((void*)(ws + 29360128), 0, (size_t)(29676736 - 29360128) * sizeof(float), stream);

  // xg = emb @ Wih^T + bih + bhh   (M=2048, N=2048, K=512)
  gemm_nt<<<dim3(32, 16), 256, 0, stream>>>(emb, 512, Wih_f, 512, xg_f, 2048, bih_f, bhh_f, 512);
  gemm_nt<<<dim3(32, 16), 256, 0, stream>>>(emb, 512, Wih_b, 512, xg_b, 2048, bih_b, bhh_b, 512);
  // tagp = tag_embed @ dec_Wih[:, :512]^T   (M=2048, N=4096, K=512)
  gemm_nt<<<dim3(64, 16), 256, 0, stream>>>(tagemb, 512, dWih, DEC_IN, tagp, G4, nullptr, nullptr, 512);
  // encoder scan (persistent, register-resident Whh)
  encoder_persistent<<<256, 256, 0, stream>>>(xg_f, xg_b, Whh_f, Whh_b, mask, hencT, outbuf, eslots, eflags);
  // projo[bt,d] = sum_e attn_W[d,e]*output[bt,e]   (M=2048, N=1024, K=1024)
  gemm_nt<<<dim3(16, 16), 256, 0, stream>>>(outbuf, H2, attnW, H2, projo, H2, nullptr, nullptr, H2);
  // basep = aligned @ dec_Wih[:,1536:]^T + dbih + dbhh   (M=2048, N=4096, K=1024)
  gemm_nt<<<dim3(64, 16), 256, 0, stream>>>(outbuf, H2, dWih + 1536, DEC_IN, basep, G4, dbih, dbhh, H2);
  // persistent decoder (3-interval schedule)
  decoder_persistent<<<256, 256, 160000, stream>>>(basep, tagp, dWhh, dWih, Wout, bout,
                                                   projo, outbuf, mask, hT, ctxT, hrow, dparts,
                                                   argslot, dslots, dflags, out);
}

// Round 9
// 8477.858 us; speedup vs baseline: 1.5487x; 1.5487x over previous
//
#include <hip/hip_runtime.h>

#define B   32
#define T   64
#define D   512
#define H   512
#define H2  1024
#define G4  4096
#define V   2048
#define DEC_IN 2560

__device__ __forceinline__ float sigm(float x) { return 1.f / (1.f + expf(-x)); }

__device__ __forceinline__ unsigned fenc(float f) {
  unsigned u = __float_as_uint(f);
  return (u & 0x80000000u) ? ~u : (u | 0x80000000u);
}

// ---- store-based parallel grid barrier (R6-proven) ----
__device__ __forceinline__ void pbar(unsigned* slots, unsigned* flag, int myid, int nblk) {
  __syncthreads();
  if (threadIdx.x == 0)
    __hip_atomic_store(slots + myid, 1u, __ATOMIC_RELEASE, __HIP_MEMORY_SCOPE_AGENT);
  if (myid == 0) {
    for (int s = threadIdx.x; s < nblk; s += 256) {
      while (!__hip_atomic_load(slots + s, __ATOMIC_RELAXED, __HIP_MEMORY_SCOPE_AGENT))
        __builtin_amdgcn_s_sleep(1);
    }
    __syncthreads();
    if (threadIdx.x == 0)
      __hip_atomic_store(flag, 1u, __ATOMIC_RELEASE, __HIP_MEMORY_SCOPE_AGENT);
  }
  if (threadIdx.x == 0) {
    while (!__hip_atomic_load(flag, __ATOMIC_RELAXED, __HIP_MEMORY_SCOPE_AGENT))
      __builtin_amdgcn_s_sleep(1);
    (void)__hip_atomic_load(flag, __ATOMIC_ACQUIRE, __HIP_MEMORY_SCOPE_AGENT);
  }
  __syncthreads();
}

// ---------------- generic fp32 GEMM ----------------
__global__ __launch_bounds__(256) void gemm_nt(
    const float* __restrict__ A, int lda,
    const float* __restrict__ W, int ldw,
    float* __restrict__ C, int ldc,
    const float* __restrict__ bias0, const float* __restrict__ bias1,
    int K)
{
  __shared__ float As[16][132];
  __shared__ float Ws[16][68];
  const int tid = threadIdx.x;
  const int nb = blockIdx.x * 64;
  const int mb = blockIdx.y * 128;
  const int tx = tid & 15;
  const int ty = tid >> 4;
  float acc[8][4] = {};

  const int am = tid >> 1, ak = (tid & 1) * 8;
  const int wn = tid >> 2, wk = (tid & 3) * 4;
  const float* aptr = A + (size_t)(mb + am) * lda + ak;
  const float* wptr = W + (size_t)(nb + wn) * ldw + wk;

  for (int k0 = 0; k0 < K; k0 += 16) {
    float4 u = *(const float4*)(aptr + k0);
    float4 v = *(const float4*)(aptr + k0 + 4);
    float4 w = *(const float4*)(wptr + k0);
    As[ak+0][am] = u.x; As[ak+1][am] = u.y; As[ak+2][am] = u.z; As[ak+3][am] = u.w;
    As[ak+4][am] = v.x; As[ak+5][am] = v.y; As[ak+6][am] = v.z; As[ak+7][am] = v.w;
    Ws[wk+0][wn] = w.x; Ws[wk+1][wn] = w.y; Ws[wk+2][wn] = w.z; Ws[wk+3][wn] = w.w;
    __syncthreads();
    #pragma unroll
    for (int k = 0; k < 16; ++k) {
      float4 a0 = *(const float4*)&As[k][ty*8];
      float4 a1 = *(const float4*)&As[k][ty*8+4];
      float4 wv = *(const float4*)&Ws[k][tx*4];
      float av[8] = {a0.x,a0.y,a0.z,a0.w,a1.x,a1.y,a1.z,a1.w};
      #pragma unroll
      for (int i = 0; i < 8; ++i) {
        acc[i][0] += av[i]*wv.x; acc[i][1] += av[i]*wv.y;
        acc[i][2] += av[i]*wv.z; acc[i][3] += av[i]*wv.w;
      }
    }
    __syncthreads();
  }
  float b4[4];
  #pragma unroll
  for (int j = 0; j < 4; ++j) {
    float bv = 0.f;
    if (bias0) bv += bias0[nb + tx*4 + j];
    if (bias1) bv += bias1[nb + tx*4 + j];
    b4[j] = bv;
  }
  #pragma unroll
  for (int i = 0; i < 8; ++i) {
    float4 o;
    o.x = acc[i][0] + b4[0]; o.y = acc[i][1] + b4[1];
    o.z = acc[i][2] + b4[2]; o.w = acc[i][3] + b4[3];
    *(float4*)&C[(size_t)(mb + ty*8 + i) * ldc + nb + tx*4] = o;
  }
}

// ---------------- attention helper for 512-thread blocks ----------------
__device__ void attend_t512(int b, const float* __restrict__ hvec, float* __restrict__ ctxdst,
                            const float* __restrict__ outbuf, const float* __restrict__ projo,
                            const int* __restrict__ mask, float* scratch, int tid)
{
  float* scp = scratch;        // 512
  float* scv = scratch + 512;  // 64
  const int tq = tid >> 3, dq = tid & 7;
  const float4* hv = (const float4*)(hvec + dq*128);
  const float4* pv = (const float4*)(projo + (size_t)(b*T + tq)*H2 + dq*128);
  float p = 0.f;
  #pragma unroll 8
  for (int k4 = 0; k4 < 32; ++k4) {
    float4 a = hv[k4], q = pv[k4];
    p += a.x*q.x + a.y*q.y + a.z*q.z + a.w*q.w;
  }
  scp[tid] = p;
  __syncthreads();
  if (tid < 64) {
    float v = 0.f;
    #pragma unroll
    for (int i = 0; i < 8; ++i) v += scp[tid*8 + i];
    float mx = v;
    #pragma unroll
    for (int d = 32; d; d >>= 1) mx = fmaxf(mx, __shfl_xor(mx, d, 64));
    float e = expf(v - mx);
    float sm = e;
    #pragma unroll
    for (int d = 32; d; d >>= 1) sm += __shfl_xor(sm, d, 64);
    scv[tid] = e * (1.f / sm) * (float)mask[b*T + tid];
  }
  __syncthreads();
  float a0 = 0.f, a1 = 0.f;
  #pragma unroll 8
  for (int tt = 0; tt < 64; ++tt) {
    float pp = scv[tt];
    float2 o2 = *(const float2*)(outbuf + (size_t)(b*T + tt)*H2 + tid*2);
    a0 += pp*o2.x; a1 += pp*o2.y;
  }
  ctxdst[(tid*2+0)*32 + b] = a0;
  ctxdst[(tid*2+1)*32 + b] = a1;
}

// ---------------- persistent encoder (unchanged, 256 threads) ----------
__global__ __launch_bounds__(256, 1) void encoder_persistent(
    const float* __restrict__ xg_f, const float* __restrict__ xg_b,
    const float* __restrict__ Whh_f, const float* __restrict__ Whh_b,
    const int* __restrict__ mask,
    float* __restrict__ hencT,    // [dir][2][512][32]
    float* __restrict__ outbuf,
    unsigned* __restrict__ eslots, unsigned* __restrict__ eflags)
{
  __shared__ float S_lds[2][128*36];
  __shared__ float pacc[2048];
  __shared__ float g_lds[512];
  const int blk = blockIdx.x, tid = threadIdx.x;
  const int lane = tid & 63, wv = tid >> 6;
  const int dir = blk >> 7, nd = blk & 127;
  const int hibase = nd * 4;
  const int jj = tid & 7, kk = tid >> 3;
  const float* xg  = dir ? xg_b : xg_f;
  const float* Whh = dir ? Whh_b : Whh_f;
  float* hbase = hencT + dir * 32768;

  float wge[2][16];
  #pragma unroll
  for (int p = 0; p < 2; ++p) {
    int jl = jj*2 + p;
    int j = (jl>>2)*512 + hibase + (jl&3);
    #pragma unroll
    for (int sc = 0; sc < 4; ++sc)
      #pragma unroll
      for (int i = 0; i < 4; ++i)
        wge[p][sc*4+i] = Whh[(size_t)j*512 + sc*128 + i*32 + kk];
  }
  float c_reg = 0.f;
  const int kr = tid >> 1, bh = (tid & 1) * 16;

  for (int tt = 0; tt < 64; ++tt) {
    const int t = dir ? (63 - tt) : tt;
    const float* hc = hbase + (tt & 1) * 16384;
    float* hn = hbase + ((tt + 1) & 1) * 16384;

    float a0[32], a1[32];
    #pragma unroll
    for (int q = 0; q < 32; ++q) { a0[q] = 0.f; a1[q] = 0.f; }

    float4 rr0, rr1, rr2, rr3;
    {
      const float4* p = (const float4*)(hc + kr*32 + bh);
      rr0 = p[0]; rr1 = p[1]; rr2 = p[2]; rr3 = p[3];
      float* d = &S_lds[0][kr*36 + bh];
      *(float4*)d = rr0; *(float4*)(d+4) = rr1; *(float4*)(d+8) = rr2; *(float4*)(d+12) = rr3;
    }
    __syncthreads();
    #pragma unroll
    for (int sc = 0; sc < 4; ++sc) {
      if (sc < 3) {
        const float4* p = (const float4*)(hc + (sc+1)*4096 + kr*32 + bh);
        rr0 = p[0]; rr1 = p[1]; rr2 = p[2]; rr3 = p[3];
      }
      const float* Sb = &S_lds[sc & 1][0];
      #pragma unroll
      for (int i = 0; i < 4; ++i) {
        const float* sp = Sb + (i*32 + kk)*36;
        float w0 = wge[0][sc*4+i], w1 = wge[1][sc*4+i];
        #pragma unroll
        for (int q = 0; q < 8; ++q) {
          float4 s4 = *(const float4*)(sp + q*4);
          a0[q*4+0] += w0*s4.x; a0[q*4+1] += w0*s4.y; a0[q*4+2] += w0*s4.z; a0[q*4+3] += w0*s4.w;
          a1[q*4+0] += w1*s4.x; a1[q*4+1] += w1*s4.y; a1[q*4+2] += w1*s4.z; a1[q*4+3] += w1*s4.w;
        }
      }
      if (sc < 3) {
        float* d = &S_lds[(sc+1) & 1][kr*36 + bh];
        *(float4*)d = rr0; *(float4*)(d+4) = rr1; *(float4*)(d+8) = rr2; *(float4*)(d+12) = rr3;
      }
      __syncthreads();
    }
    #pragma unroll
    for (int dd = 8; dd <= 32; dd <<= 1) {
      #pragma unroll
      for (int q = 0; q < 32; ++q) {
        a0[q] += __shfl_down(a0[q], dd, 64);
        a1[q] += __shfl_down(a1[q], dd, 64);
      }
    }
    if (lane < 8) {
      float* pw = &pacc[wv*512 + lane*64];
      #pragma unroll
      for (int q = 0; q < 32; ++q) { pw[q] = a0[q]; pw[32+q] = a1[q]; }
    }
    __syncthreads();
    #pragma unroll
    for (int r = 0; r < 2; ++r) {
      int o = tid + r*256;
      int jl = o >> 5, b = o & 31;
      int off = (jl>>1)*64 + (jl&1)*32 + b;
      float v = pacc[off] + pacc[512+off] + pacc[1024+off] + pacc[1536+off];
      v += xg[(size_t)(b*T + t)*2048 + (jl>>2)*512 + hibase + (jl&3)];
      g_lds[jl*32 + b] = v;
    }
    __syncthreads();
    if (tid < 128) {
      int hil = tid >> 5, b = tid & 31;
      float gi = g_lds[(0*4+hil)*32 + b];
      float gf = g_lds[(1*4+hil)*32 + b];
      float gg = g_lds[(2*4+hil)*32 + b];
      float go = g_lds[(3*4+hil)*32 + b];
      c_reg = sigm(gf)*c_reg + sigm(gi)*tanhf(gg);
      float h = sigm(go)*tanhf(c_reg);
      int hi = hibase + hil;
      hn[hi*32 + b] = h;
      outbuf[(size_t)(b*T + t)*H2 + dir*512 + hi] = h * (float)mask[b*T + t];
    }
    pbar(eslots + (dir*64 + tt)*128, eflags + (dir*64 + tt)*16, nd, 128);
  }
}

// ---- decoder macros (512-thread mapping: 1 float4 per thread per slice) ----
#define SLD1(qq, s) { int krr = (s)*64 + sr; \
  const float* bs = (krr < 1024) ? (hTc + krr*32) : (ctxc + (krr-1024)*32); \
  qq = *(const float4*)(bs + scol); }
#define SLD2(qq, s) { int krr = (s)*64 + sr; \
  const float* bs = (krr < 1024) ? (hTn + krr*32) : (ctxc + (krr-1024)*32); \
  qq = *(const float4*)(bs + scol); }
#define ST(qq, OFF) { *(float4*)&S2[(OFF) + sr*36 + scol] = qq; }
// gates: 2 rows (jl0,jl1), 1 k-row per slice (kk2)
#define COMPG(sl, OFF) { \
  float w0 = Wg[jl0*2052 + (sl)*64 + kk2]; \
  float w1 = Wg[jl1*2052 + (sl)*64 + kk2]; \
  const float* sp = &S2[(OFF)] + kk2*36; \
  _Pragma("unroll") for (int q = 0; q < 8; ++q) { \
    float4 s4 = *(const float4*)(sp + q*4); \
    a0[q*4+0] += w0*s4.x; a0[q*4+1] += w0*s4.y; a0[q*4+2] += w0*s4.z; a0[q*4+3] += w0*s4.w; \
    a1[q*4+0] += w1*s4.x; a1[q*4+1] += w1*s4.y; a1[q*4+2] += w1*s4.z; a1[q*4+3] += w1*s4.w; } }
// scores: 1 row, 1 k-row per slice (kq2)
#define COMPS(sl, OFF) { \
  float w0 = wsr[sl]; \
  const float* sp = &S2[(OFF)] + kq2*36; \
  _Pragma("unroll") for (int q = 0; q < 8; ++q) { \
    float4 s4 = *(const float4*)(sp + q*4); \
    a0[q*4+0] += w0*s4.x; a0[q*4+1] += w0*s4.y; a0[q*4+2] += w0*s4.z; a0[q*4+3] += w0*s4.w; } }

// ---------------- persistent decoder: 512 threads, 2 waves/SIMD -----------------
// Dynamic LDS (floats): Wg 16x2052=32832 | S2 2x64x36=4608 (pacc aliases S2) | g_lds 512
// total 37952 floats = 151808 B
__global__ __launch_bounds__(512, 2) void decoder_persistent(
    const float* __restrict__ basep, const float* __restrict__ tagp,
    const float* __restrict__ dWhh,  const float* __restrict__ dWih,
    const float* __restrict__ Wout,  const float* __restrict__ bout,
    const float* __restrict__ projo, const float* __restrict__ outbuf,
    const int* __restrict__ mask,
    float* __restrict__ hT,          // [2][1024][32]
    float* __restrict__ ctxT,        // [2][1024][32]
    float* __restrict__ hrow,        // [32][1024]
    unsigned long long* __restrict__ argslot,
    unsigned* __restrict__ dslots, unsigned* __restrict__ dflags,
    float* __restrict__ out)
{
  extern __shared__ float dyn[];
  float* Wg    = dyn;           // 32832
  float* S2    = dyn + 32832;   // 4608 (also pacc/scratch after staging done)
  float* pacc  = dyn + 32832;   // alias
  float* g_lds = dyn + 37440;   // 512

  const int blk = blockIdx.x, tid = threadIdx.x;
  const int lane = tid & 63, wv = tid >> 6;       // 8 waves
  const int hibase = blk * 4;
  const int jj = tid & 7, kk2 = tid >> 3;         // gates: j-pair, 64 k-chunks
  const int jl0 = jj*2, jl1 = jj*2 + 1;
  const int vv3 = tid & 7, kq2 = tid >> 3;        // scores: v-row, 64 k-chunks
  const int vbase = blk * 8;
  const int sr = tid >> 3, scol = (tid & 7) * 4;  // staging row/col (1 float4)

  // ---- preload gates weights into LDS (once): row jl, 2048 cols, 1 float4/thread ----
  for (int jl = 0; jl < 16; ++jl) {
    int j = (jl>>2)*1024 + hibase + (jl&3);
    int c = tid*4;
    float4 w;
    if (c < 1024) w = *(const float4*)(dWhh + (size_t)j*1024 + c);
    else          w = *(const float4*)(dWih + (size_t)j*2560 + 512 + (c - 1024));
    *(float4*)&Wg[jl*2052 + c] = w;
  }
  // ---- scores weights in registers (32 floats/thread) ----
  float wsr[32];
  {
    int v = vbase + vv3;
    #pragma unroll
    for (int s2 = 0; s2 < 32; ++s2)
      wsr[s2] = Wout[(size_t)v*2048 + s2*64 + kq2];
  }

  float c_reg = 0.f;
  int bslot = 0;

  // ---- prologue: ctx(0) = attend(last_output) ----
  if (blk < 32) {
    int b = blk;
    int len = -1;
    for (int i = 0; i < T; ++i) len += mask[b*T + i];
    attend_t512(b, outbuf + (size_t)(b*T + len)*H2, ctxT, outbuf, projo, mask, pacc, tid);
  }
  pbar(dslots + (bslot)*256, dflags + (bslot)*16, blk, 256); bslot++;

  for (int t = 0; t < T; ++t) {
    const int cur = t & 1, nxt = cur ^ 1;
    const float* hTc  = hT + cur*32768;
    float*       hTn  = hT + nxt*32768;
    const float* ctxc = ctxT + cur*32768;
    float*       ctxn = ctxT + nxt*32768;

    // per-thread external gate contribution for its single output (jl = tid>>5, b = tid&31)
    const int b_own = tid & 31;
    const int jlE = tid >> 5;                     // 0..15
    const int jE = (jlE>>2)*1024 + hibase + (jlE&3);
    float extv = basep[(size_t)(b_own*T + t)*G4 + jE];
    if (t > 0) {
      unsigned tg = ~(unsigned)argslot[((t+2)%3)*32 + b_own];
      extv += tagp[(size_t)tg*G4 + jE];
    }

    // ===== phase 1: gates (K=2048: h | ctx), 4-deep register prefetch =====
    float a0[32], a1[32];
    #pragma unroll
    for (int q = 0; q < 32; ++q) { a0[q] = 0.f; a1[q] = 0.f; }
    {
      float4 q0, q1, q2, q3;
      SLD1(q0, 0) SLD1(q1, 1) SLD1(q2, 2) SLD1(q3, 3)
      ST(q0, 0)
      __syncthreads();
      for (int g = 0; g < 8; ++g) {
        const int sl = g*4;
        if (sl+4 < 32) SLD1(q0, sl+4)
        COMPG(sl, 0)
        ST(q1, 2304)
        __syncthreads();
        if (sl+5 < 32) SLD1(q1, sl+5)
        COMPG(sl+1, 2304)
        ST(q2, 0)
        __syncthreads();
        if (sl+6 < 32) SLD1(q2, sl+6)
        COMPG(sl+2, 0)
        ST(q3, 2304)
        __syncthreads();
        if (sl+7 < 32) SLD1(q3, sl+7)
        COMPG(sl+3, 2304)
        if (sl+4 < 32) ST(q0, 0)
        __syncthreads();
      }
    }
    // in-wave reduce over kk2-low (8) -> lanes 0..7 hold rows jl0/jl1 for jj=lane
    #pragma unroll
    for (int dd = 8; dd <= 32; dd <<= 1) {
      #pragma unroll
      for (int q = 0; q < 32; ++q) {
        a0[q] += __shfl_down(a0[q], dd, 64);
        a1[q] += __shfl_down(a1[q], dd, 64);
      }
    }
    if (lane < 8) {
      float* pw = &pacc[wv*512 + lane*64];
      #pragma unroll
      for (int q = 0; q < 32; ++q) { pw[q] = a0[q]; pw[32+q] = a1[q]; }
    }
    __syncthreads();
    {
      int jl = tid >> 5, b = tid & 31;
      int jj2 = jl >> 1, p = jl & 1;
      float vsum = 0.f;
      #pragma unroll
      for (int w = 0; w < 8; ++w) vsum += pacc[w*512 + jj2*64 + p*32 + b];
      vsum += extv;
      g_lds[jl*32 + b] = vsum;
    }
    __syncthreads();
    if (tid < 128) {
      int hil = tid >> 5, b = tid & 31;
      float gi = g_lds[(0*4+hil)*32 + b];
      float gf = g_lds[(1*4+hil)*32 + b];
      float gg = g_lds[(2*4+hil)*32 + b];
      float go = g_lds[(3*4+hil)*32 + b];
      c_reg = sigm(gf)*c_reg + sigm(gi)*tanhf(gg);
      float h = sigm(go)*tanhf(c_reg);
      int hi = hibase + hil;
      hTn[hi*32 + b] = h;
      hrow[b*1024 + hi] = h;
    }
    pbar(dslots + (bslot)*256, dflags + (bslot)*16, blk, 256); bslot++;

    // ===== phase 2: scores (K=2048: h_new | ctx_old), weights in regs =====
    #pragma unroll
    for (int q = 0; q < 32; ++q) a0[q] = 0.f;
    {
      float4 q0, q1, q2, q3;
      SLD2(q0, 0) SLD2(q1, 1) SLD2(q2, 2) SLD2(q3, 3)
      ST(q0, 0)
      __syncthreads();
      #pragma unroll
      for (int g = 0; g < 8; ++g) {
        const int sl = g*4;
        if (sl+4 < 32) SLD2(q0, sl+4)
        COMPS(sl, 0)
        ST(q1, 2304)
        __syncthreads();
        if (sl+5 < 32) SLD2(q1, sl+5)
        COMPS(sl+1, 2304)
        ST(q2, 0)
        __syncthreads();
        if (sl+6 < 32) SLD2(q2, sl+6)
        COMPS(sl+2, 0)
        ST(q3, 2304)
        __syncthreads();
        if (sl+7 < 32) SLD2(q3, sl+7)
        COMPS(sl+3, 2304)
        if (sl+4 < 32) ST(q0, 0)
        __syncthreads();
      }
    }
    #pragma unroll
    for (int dd = 8; dd <= 32; dd <<= 1) {
      #pragma unroll
      for (int q = 0; q < 32; ++q)
        a0[q] += __shfl_down(a0[q], dd, 64);
    }
    if (lane < 8) {
      float* pw = &pacc[wv*256 + lane*32];
      #pragma unroll
      for (int q = 0; q < 32; ++q) pw[q] = a0[q];
    }
    __syncthreads();
    if (tid < 256) {
      int vl = tid >> 5, b = tid & 31;
      float s = 0.f;
      #pragma unroll
      for (int w = 0; w < 8; ++w) s += pacc[w*256 + vl*32 + b];
      s += bout[vbase + vl];
      out[(size_t)(b*T + t)*V + vbase + vl] = s;
      g_lds[vl*32 + b] = s;
    }
    __syncthreads();
    if (tid < 32) {
      int b = tid;
      float best = g_lds[b]; int bi = 0;
      #pragma unroll
      for (int vl = 1; vl < 8; ++vl) {
        float s = g_lds[vl*32 + b];
        if (s > best) { best = s; bi = vl; }
      }
      unsigned long long e = ((unsigned long long)fenc(best) << 32)
                           | (unsigned long long)(unsigned)(~(unsigned)(vbase + bi));
      atomicMax(&argslot[(t%3)*32 + b], e);
    } else if (blk == 0 && tid >= 32 && tid < 64) {
      argslot[((t+1)%3)*32 + (tid - 32)] = 0ull;
    }
    if (blk < 32) {
      __syncthreads();
      attend_t512(blk, hrow + blk*1024, ctxn, outbuf, projo, mask, pacc, tid);
    }
    pbar(dslots + (bslot)*256, dflags + (bslot)*16, blk, 256); bslot++;
  }
}

// ---------------- host launch ----------------
extern "C" void kernel_launch(void* const* d_in, const int* in_sizes, int n_in,
                              void* d_out, int out_size, void* d_ws, size_t ws_size,
                              hipStream_t stream)
{
  (void)in_sizes; (void)n_in; (void)out_size; (void)ws_size;
  const float* emb    = (const float*)d_in[0];
  const int*   mask   = (const int*)d_in[1];
  const float* Wih_f  = (const float*)d_in[2];
  const float* Whh_f  = (const float*)d_in[3];
  const float* bih_f  = (const float*)d_in[4];
  const float* bhh_f  = (const float*)d_in[5];
  const float* Wih_b  = (const float*)d_in[6];
  const float* Whh_b  = (const float*)d_in[7];
  const float* bih_b  = (const float*)d_in[8];
  const float* bhh_b  = (const float*)d_in[9];
  const float* attnW  = (const float*)d_in[10];
  const float* tagemb = (const float*)d_in[12];
  const float* dWih   = (const float*)d_in[13];
  const float* dWhh   = (const float*)d_in[14];
  const float* dbih   = (const float*)d_in[15];
  const float* dbhh   = (const float*)d_in[16];
  const float* Wout   = (const float*)d_in[17];
  const float* bout   = (const float*)d_in[18];
  float* out = (float*)d_out;

  float* ws = (float*)d_ws;
  float* xg_f   = ws + 0;          // 4194304
  float* xg_b   = ws + 4194304;    // 4194304
  float* outbuf = ws + 8388608;    // 2097152
  float* projo  = ws + 10485760;   // 2097152
  float* basep  = ws + 12582912;   // 8388608
  float* tagp   = ws + 20971520;   // 8388608
  // --- zeroed state block ---
  float* hT     = ws + 29360128;   // 65536  [2][1024][32]
  float* ctxT   = ws + 29425664;   // 65536  [2][1024][32]
  float* hrow   = ws + 29491200;   // 32768
  float* hencT  = ws + 29523968;   // 65536  [2][2][512][32]
  unsigned long long* argslot = (unsigned long long*)(ws + 29589504);  // 96 u64 (192 fl)
  unsigned* dslots = (unsigned*)(ws + 29589696);   // 129*256 = 33024 u32
  unsigned* dflags = (unsigned*)(ws + 29622720);   // 129*16  = 2064 u32
  unsigned* eslots = (unsigned*)(ws + 29624784);   // 128*128 = 16384 u32
  unsigned* eflags = (unsigned*)(ws + 29641168);   // 128*16  = 2048 u32
  // end: 29643216 floats

  // allow 151808 B dynamic LDS for the decoder
  (void)hipFuncSetAttribute((const void*)decoder_persistent,
                            hipFuncAttributeMaxDynamicSharedMemorySize, 151808);

  // zero all persistent-kernel state every call (graph-replay deterministic)
  hipMemsetAsync((void*)(ws + 29360128), 0, (size_t)(29643216 - 29360128) * sizeof(float), stream);

  // xg = emb @ Wih^T + bih + bhh   (M=2048, N=2048, K=512)
  gemm_nt<<<dim3(32, 16), 256, 0, stream>>>(emb, 512, Wih_f, 512, xg_f, 2048, bih_f, bhh_f, 512);
  gemm_nt<<<dim3(32, 16), 256, 0, stream>>>(emb, 512, Wih_b, 512, xg_b, 2048, bih_b, bhh_b, 512);
  // tagp = tag_embed @ dec_Wih[:, :512]^T   (M=2048, N=4096, K=512)
  gemm_nt<<<dim3(64, 16), 256, 0, stream>>>(tagemb, 512, dWih, DEC_IN, tagp, G4, nullptr, nullptr, 512);
  // encoder scan (persistent, register-resident Whh)
  encoder_persistent<<<256, 256, 0, stream>>>(xg_f, xg_b, Whh_f, Whh_b, mask, hencT, outbuf, eslots, eflags);
  // projo[bt,d] = sum_e attn_W[d,e]*output[bt,e]   (M=2048, N=1024, K=1024)
  gemm_nt<<<dim3(16, 16), 256, 0, stream>>>(outbuf, H2, attnW, H2, projo, H2, nullptr, nullptr, H2);
  // basep = aligned @ dec_Wih[:,1536:]^T + dbih + dbhh   (M=2048, N=4096, K=1024)
  gemm_nt<<<dim3(64, 16), 256, 0, stream>>>(outbuf, H2, dWih + 1536, DEC_IN, basep, G4, dbih, dbhh, H2);
  // persistent decoder (512 threads, 2 waves/SIMD)
  decoder_persistent<<<256, 512, 151808, stream>>>(basep, tagp, dWhh, dWih, Wout, bout,
                                                   projo, outbuf, mask, hT, ctxT, hrow,
                                                   argslot, dslots, dflags, out);
}

// Round 10
// 6217.508 us; speedup vs baseline: 2.1117x; 1.3635x over previous
//
#include <hip/hip_runtime.h>

#define B   32
#define T   64
#define D   512
#define H   512
#define H2  1024
#define G4  4096
#define V   2048
#define DEC_IN 2560

__device__ __forceinline__ float sigm(float x) { return 1.f / (1.f + expf(-x)); }

__device__ __forceinline__ unsigned fenc(float f) {
  unsigned u = __float_as_uint(f);
  return (u & 0x80000000u) ? ~u : (u | 0x80000000u);
}

// ---- store-based parallel grid barrier (R6-proven) ----
__device__ __forceinline__ void pbar(unsigned* slots, unsigned* flag, int myid, int nblk) {
  __syncthreads();
  if (threadIdx.x == 0)
    __hip_atomic_store(slots + myid, 1u, __ATOMIC_RELEASE, __HIP_MEMORY_SCOPE_AGENT);
  if (myid == 0) {
    for (int s = threadIdx.x; s < nblk; s += 256) {
      while (!__hip_atomic_load(slots + s, __ATOMIC_RELAXED, __HIP_MEMORY_SCOPE_AGENT))
        __builtin_amdgcn_s_sleep(1);
    }
    __syncthreads();
    if (threadIdx.x == 0)
      __hip_atomic_store(flag, 1u, __ATOMIC_RELEASE, __HIP_MEMORY_SCOPE_AGENT);
  }
  if (threadIdx.x == 0) {
    while (!__hip_atomic_load(flag, __ATOMIC_RELAXED, __HIP_MEMORY_SCOPE_AGENT))
      __builtin_amdgcn_s_sleep(1);
    (void)__hip_atomic_load(flag, __ATOMIC_ACQUIRE, __HIP_MEMORY_SCOPE_AGENT);
  }
  __syncthreads();
}

// ---------------- generic fp32 GEMM ----------------
__global__ __launch_bounds__(256) void gemm_nt(
    const float* __restrict__ A, int lda,
    const float* __restrict__ W, int ldw,
    float* __restrict__ C, int ldc,
    const float* __restrict__ bias0, const float* __restrict__ bias1,
    int K)
{
  __shared__ float As[16][132];
  __shared__ float Ws[16][68];
  const int tid = threadIdx.x;
  const int nb = blockIdx.x * 64;
  const int mb = blockIdx.y * 128;
  const int tx = tid & 15;
  const int ty = tid >> 4;
  float acc[8][4] = {};

  const int am = tid >> 1, ak = (tid & 1) * 8;
  const int wn = tid >> 2, wk = (tid & 3) * 4;
  const float* aptr = A + (size_t)(mb + am) * lda + ak;
  const float* wptr = W + (size_t)(nb + wn) * ldw + wk;

  for (int k0 = 0; k0 < K; k0 += 16) {
    float4 u = *(const float4*)(aptr + k0);
    float4 v = *(const float4*)(aptr + k0 + 4);
    float4 w = *(const float4*)(wptr + k0);
    As[ak+0][am] = u.x; As[ak+1][am] = u.y; As[ak+2][am] = u.z; As[ak+3][am] = u.w;
    As[ak+4][am] = v.x; As[ak+5][am] = v.y; As[ak+6][am] = v.z; As[ak+7][am] = v.w;
    Ws[wk+0][wn] = w.x; Ws[wk+1][wn] = w.y; Ws[wk+2][wn] = w.z; Ws[wk+3][wn] = w.w;
    __syncthreads();
    #pragma unroll
    for (int k = 0; k < 16; ++k) {
      float4 a0 = *(const float4*)&As[k][ty*8];
      float4 a1 = *(const float4*)&As[k][ty*8+4];
      float4 wv = *(const float4*)&Ws[k][tx*4];
      float av[8] = {a0.x,a0.y,a0.z,a0.w,a1.x,a1.y,a1.z,a1.w};
      #pragma unroll
      for (int i = 0; i < 8; ++i) {
        acc[i][0] += av[i]*wv.x; acc[i][1] += av[i]*wv.y;
        acc[i][2] += av[i]*wv.z; acc[i][3] += av[i]*wv.w;
      }
    }
    __syncthreads();
  }
  float b4[4];
  #pragma unroll
  for (int j = 0; j < 4; ++j) {
    float bv = 0.f;
    if (bias0) bv += bias0[nb + tx*4 + j];
    if (bias1) bv += bias1[nb + tx*4 + j];
    b4[j] = bv;
  }
  #pragma unroll
  for (int i = 0; i < 8; ++i) {
    float4 o;
    o.x = acc[i][0] + b4[0]; o.y = acc[i][1] + b4[1];
    o.z = acc[i][2] + b4[2]; o.w = acc[i][3] + b4[3];
    *(float4*)&C[(size_t)(mb + ty*8 + i) * ldc + nb + tx*4] = o;
  }
}

// ---------------- distributed attention: block (ab, aslice) -> ctx slice ----------------
// dots over full 1024 dims (all 256 threads), softmax (1 wave), PV over 128-dim slice.
__device__ void attend_slice(int ab, int aslice, const float* __restrict__ hvec,
                             float* __restrict__ ctxdst,
                             const float* __restrict__ outbuf, const float* __restrict__ projo,
                             const int* __restrict__ mask, float* scratch, int tid)
{
  float* scp = scratch;        // 256
  float* scv = scratch + 256;  // 64
  float* p2  = scratch + 320;  // 128
  const int tq = tid >> 2, dq = tid & 3;
  const float4* hv = (const float4*)(hvec + dq*256);
  const float4* pv = (const float4*)(projo + (size_t)(ab*T + tq)*H2 + dq*256);
  float p = 0.f;
  #pragma unroll 8
  for (int k4 = 0; k4 < 64; ++k4) {
    float4 a = hv[k4], q = pv[k4];
    p += a.x*q.x + a.y*q.y + a.z*q.z + a.w*q.w;
  }
  scp[tid] = p;
  __syncthreads();
  if (tid < 64) {
    float v = scp[tid*4] + scp[tid*4+1] + scp[tid*4+2] + scp[tid*4+3];
    float mx = v;
    #pragma unroll
    for (int d = 32; d; d >>= 1) mx = fmaxf(mx, __shfl_xor(mx, d, 64));
    float e = expf(v - mx);
    float sm = e;
    #pragma unroll
    for (int d = 32; d; d >>= 1) sm += __shfl_xor(sm, d, 64);
    scv[tid] = e * (1.f / sm) * (float)mask[ab*T + tid];
  }
  __syncthreads();
  {
    const int dl = tid & 127, th = tid >> 7;
    const int dg = aslice*128 + dl;
    float acc = 0.f;
    #pragma unroll 8
    for (int q = 0; q < 32; ++q) {
      int tt = th*32 + q;
      acc += scv[tt] * outbuf[(size_t)(ab*T + tt)*H2 + dg];
    }
    if (th == 1) p2[dl] = acc;
    __syncthreads();
    if (th == 0) ctxdst[dg*32 + ab] = acc + p2[dl];
  }
}

// ---------------- persistent encoder (unchanged from R6/R7) ----------
__global__ __launch_bounds__(256, 1) void encoder_persistent(
    const float* __restrict__ xg_f, const float* __restrict__ xg_b,
    const float* __restrict__ Whh_f, const float* __restrict__ Whh_b,
    const int* __restrict__ mask,
    float* __restrict__ hencT,    // [dir][2][512][32]
    float* __restrict__ outbuf,
    unsigned* __restrict__ eslots, unsigned* __restrict__ eflags)
{
  __shared__ float S_lds[2][128*36];
  __shared__ float pacc[2048];
  __shared__ float g_lds[512];
  const int blk = blockIdx.x, tid = threadIdx.x;
  const int lane = tid & 63, wv = tid >> 6;
  const int dir = blk >> 7, nd = blk & 127;
  const int hibase = nd * 4;
  const int jj = tid & 7, kk = tid >> 3;
  const float* xg  = dir ? xg_b : xg_f;
  const float* Whh = dir ? Whh_b : Whh_f;
  float* hbase = hencT + dir * 32768;

  float wge[2][16];
  #pragma unroll
  for (int p = 0; p < 2; ++p) {
    int jl = jj*2 + p;
    int j = (jl>>2)*512 + hibase + (jl&3);
    #pragma unroll
    for (int sc = 0; sc < 4; ++sc)
      #pragma unroll
      for (int i = 0; i < 4; ++i)
        wge[p][sc*4+i] = Whh[(size_t)j*512 + sc*128 + i*32 + kk];
  }
  float c_reg = 0.f;
  const int kr = tid >> 1, bh = (tid & 1) * 16;

  for (int tt = 0; tt < 64; ++tt) {
    const int t = dir ? (63 - tt) : tt;
    const float* hc = hbase + (tt & 1) * 16384;
    float* hn = hbase + ((tt + 1) & 1) * 16384;

    float a0[32], a1[32];
    #pragma unroll
    for (int q = 0; q < 32; ++q) { a0[q] = 0.f; a1[q] = 0.f; }

    float4 rr0, rr1, rr2, rr3;
    {
      const float4* p = (const float4*)(hc + kr*32 + bh);
      rr0 = p[0]; rr1 = p[1]; rr2 = p[2]; rr3 = p[3];
      float* d = &S_lds[0][kr*36 + bh];
      *(float4*)d = rr0; *(float4*)(d+4) = rr1; *(float4*)(d+8) = rr2; *(float4*)(d+12) = rr3;
    }
    __syncthreads();
    #pragma unroll
    for (int sc = 0; sc < 4; ++sc) {
      if (sc < 3) {
        const float4* p = (const float4*)(hc + (sc+1)*4096 + kr*32 + bh);
        rr0 = p[0]; rr1 = p[1]; rr2 = p[2]; rr3 = p[3];
      }
      const float* Sb = &S_lds[sc & 1][0];
      #pragma unroll
      for (int i = 0; i < 4; ++i) {
        const float* sp = Sb + (i*32 + kk)*36;
        float w0 = wge[0][sc*4+i], w1 = wge[1][sc*4+i];
        #pragma unroll
        for (int q = 0; q < 8; ++q) {
          float4 s4 = *(const float4*)(sp + q*4);
          a0[q*4+0] += w0*s4.x; a0[q*4+1] += w0*s4.y; a0[q*4+2] += w0*s4.z; a0[q*4+3] += w0*s4.w;
          a1[q*4+0] += w1*s4.x; a1[q*4+1] += w1*s4.y; a1[q*4+2] += w1*s4.z; a1[q*4+3] += w1*s4.w;
        }
      }
      if (sc < 3) {
        float* d = &S_lds[(sc+1) & 1][kr*36 + bh];
        *(float4*)d = rr0; *(float4*)(d+4) = rr1; *(float4*)(d+8) = rr2; *(float4*)(d+12) = rr3;
      }
      __syncthreads();
    }
    #pragma unroll
    for (int dd = 8; dd <= 32; dd <<= 1) {
      #pragma unroll
      for (int q = 0; q < 32; ++q) {
        a0[q] += __shfl_down(a0[q], dd, 64);
        a1[q] += __shfl_down(a1[q], dd, 64);
      }
    }
    if (lane < 8) {
      float* pw = &pacc[wv*512 + lane*64];
      #pragma unroll
      for (int q = 0; q < 32; ++q) { pw[q] = a0[q]; pw[32+q] = a1[q]; }
    }
    __syncthreads();
    #pragma unroll
    for (int r = 0; r < 2; ++r) {
      int o = tid + r*256;
      int jl = o >> 5, b = o & 31;
      int off = (jl>>1)*64 + (jl&1)*32 + b;
      float v = pacc[off] + pacc[512+off] + pacc[1024+off] + pacc[1536+off];
      v += xg[(size_t)(b*T + t)*2048 + (jl>>2)*512 + hibase + (jl&3)];
      g_lds[jl*32 + b] = v;
    }
    __syncthreads();
    if (tid < 128) {
      int hil = tid >> 5, b = tid & 31;
      float gi = g_lds[(0*4+hil)*32 + b];
      float gf = g_lds[(1*4+hil)*32 + b];
      float gg = g_lds[(2*4+hil)*32 + b];
      float go = g_lds[(3*4+hil)*32 + b];
      c_reg = sigm(gf)*c_reg + sigm(gi)*tanhf(gg);
      float h = sigm(go)*tanhf(c_reg);
      int hi = hibase + hil;
      hn[hi*32 + b] = h;
      outbuf[(size_t)(b*T + t)*H2 + dir*512 + hi] = h * (float)mask[b*T + t];
    }
    pbar(eslots + (dir*64 + tt)*128, eflags + (dir*64 + tt)*16, nd, 128);
  }
}

// ---- decoder macros: wave-private staging (NO __syncthreads in K-loops) ----
// gates: wave wv stages within-slice rows {8w..8w+7, 8w+32..8w+39}; scores: {16w..16w+15}
#define GROW1(lr) (8*wv + ((lr) < 8 ? (lr) : 24 + (lr)))
#define GROW2(lr) (16*wv + (lr))
#define SLDG(qq, s) { int krr = (s)*64 + GROW1(lrow); \
  const float* bs = (krr < 1024) ? (hTc + krr*32) : (ctxc + (krr-1024)*32); \
  qq##a = *(const float4*)(bs + scol2); qq##b = *(const float4*)(bs + scol2 + 4); }
#define SLDS(qq, s) { int krr = (s)*64 + GROW2(lrow); \
  const float* bs = (krr < 1024) ? (hTn + krr*32) : (ctxc + (krr-1024)*32); \
  qq##a = *(const float4*)(bs + scol2); qq##b = *(const float4*)(bs + scol2 + 4); }
#define STW(qq, BUF) { float* d = Sw + (BUF)*576 + lrow*36 + scol2; \
  *(float4*)d = qq##a; *(float4*)(d+4) = qq##b; }
// gates compute: reads local rows i*8+kkl; weights i*32 + kkg
#define COMPG(sl, BUF) { const float* Sb = Sw + (BUF)*576; \
  _Pragma("unroll") for (int i = 0; i < 2; ++i) { \
    float w0 = Wg[jl0*2052 + (sl)*64 + i*32 + kkg]; \
    float w1 = Wg[jl1*2052 + (sl)*64 + i*32 + kkg]; \
    const float* sp = Sb + (i*8 + kkl)*36; \
    _Pragma("unroll") for (int q = 0; q < 8; ++q) { \
      float4 s4 = *(const float4*)(sp + q*4); \
      a0[q*4+0] += w0*s4.x; a0[q*4+1] += w0*s4.y; a0[q*4+2] += w0*s4.z; a0[q*4+3] += w0*s4.w; \
      a1[q*4+0] += w1*s4.x; a1[q*4+1] += w1*s4.y; a1[q*4+2] += w1*s4.z; a1[q*4+3] += w1*s4.w; } } }
// scores compute: reads local row kql (== lrow)
#define COMPS(sl, BUF) { const float* sp = Sw + (BUF)*576 + lrow*36; \
  float w0 = ws0[sl], w1 = ws1[sl]; \
  _Pragma("unroll") for (int q = 0; q < 8; ++q) { \
    float4 s4 = *(const float4*)(sp + q*4); \
    a0[q*4+0] += w0*s4.x; a0[q*4+1] += w0*s4.y; a0[q*4+2] += w0*s4.z; a0[q*4+3] += w0*s4.w; \
    a1[q*4+0] += w1*s4.x; a1[q*4+1] += w1*s4.y; a1[q*4+2] += w1*s4.z; a1[q*4+3] += w1*s4.w; } }

// ---------------- persistent decoder: wave-private K-loops, distributed attend ----------
// Dynamic LDS (floats): Wg 16x2052=32832 | S2 4x2x576=4608 | pacc 2048 | g_lds 512 = 160000 B
__global__ __launch_bounds__(256, 1) void decoder_persistent(
    const float* __restrict__ basep, const float* __restrict__ tagp,
    const float* __restrict__ dWhh,  const float* __restrict__ dWih,
    const float* __restrict__ Wout,  const float* __restrict__ bout,
    const float* __restrict__ projo, const float* __restrict__ outbuf,
    const int* __restrict__ mask,
    float* __restrict__ hT,          // [2][1024][32]
    float* __restrict__ ctxT,        // [2][1024][32]
    float* __restrict__ hrow,        // [32][1024]
    unsigned long long* __restrict__ argslot,
    unsigned* __restrict__ dslots, unsigned* __restrict__ dflags,
    float* __restrict__ out)
{
  extern __shared__ float dyn[];
  float* Wg    = dyn;           // 32832
  float* S2    = dyn + 32832;   // 4608 (wave-private: wv*1152 + buf*576)
  float* pacc  = dyn + 37440;   // 2048
  float* g_lds = dyn + 39488;   // 512

  const int blk = blockIdx.x, tid = threadIdx.x;
  const int lane = tid & 63, wv = tid >> 6;
  const int hibase = blk * 4;
  const int jj = lane & 7, kkl = lane >> 3;       // gates: j-pair, local k-row
  const int kkg = 8*wv + kkl;                     // gates: global k-chunk 0..31
  const int jl0 = jj*2, jl1 = jj*2 + 1;
  const int vv = tid & 3, kq = tid >> 2;          // scores: v-pair, global k-row 0..63
  const int vbase = blk * 8;
  const int lrow = lane >> 2, scol2 = (lane & 3) * 8;  // wave-private staging row/col
  const int ab = blk >> 3, aslice = blk & 7;      // attention mapping
  float* Sw = S2 + wv*1152;

  // ---- preload gates weights into LDS (once) ----
  for (int jl = 0; jl < 16; ++jl) {
    int j = (jl>>2)*1024 + hibase + (jl&3);
    #pragma unroll
    for (int r = 0; r < 2; ++r) {
      int c = tid*4 + r*1024;
      float4 w;
      if (c < 1024) w = *(const float4*)(dWhh + (size_t)j*1024 + c);
      else          w = *(const float4*)(dWih + (size_t)j*2560 + 512 + (c - 1024));
      *(float4*)&Wg[jl*2052 + c] = w;
    }
  }
  // ---- scores weights in registers (64 floats/thread) ----
  float ws0[32], ws1[32];
  {
    int v0 = vbase + vv*2;
    #pragma unroll
    for (int s2 = 0; s2 < 32; ++s2) {
      ws0[s2] = Wout[(size_t)(v0+0)*2048 + s2*64 + kq];
      ws1[s2] = Wout[(size_t)(v0+1)*2048 + s2*64 + kq];
    }
  }

  float c_reg = 0.f;
  int bslot = 0;

  // ---- prologue: ctx(0) = attend(last_output), distributed over all 256 blocks ----
  {
    int len = -1;
    for (int i = 0; i < T; ++i) len += mask[ab*T + i];
    attend_slice(ab, aslice, outbuf + (size_t)(ab*T + len)*H2, ctxT,
                 outbuf, projo, mask, pacc, tid);
  }
  pbar(dslots + (bslot)*256, dflags + (bslot)*16, blk, 256); bslot++;

  for (int t = 0; t < T; ++t) {
    const int cur = t & 1, nxt = cur ^ 1;
    const float* hTc  = hT + cur*32768;
    float*       hTn  = hT + nxt*32768;
    const float* ctxc = ctxT + cur*32768;
    float*       ctxn = ctxT + nxt*32768;

    // prefetch per-thread external gate contributions (base + tag embed proj)
    const int b_own = tid & 31;
    const int jlA = tid >> 5, jlB = jlA + 8;
    const int jA = (jlA>>2)*1024 + hibase + (jlA&3);
    const int jB = (jlB>>2)*1024 + hibase + (jlB&3);
    float extA = basep[(size_t)(b_own*T + t)*G4 + jA];
    float extB = basep[(size_t)(b_own*T + t)*G4 + jB];
    if (t > 0) {
      unsigned tg = ~(unsigned)argslot[((t+2)%3)*32 + b_own];
      extA += tagp[(size_t)tg*G4 + jA];
      extB += tagp[(size_t)tg*G4 + jB];
    }

    // ===== phase 1: gates (K=2048: h | ctx), wave-private staging, no K-loop syncs =====
    float a0[32], a1[32];
    #pragma unroll
    for (int q = 0; q < 32; ++q) { a0[q] = 0.f; a1[q] = 0.f; }
    {
      float4 q0a,q0b,q1a,q1b,q2a,q2b,q3a,q3b;
      SLDG(q0, 0) SLDG(q1, 1) SLDG(q2, 2) SLDG(q3, 3)
      STW(q0, 0)
      for (int g = 0; g < 8; ++g) {
        const int sl = g*4;
        if (sl+4 < 32) SLDG(q0, sl+4)
        COMPG(sl, 0)
        STW(q1, 1)
        if (sl+5 < 32) SLDG(q1, sl+5)
        COMPG(sl+1, 1)
        STW(q2, 0)
        if (sl+6 < 32) SLDG(q2, sl+6)
        COMPG(sl+2, 0)
        STW(q3, 1)
        if (sl+7 < 32) SLDG(q3, sl+7)
        COMPG(sl+3, 1)
        if (sl+4 < 32) STW(q0, 0)
      }
    }
    #pragma unroll
    for (int dd = 8; dd <= 32; dd <<= 1) {
      #pragma unroll
      for (int q = 0; q < 32; ++q) {
        a0[q] += __shfl_down(a0[q], dd, 64);
        a1[q] += __shfl_down(a1[q], dd, 64);
      }
    }
    if (lane < 8) {
      float* pw = &pacc[wv*512 + lane*64];
      #pragma unroll
      for (int q = 0; q < 32; ++q) { pw[q] = a0[q]; pw[32+q] = a1[q]; }
    }
    __syncthreads();
    #pragma unroll
    for (int r = 0; r < 2; ++r) {
      int o = tid + r*256;
      int jl = o >> 5, b = o & 31;
      int off = (jl>>1)*64 + (jl&1)*32 + b;
      float vsum = pacc[off] + pacc[512+off] + pacc[1024+off] + pacc[1536+off];
      vsum += (r == 0) ? extA : extB;
      g_lds[jl*32 + b] = vsum;
    }
    __syncthreads();
    if (tid < 128) {
      int hil = tid >> 5, b = tid & 31;
      float gi = g_lds[(0*4+hil)*32 + b];
      float gf = g_lds[(1*4+hil)*32 + b];
      float gg = g_lds[(2*4+hil)*32 + b];
      float go = g_lds[(3*4+hil)*32 + b];
      c_reg = sigm(gf)*c_reg + sigm(gi)*tanhf(gg);
      float h = sigm(go)*tanhf(c_reg);
      int hi = hibase + hil;
      hTn[hi*32 + b] = h;
      hrow[b*1024 + hi] = h;
    }
    pbar(dslots + (bslot)*256, dflags + (bslot)*16, blk, 256); bslot++;

    // ===== phase 2: scores (K=2048: h_new | ctx_old), wave-private staging =====
    #pragma unroll
    for (int q = 0; q < 32; ++q) { a0[q] = 0.f; a1[q] = 0.f; }
    {
      float4 q0a,q0b,q1a,q1b,q2a,q2b,q3a,q3b;
      SLDS(q0, 0) SLDS(q1, 1) SLDS(q2, 2) SLDS(q3, 3)
      STW(q0, 0)
      #pragma unroll
      for (int g = 0; g < 8; ++g) {
        const int sl = g*4;
        if (sl+4 < 32) SLDS(q0, sl+4)
        COMPS(sl, 0)
        STW(q1, 1)
        if (sl+5 < 32) SLDS(q1, sl+5)
        COMPS(sl+1, 1)
        STW(q2, 0)
        if (sl+6 < 32) SLDS(q2, sl+6)
        COMPS(sl+2, 0)
        STW(q3, 1)
        if (sl+7 < 32) SLDS(q3, sl+7)
        COMPS(sl+3, 1)
        if (sl+4 < 32) STW(q0, 0)
      }
    }
    #pragma unroll
    for (int dd = 4; dd <= 32; dd <<= 1) {
      #pragma unroll
      for (int q = 0; q < 32; ++q) {
        a0[q] += __shfl_down(a0[q], dd, 64);
        a1[q] += __shfl_down(a1[q], dd, 64);
      }
    }
    if (lane < 4) {
      float* pw = &pacc[wv*256 + lane*64];
      #pragma unroll
      for (int q = 0; q < 32; ++q) { pw[q] = a0[q]; pw[32+q] = a1[q]; }
    }
    __syncthreads();
    {
      int vl = tid & 7, b = tid >> 3;
      int off = (vl>>1)*64 + (vl&1)*32 + b;
      float s = pacc[off] + pacc[256+off] + pacc[512+off] + pacc[768+off];
      s += bout[vbase + vl];
      out[(size_t)(b*T + t)*V + vbase + vl] = s;
      g_lds[vl*32 + b] = s;
    }
    __syncthreads();
    if (tid < 32) {
      int b = tid;
      float best = g_lds[b]; int bi = 0;
      #pragma unroll
      for (int vl = 1; vl < 8; ++vl) {
        float s = g_lds[vl*32 + b];
        if (s > best) { best = s; bi = vl; }
      }
      unsigned long long e = ((unsigned long long)fenc(best) << 32)
                           | (unsigned long long)(unsigned)(~(unsigned)(vbase + bi));
      atomicMax(&argslot[(t%3)*32 + b], e);
    } else if (blk == 0 && tid >= 32 && tid < 64) {
      argslot[((t+1)%3)*32 + (tid - 32)] = 0ull;
    }
    if (t < 63) {
      __syncthreads();
      attend_slice(ab, aslice, hrow + ab*1024, ctxn, outbuf, projo, mask, pacc, tid);
    }
    pbar(dslots + (bslot)*256, dflags + (bslot)*16, blk, 256); bslot++;
  }
}

// ---------------- host launch ----------------
extern "C" void kernel_launch(void* const* d_in, const int* in_sizes, int n_in,
                              void* d_out, int out_size, void* d_ws, size_t ws_size,
                              hipStream_t stream)
{
  (void)in_sizes; (void)n_in; (void)out_size; (void)ws_size;
  const float* emb    = (const float*)d_in[0];
  const int*   mask   = (const int*)d_in[1];
  const float* Wih_f  = (const float*)d_in[2];
  const float* Whh_f  = (const float*)d_in[3];
  const float* bih_f  = (const float*)d_in[4];
  const float* bhh_f  = (const float*)d_in[5];
  const float* Wih_b  = (const float*)d_in[6];
  const float* Whh_b  = (const float*)d_in[7];
  const float* bih_b  = (const float*)d_in[8];
  const float* bhh_b  = (const float*)d_in[9];
  const float* attnW  = (const float*)d_in[10];
  const float* tagemb = (const float*)d_in[12];
  const float* dWih   = (const float*)d_in[13];
  const float* dWhh   = (const float*)d_in[14];
  const float* dbih   = (const float*)d_in[15];
  const float* dbhh   = (const float*)d_in[16];
  const float* Wout   = (const float*)d_in[17];
  const float* bout   = (const float*)d_in[18];
  float* out = (float*)d_out;

  float* ws = (float*)d_ws;
  float* xg_f   = ws + 0;          // 4194304
  float* xg_b   = ws + 4194304;    // 4194304
  float* outbuf = ws + 8388608;    // 2097152
  float* projo  = ws + 10485760;   // 2097152
  float* basep  = ws + 12582912;   // 8388608
  float* tagp   = ws + 20971520;   // 8388608
  // --- zeroed state block ---
  float* hT     = ws + 29360128;   // 65536  [2][1024][32]
  float* ctxT   = ws + 29425664;   // 65536  [2][1024][32]
  float* hrow   = ws + 29491200;   // 32768
  float* hencT  = ws + 29523968;   // 65536  [2][2][512][32]
  unsigned long long* argslot = (unsigned long long*)(ws + 29589504);  // 96 u64 (192 fl)
  unsigned* dslots = (unsigned*)(ws + 29589696);   // 129*256 = 33024 u32
  unsigned* dflags = (unsigned*)(ws + 29622720);   // 129*16  = 2064 u32
  unsigned* eslots = (unsigned*)(ws + 29624784);   // 128*128 = 16384 u32
  unsigned* eflags = (unsigned*)(ws + 29641168);   // 128*16  = 2048 u32
  // end: 29643216 floats

  // allow 160000 B dynamic LDS for the decoder
  (void)hipFuncSetAttribute((const void*)decoder_persistent,
                            hipFuncAttributeMaxDynamicSharedMemorySize, 160000);

  // zero all persistent-kernel state every call (graph-replay deterministic)
  hipMemsetAsync((void*)(ws + 29360128), 0, (size_t)(29643216 - 29360128) * sizeof(float), stream);

  // xg = emb @ Wih^T + bih + bhh   (M=2048, N=2048, K=512)
  gemm_nt<<<dim3(32, 16), 256, 0, stream>>>(emb, 512, Wih_f, 512, xg_f, 2048, bih_f, bhh_f, 512);
  gemm_nt<<<dim3(32, 16), 256, 0, stream>>>(emb, 512, Wih_b, 512, xg_b, 2048, bih_b, bhh_b, 512);
  // tagp = tag_embed @ dec_Wih[:, :512]^T   (M=2048, N=4096, K=512)
  gemm_nt<<<dim3(64, 16), 256, 0, stream>>>(tagemb, 512, dWih, DEC_IN, tagp, G4, nullptr, nullptr, 512);
  // encoder scan (persistent, register-resident Whh)
  encoder_persistent<<<256, 256, 0, stream>>>(xg_f, xg_b, Whh_f, Whh_b, mask, hencT, outbuf, eslots, eflags);
  // projo[bt,d] = sum_e attn_W[d,e]*output[bt,e]   (M=2048, N=1024, K=1024)
  gemm_nt<<<dim3(16, 16), 256, 0, stream>>>(outbuf, H2, attnW, H2, projo, H2, nullptr, nullptr, H2);
  // basep = aligned @ dec_Wih[:,1536:]^T + dbih + dbhh   (M=2048, N=4096, K=1024)
  gemm_nt<<<dim3(64, 16), 256, 0, stream>>>(outbuf, H2, dWih + 1536, DEC_IN, basep, G4, dbih, dbhh, H2);
  // persistent decoder (wave-private staging, distributed attend)
  decoder_persistent<<<256, 256, 160000, stream>>>(basep, tagp, dWhh, dWih, Wout, bout,
                                                   projo, outbuf, mask, hT, ctxT, hrow,
                                                   argslot, dslots, dflags, out);
}

// Round 11
// 4980.936 us; speedup vs baseline: 2.6359x; 1.2483x over previous
//
#include <hip/hip_runtime.h>

#define B   32
#define T   64
#define D   512
#define H   512
#define H2  1024
#define G4  4096
#define V   2048
#define DEC_IN 2560

__device__ __forceinline__ float sigm(float x) { return 1.f / (1.f + expf(-x)); }

__device__ __forceinline__ unsigned fenc(float f) {
  unsigned u = __float_as_uint(f);
  return (u & 0x80000000u) ? ~u : (u | 0x80000000u);
}

__device__ __forceinline__ void st_wt(float* p, float v) {       // write-through (L3-visible on retire)
  __hip_atomic_store(p, v, __ATOMIC_RELAXED, __HIP_MEMORY_SCOPE_AGENT);
}

// ---- store-based grid barrier, WB-free: relaxed arrival (state stores are write-through),
// 16 replicated flags (64B apart), single ACQUIRE (L2 inv) at exit for cached readers. ----
__device__ __forceinline__ void pbar(unsigned* slots, unsigned* flags, int myid, int nblk) {
  __syncthreads();   // drains each wave's vmcnt -> all write-through stores L3-visible
  if (threadIdx.x == 0)
    __hip_atomic_store(slots + myid, 1u, __ATOMIC_RELAXED, __HIP_MEMORY_SCOPE_AGENT);
  if (myid == 0) {
    for (int s = threadIdx.x; s < nblk; s += 256) {
      while (!__hip_atomic_load(slots + s, __ATOMIC_RELAXED, __HIP_MEMORY_SCOPE_AGENT))
        __builtin_amdgcn_s_sleep(1);
    }
    __syncthreads();
    if (threadIdx.x < 16)
      __hip_atomic_store(flags + threadIdx.x*16, 1u, __ATOMIC_RELAXED, __HIP_MEMORY_SCOPE_AGENT);
  }
  if (threadIdx.x == 0) {
    unsigned* f = flags + (myid & 15)*16;
    while (!__hip_atomic_load(f, __ATOMIC_RELAXED, __HIP_MEMORY_SCOPE_AGENT))
      __builtin_amdgcn_s_sleep(1);
    (void)__hip_atomic_load(f, __ATOMIC_ACQUIRE, __HIP_MEMORY_SCOPE_AGENT);  // L2 INV only
  }
  __syncthreads();
}

// ---------------- generic fp32 GEMM ----------------
__global__ __launch_bounds__(256) void gemm_nt(
    const float* __restrict__ A, int lda,
    const float* __restrict__ W, int ldw,
    float* __restrict__ C, int ldc,
    const float* __restrict__ bias0, const float* __restrict__ bias1,
    int K)
{
  __shared__ float As[16][132];
  __shared__ float Ws[16][68];
  const int tid = threadIdx.x;
  const int nb = blockIdx.x * 64;
  const int mb = blockIdx.y * 128;
  const int tx = tid & 15;
  const int ty = tid >> 4;
  float acc[8][4] = {};

  const int am = tid >> 1, ak = (tid & 1) * 8;
  const int wn = tid >> 2, wk = (tid & 3) * 4;
  const float* aptr = A + (size_t)(mb + am) * lda + ak;
  const float* wptr = W + (size_t)(nb + wn) * ldw + wk;

  for (int k0 = 0; k0 < K; k0 += 16) {
    float4 u = *(const float4*)(aptr + k0);
    float4 v = *(const float4*)(aptr + k0 + 4);
    float4 w = *(const float4*)(wptr + k0);
    As[ak+0][am] = u.x; As[ak+1][am] = u.y; As[ak+2][am] = u.z; As[ak+3][am] = u.w;
    As[ak+4][am] = v.x; As[ak+5][am] = v.y; As[ak+6][am] = v.z; As[ak+7][am] = v.w;
    Ws[wk+0][wn] = w.x; Ws[wk+1][wn] = w.y; Ws[wk+2][wn] = w.z; Ws[wk+3][wn] = w.w;
    __syncthreads();
    #pragma unroll
    for (int k = 0; k < 16; ++k) {
      float4 a0 = *(const float4*)&As[k][ty*8];
      float4 a1 = *(const float4*)&As[k][ty*8+4];
      float4 wv = *(const float4*)&Ws[k][tx*4];
      float av[8] = {a0.x,a0.y,a0.z,a0.w,a1.x,a1.y,a1.z,a1.w};
      #pragma unroll
      for (int i = 0; i < 8; ++i) {
        acc[i][0] += av[i]*wv.x; acc[i][1] += av[i]*wv.y;
        acc[i][2] += av[i]*wv.z; acc[i][3] += av[i]*wv.w;
      }
    }
    __syncthreads();
  }
  float b4[4];
  #pragma unroll
  for (int j = 0; j < 4; ++j) {
    float bv = 0.f;
    if (bias0) bv += bias0[nb + tx*4 + j];
    if (bias1) bv += bias1[nb + tx*4 + j];
    b4[j] = bv;
  }
  #pragma unroll
  for (int i = 0; i < 8; ++i) {
    float4 o;
    o.x = acc[i][0] + b4[0]; o.y = acc[i][1] + b4[1];
    o.z = acc[i][2] + b4[2]; o.w = acc[i][3] + b4[3];
    *(float4*)&C[(size_t)(mb + ty*8 + i) * ldc + nb + tx*4] = o;
  }
}

// ---------------- distributed attention: block (ab, aslice) -> ctx slice ----------------
__device__ void attend_slice(int ab, int aslice, const float* __restrict__ hvec,
                             float* __restrict__ ctxdst,
                             const float* __restrict__ outbuf, const float* __restrict__ projo,
                             const int* __restrict__ mask, float* scratch, int tid)
{
  float* scp = scratch;        // 256
  float* scv = scratch + 256;  // 64
  float* p2  = scratch + 320;  // 128
  const int tq = tid >> 2, dq = tid & 3;
  const float4* hv = (const float4*)(hvec + dq*256);
  const float4* pv = (const float4*)(projo + (size_t)(ab*T + tq)*H2 + dq*256);
  float p = 0.f;
  #pragma unroll 8
  for (int k4 = 0; k4 < 64; ++k4) {
    float4 a = hv[k4], q = pv[k4];
    p += a.x*q.x + a.y*q.y + a.z*q.z + a.w*q.w;
  }
  scp[tid] = p;
  __syncthreads();
  if (tid < 64) {
    float v = scp[tid*4] + scp[tid*4+1] + scp[tid*4+2] + scp[tid*4+3];
    float mx = v;
    #pragma unroll
    for (int d = 32; d; d >>= 1) mx = fmaxf(mx, __shfl_xor(mx, d, 64));
    float e = expf(v - mx);
    float sm = e;
    #pragma unroll
    for (int d = 32; d; d >>= 1) sm += __shfl_xor(sm, d, 64);
    scv[tid] = e * (1.f / sm) * (float)mask[ab*T + tid];
  }
  __syncthreads();
  {
    const int dl = tid & 127, th = tid >> 7;
    const int dg = aslice*128 + dl;
    float acc = 0.f;
    #pragma unroll 8
    for (int q = 0; q < 32; ++q) {
      int tt = th*32 + q;
      acc += scv[tt] * outbuf[(size_t)(ab*T + tt)*H2 + dg];
    }
    if (th == 1) p2[dl] = acc;
    __syncthreads();
    if (th == 0) st_wt(&ctxdst[dg*32 + ab], acc + p2[dl]);
  }
}

// ---------------- persistent encoder ----------
__global__ __launch_bounds__(256, 1) void encoder_persistent(
    const float* __restrict__ xg_f, const float* __restrict__ xg_b,
    const float* __restrict__ Whh_f, const float* __restrict__ Whh_b,
    const int* __restrict__ mask,
    float* __restrict__ hencT,    // [dir][2][512][32]
    float* __restrict__ outbuf,
    unsigned* __restrict__ eslots, unsigned* __restrict__ eflags)
{
  __shared__ float S_lds[2][128*36];
  __shared__ float pacc[2048];
  __shared__ float g_lds[512];
  const int blk = blockIdx.x, tid = threadIdx.x;
  const int lane = tid & 63, wv = tid >> 6;
  const int dir = blk >> 7, nd = blk & 127;
  const int hibase = nd * 4;
  const int jj = tid & 7, kk = tid >> 3;
  const float* xg  = dir ? xg_b : xg_f;
  const float* Whh = dir ? Whh_b : Whh_f;
  float* hbase = hencT + dir * 32768;

  float wge[2][16];
  #pragma unroll
  for (int p = 0; p < 2; ++p) {
    int jl = jj*2 + p;
    int j = (jl>>2)*512 + hibase + (jl&3);
    #pragma unroll
    for (int sc = 0; sc < 4; ++sc)
      #pragma unroll
      for (int i = 0; i < 4; ++i)
        wge[p][sc*4+i] = Whh[(size_t)j*512 + sc*128 + i*32 + kk];
  }
  float c_reg = 0.f;
  const int kr = tid >> 1, bh = (tid & 1) * 16;

  for (int tt = 0; tt < 64; ++tt) {
    const int t = dir ? (63 - tt) : tt;
    const float* hc = hbase + (tt & 1) * 16384;
    float* hn = hbase + ((tt + 1) & 1) * 16384;

    float a0[32], a1[32];
    #pragma unroll
    for (int q = 0; q < 32; ++q) { a0[q] = 0.f; a1[q] = 0.f; }

    float4 rr0, rr1, rr2, rr3;
    {
      const float4* p = (const float4*)(hc + kr*32 + bh);
      rr0 = p[0]; rr1 = p[1]; rr2 = p[2]; rr3 = p[3];
      float* d = &S_lds[0][kr*36 + bh];
      *(float4*)d = rr0; *(float4*)(d+4) = rr1; *(float4*)(d+8) = rr2; *(float4*)(d+12) = rr3;
    }
    __syncthreads();
    #pragma unroll
    for (int sc = 0; sc < 4; ++sc) {
      if (sc < 3) {
        const float4* p = (const float4*)(hc + (sc+1)*4096 + kr*32 + bh);
        rr0 = p[0]; rr1 = p[1]; rr2 = p[2]; rr3 = p[3];
      }
      const float* Sb = &S_lds[sc & 1][0];
      #pragma unroll
      for (int i = 0; i < 4; ++i) {
        const float* sp = Sb + (i*32 + kk)*36;
        float w0 = wge[0][sc*4+i], w1 = wge[1][sc*4+i];
        #pragma unroll
        for (int q = 0; q < 8; ++q) {
          float4 s4 = *(const float4*)(sp + q*4);
          a0[q*4+0] += w0*s4.x; a0[q*4+1] += w0*s4.y; a0[q*4+2] += w0*s4.z; a0[q*4+3] += w0*s4.w;
          a1[q*4+0] += w1*s4.x; a1[q*4+1] += w1*s4.y; a1[q*4+2] += w1*s4.z; a1[q*4+3] += w1*s4.w;
        }
      }
      if (sc < 3) {
        float* d = &S_lds[(sc+1) & 1][kr*36 + bh];
        *(float4*)d = rr0; *(float4*)(d+4) = rr1; *(float4*)(d+8) = rr2; *(float4*)(d+12) = rr3;
      }
      __syncthreads();
    }
    #pragma unroll
    for (int dd = 8; dd <= 32; dd <<= 1) {
      #pragma unroll
      for (int q = 0; q < 32; ++q) {
        a0[q] += __shfl_down(a0[q], dd, 64);
        a1[q] += __shfl_down(a1[q], dd, 64);
      }
    }
    if (lane < 8) {
      float* pw = &pacc[wv*512 + lane*64];
      #pragma unroll
      for (int q = 0; q < 32; ++q) { pw[q] = a0[q]; pw[32+q] = a1[q]; }
    }
    __syncthreads();
    #pragma unroll
    for (int r = 0; r < 2; ++r) {
      int o = tid + r*256;
      int jl = o >> 5, b = o & 31;
      int off = (jl>>1)*64 + (jl&1)*32 + b;
      float v = pacc[off] + pacc[512+off] + pacc[1024+off] + pacc[1536+off];
      v += xg[(size_t)(b*T + t)*2048 + (jl>>2)*512 + hibase + (jl&3)];
      g_lds[jl*32 + b] = v;
    }
    __syncthreads();
    if (tid < 128) {
      int hil = tid >> 5, b = tid & 31;
      float gi = g_lds[(0*4+hil)*32 + b];
      float gf = g_lds[(1*4+hil)*32 + b];
      float gg = g_lds[(2*4+hil)*32 + b];
      float go = g_lds[(3*4+hil)*32 + b];
      c_reg = sigm(gf)*c_reg + sigm(gi)*tanhf(gg);
      float h = sigm(go)*tanhf(c_reg);
      int hi = hibase + hil;
      st_wt(&hn[hi*32 + b], h);
      st_wt(&outbuf[(size_t)(b*T + t)*H2 + dir*512 + hi], h * (float)mask[b*T + t]);
    }
    pbar(eslots + (dir*64 + tt)*128, eflags + (dir*64 + tt)*256, nd, 128);
  }
}

// ---- decoder macros: wave-private staging (NO __syncthreads in K-loops) ----
#define GROW1(lr) (8*wv + ((lr) < 8 ? (lr) : 24 + (lr)))
#define GROW2(lr) (16*wv + (lr))
#define SLDG(qq, s) { int krr = (s)*64 + GROW1(lrow); \
  const float* bs = (krr < 1024) ? (hTc + krr*32) : (ctxc + (krr-1024)*32); \
  qq##a = *(const float4*)(bs + scol2); qq##b = *(const float4*)(bs + scol2 + 4); }
#define SLDS(qq, s) { int krr = (s)*64 + GROW2(lrow); \
  const float* bs = (krr < 1024) ? (hTn + krr*32) : (ctxc + (krr-1024)*32); \
  qq##a = *(const float4*)(bs + scol2); qq##b = *(const float4*)(bs + scol2 + 4); }
#define STW(qq, BUF) { float* d = Sw + (BUF)*576 + lrow*36 + scol2; \
  *(float4*)d = qq##a; *(float4*)(d+4) = qq##b; }
#define COMPG(sl, BUF) { const float* Sb = Sw + (BUF)*576; \
  _Pragma("unroll") for (int i = 0; i < 2; ++i) { \
    float w0 = Wg[jl0*2052 + (sl)*64 + i*32 + kkg]; \
    float w1 = Wg[jl1*2052 + (sl)*64 + i*32 + kkg]; \
    const float* sp = Sb + (i*8 + kkl)*36; \
    _Pragma("unroll") for (int q = 0; q < 8; ++q) { \
      float4 s4 = *(const float4*)(sp + q*4); \
      a0[q*4+0] += w0*s4.x; a0[q*4+1] += w0*s4.y; a0[q*4+2] += w0*s4.z; a0[q*4+3] += w0*s4.w; \
      a1[q*4+0] += w1*s4.x; a1[q*4+1] += w1*s4.y; a1[q*4+2] += w1*s4.z; a1[q*4+3] += w1*s4.w; } } }
#define COMPS(sl, BUF) { const float* sp = Sw + (BUF)*576 + lrow*36; \
  float w0 = ws0[sl], w1 = ws1[sl]; \
  _Pragma("unroll") for (int q = 0; q < 8; ++q) { \
    float4 s4 = *(const float4*)(sp + q*4); \
    a0[q*4+0] += w0*s4.x; a0[q*4+1] += w0*s4.y; a0[q*4+2] += w0*s4.z; a0[q*4+3] += w0*s4.w; \
    a1[q*4+0] += w1*s4.x; a1[q*4+1] += w1*s4.y; a1[q*4+2] += w1*s4.z; a1[q*4+3] += w1*s4.w; } }

// ---------------- persistent decoder: wave-private K-loops, distributed attend ----------
// Dynamic LDS (floats): Wg 16x2052=32832 | S2 4x2x576=4608 | pacc 2048 | g_lds 512 = 160000 B
__global__ __launch_bounds__(256, 1) void decoder_persistent(
    const float* __restrict__ basep, const float* __restrict__ tagp,
    const float* __restrict__ dWhh,  const float* __restrict__ dWih,
    const float* __restrict__ Wout,  const float* __restrict__ bout,
    const float* __restrict__ projo, const float* __restrict__ outbuf,
    const int* __restrict__ mask,
    float* __restrict__ hT,          // [2][1024][32]
    float* __restrict__ ctxT,        // [2][1024][32]
    float* __restrict__ hrow,        // [32][1024]
    unsigned long long* __restrict__ argslot,
    unsigned* __restrict__ dslots, unsigned* __restrict__ dflags,
    float* __restrict__ out)
{
  extern __shared__ float dyn[];
  float* Wg    = dyn;           // 32832
  float* S2    = dyn + 32832;   // 4608 (wave-private: wv*1152 + buf*576)
  float* pacc  = dyn + 37440;   // 2048
  float* g_lds = dyn + 39488;   // 512

  const int blk = blockIdx.x, tid = threadIdx.x;
  const int lane = tid & 63, wv = tid >> 6;
  const int hibase = blk * 4;
  const int jj = lane & 7, kkl = lane >> 3;
  const int kkg = 8*wv + kkl;
  const int jl0 = jj*2, jl1 = jj*2 + 1;
  const int vv = tid & 3, kq = tid >> 2;
  const int vbase = blk * 8;
  const int lrow = lane >> 2, scol2 = (lane & 3) * 8;
  const int ab = blk >> 3, aslice = blk & 7;
  float* Sw = S2 + wv*1152;

  // ---- preload gates weights into LDS (once) ----
  for (int jl = 0; jl < 16; ++jl) {
    int j = (jl>>2)*1024 + hibase + (jl&3);
    #pragma unroll
    for (int r = 0; r < 2; ++r) {
      int c = tid*4 + r*1024;
      float4 w;
      if (c < 1024) w = *(const float4*)(dWhh + (size_t)j*1024 + c);
      else          w = *(const float4*)(dWih + (size_t)j*2560 + 512 + (c - 1024));
      *(float4*)&Wg[jl*2052 + c] = w;
    }
  }
  // ---- scores weights in registers (64 floats/thread) ----
  float ws0[32], ws1[32];
  {
    int v0 = vbase + vv*2;
    #pragma unroll
    for (int s2 = 0; s2 < 32; ++s2) {
      ws0[s2] = Wout[(size_t)(v0+0)*2048 + s2*64 + kq];
      ws1[s2] = Wout[(size_t)(v0+1)*2048 + s2*64 + kq];
    }
  }

  float c_reg = 0.f;
  int bslot = 0;

  // ---- prologue: ctx(0) = attend(last_output), distributed over all 256 blocks ----
  {
    int len = -1;
    for (int i = 0; i < T; ++i) len += mask[ab*T + i];
    attend_slice(ab, aslice, outbuf + (size_t)(ab*T + len)*H2, ctxT,
                 outbuf, projo, mask, pacc, tid);
  }
  pbar(dslots + (bslot)*256, dflags + (bslot)*256, blk, 256); bslot++;

  for (int t = 0; t < T; ++t) {
    const int cur = t & 1, nxt = cur ^ 1;
    const float* hTc  = hT + cur*32768;
    float*       hTn  = hT + nxt*32768;
    const float* ctxc = ctxT + cur*32768;
    float*       ctxn = ctxT + nxt*32768;

    // prefetch per-thread external gate contributions (base + tag embed proj)
    const int b_own = tid & 31;
    const int jlA = tid >> 5, jlB = jlA + 8;
    const int jA = (jlA>>2)*1024 + hibase + (jlA&3);
    const int jB = (jlB>>2)*1024 + hibase + (jlB&3);
    float extA = basep[(size_t)(b_own*T + t)*G4 + jA];
    float extB = basep[(size_t)(b_own*T + t)*G4 + jB];
    if (t > 0) {
      unsigned long long sl64 = __hip_atomic_load(&argslot[((t+2)%3)*32 + b_own],
                                                  __ATOMIC_RELAXED, __HIP_MEMORY_SCOPE_AGENT);
      unsigned tg = ~(unsigned)sl64;
      extA += tagp[(size_t)tg*G4 + jA];
      extB += tagp[(size_t)tg*G4 + jB];
    }

    // ===== phase 1: gates (K=2048: h | ctx), wave-private staging, no K-loop syncs =====
    float a0[32], a1[32];
    #pragma unroll
    for (int q = 0; q < 32; ++q) { a0[q] = 0.f; a1[q] = 0.f; }
    {
      float4 q0a,q0b,q1a,q1b,q2a,q2b,q3a,q3b;
      SLDG(q0, 0) SLDG(q1, 1) SLDG(q2, 2) SLDG(q3, 3)
      STW(q0, 0)
      for (int g = 0; g < 8; ++g) {
        const int sl = g*4;
        if (sl+4 < 32) SLDG(q0, sl+4)
        COMPG(sl, 0)
        STW(q1, 1)
        if (sl+5 < 32) SLDG(q1, sl+5)
        COMPG(sl+1, 1)
        STW(q2, 0)
        if (sl+6 < 32) SLDG(q2, sl+6)
        COMPG(sl+2, 0)
        STW(q3, 1)
        if (sl+7 < 32) SLDG(q3, sl+7)
        COMPG(sl+3, 1)
        if (sl+4 < 32) STW(q0, 0)
      }
    }
    #pragma unroll
    for (int dd = 8; dd <= 32; dd <<= 1) {
      #pragma unroll
      for (int q = 0; q < 32; ++q) {
        a0[q] += __shfl_down(a0[q], dd, 64);
        a1[q] += __shfl_down(a1[q], dd, 64);
      }
    }
    if (lane < 8) {
      float* pw = &pacc[wv*512 + lane*64];
      #pragma unroll
      for (int q = 0; q < 32; ++q) { pw[q] = a0[q]; pw[32+q] = a1[q]; }
    }
    __syncthreads();
    #pragma unroll
    for (int r = 0; r < 2; ++r) {
      int o = tid + r*256;
      int jl = o >> 5, b = o & 31;
      int off = (jl>>1)*64 + (jl&1)*32 + b;
      float vsum = pacc[off] + pacc[512+off] + pacc[1024+off] + pacc[1536+off];
      vsum += (r == 0) ? extA : extB;
      g_lds[jl*32 + b] = vsum;
    }
    __syncthreads();
    if (tid < 128) {
      int hil = tid >> 5, b = tid & 31;
      float gi = g_lds[(0*4+hil)*32 + b];
      float gf = g_lds[(1*4+hil)*32 + b];
      float gg = g_lds[(2*4+hil)*32 + b];
      float go = g_lds[(3*4+hil)*32 + b];
      c_reg = sigm(gf)*c_reg + sigm(gi)*tanhf(gg);
      float h = sigm(go)*tanhf(c_reg);
      int hi = hibase + hil;
      st_wt(&hTn[hi*32 + b], h);
      st_wt(&hrow[b*1024 + hi], h);
    }
    pbar(dslots + (bslot)*256, dflags + (bslot)*256, blk, 256); bslot++;

    // ===== phase 2: scores (K=2048: h_new | ctx_old), wave-private staging =====
    #pragma unroll
    for (int q = 0; q < 32; ++q) { a0[q] = 0.f; a1[q] = 0.f; }
    {
      float4 q0a,q0b,q1a,q1b,q2a,q2b,q3a,q3b;
      SLDS(q0, 0) SLDS(q1, 1) SLDS(q2, 2) SLDS(q3, 3)
      STW(q0, 0)
      #pragma unroll
      for (int g = 0; g < 8; ++g) {
        const int sl = g*4;
        if (sl+4 < 32) SLDS(q0, sl+4)
        COMPS(sl, 0)
        STW(q1, 1)
        if (sl+5 < 32) SLDS(q1, sl+5)
        COMPS(sl+1, 1)
        STW(q2, 0)
        if (sl+6 < 32) SLDS(q2, sl+6)
        COMPS(sl+2, 0)
        STW(q3, 1)
        if (sl+7 < 32) SLDS(q3, sl+7)
        COMPS(sl+3, 1)
        if (sl+4 < 32) STW(q0, 0)
      }
    }
    #pragma unroll
    for (int dd = 4; dd <= 32; dd <<= 1) {
      #pragma unroll
      for (int q = 0; q < 32; ++q) {
        a0[q] += __shfl_down(a0[q], dd, 64);
        a1[q] += __shfl_down(a1[q], dd, 64);
      }
    }
    if (lane < 4) {
      float* pw = &pacc[wv*256 + lane*64];
      #pragma unroll
      for (int q = 0; q < 32; ++q) { pw[q] = a0[q]; pw[32+q] = a1[q]; }
    }
    __syncthreads();
    {
      int vl = tid & 7, b = tid >> 3;
      int off = (vl>>1)*64 + (vl&1)*32 + b;
      float s = pacc[off] + pacc[256+off] + pacc[512+off] + pacc[768+off];
      s += bout[vbase + vl];
      st_wt(&out[(size_t)(b*T + t)*V + vbase + vl], s);
      g_lds[vl*32 + b] = s;
    }
    __syncthreads();
    if (tid < 32) {
      int b = tid;
      float best = g_lds[b]; int bi = 0;
      #pragma unroll
      for (int vl = 1; vl < 8; ++vl) {
        float s = g_lds[vl*32 + b];
        if (s > best) { best = s; bi = vl; }
      }
      unsigned long long e = ((unsigned long long)fenc(best) << 32)
                           | (unsigned long long)(unsigned)(~(unsigned)(vbase + bi));
      atomicMax(&argslot[(t%3)*32 + b], e);
    } else if (blk == 0 && tid >= 32 && tid < 64) {
      __hip_atomic_store(&argslot[((t+1)%3)*32 + (tid - 32)], 0ull,
                         __ATOMIC_RELAXED, __HIP_MEMORY_SCOPE_AGENT);
    }
    if (t < 63) {
      __syncthreads();
      attend_slice(ab, aslice, hrow + ab*1024, ctxn, outbuf, projo, mask, pacc, tid);
    }
    pbar(dslots + (bslot)*256, dflags + (bslot)*256, blk, 256); bslot++;
  }
}

// ---------------- host launch ----------------
extern "C" void kernel_launch(void* const* d_in, const int* in_sizes, int n_in,
                              void* d_out, int out_size, void* d_ws, size_t ws_size,
                              hipStream_t stream)
{
  (void)in_sizes; (void)n_in; (void)out_size; (void)ws_size;
  const float* emb    = (const float*)d_in[0];
  const int*   mask   = (const int*)d_in[1];
  const float* Wih_f  = (const float*)d_in[2];
  const float* Whh_f  = (const float*)d_in[3];
  const float* bih_f  = (const float*)d_in[4];
  const float* bhh_f  = (const float*)d_in[5];
  const float* Wih_b  = (const float*)d_in[6];
  const float* Whh_b  = (const float*)d_in[7];
  const float* bih_b  = (const float*)d_in[8];
  const float* bhh_b  = (const float*)d_in[9];
  const float* attnW  = (const float*)d_in[10];
  const float* tagemb = (const float*)d_in[12];
  const float* dWih   = (const float*)d_in[13];
  const float* dWhh   = (const float*)d_in[14];
  const float* dbih   = (const float*)d_in[15];
  const float* dbhh   = (const float*)d_in[16];
  const float* Wout   = (const float*)d_in[17];
  const float* bout   = (const float*)d_in[18];
  float* out = (float*)d_out;

  float* ws = (float*)d_ws;
  float* xg_f   = ws + 0;          // 4194304
  float* xg_b   = ws + 4194304;    // 4194304
  float* outbuf = ws + 8388608;    // 2097152
  float* projo  = ws + 10485760;   // 2097152
  float* basep  = ws + 12582912;   // 8388608
  float* tagp   = ws + 20971520;   // 8388608
  // --- zeroed state block ---
  float* hT     = ws + 29360128;   // 65536  [2][1024][32]
  float* ctxT   = ws + 29425664;   // 65536  [2][1024][32]
  float* hrow   = ws + 29491200;   // 32768
  float* hencT  = ws + 29523968;   // 65536  [2][2][512][32]
  unsigned long long* argslot = (unsigned long long*)(ws + 29589504);  // 96 u64 (192 fl)
  unsigned* dslots = (unsigned*)(ws + 29589696);   // 129*256 = 33024 u32
  unsigned* dflags = (unsigned*)(ws + 29622720);   // 129*256 = 33024 u32
  unsigned* eslots = (unsigned*)(ws + 29655744);   // 128*128 = 16384 u32
  unsigned* eflags = (unsigned*)(ws + 29672128);   // 128*256 = 32768 u32
  // end: 29704896 floats

  // allow 160000 B dynamic LDS for the decoder
  (void)hipFuncSetAttribute((const void*)decoder_persistent,
                            hipFuncAttributeMaxDynamicSharedMemorySize, 160000);

  // zero all persistent-kernel state every call (graph-replay deterministic)
  hipMemsetAsync((void*)(ws + 29360128), 0, (size_t)(29704896 - 29360128) * sizeof(float), stream);

  // xg = emb @ Wih^T + bih + bhh   (M=2048, N=2048, K=512)
  gemm_nt<<<dim3(32, 16), 256, 0, stream>>>(emb, 512, Wih_f, 512, xg_f, 2048, bih_f, bhh_f, 512);
  gemm_nt<<<dim3(32, 16), 256, 0, stream>>>(emb, 512, Wih_b, 512, xg_b, 2048, bih_b, bhh_b, 512);
  // tagp = tag_embed @ dec_Wih[:, :512]^T   (M=2048, N=4096, K=512)
  gemm_nt<<<dim3(64, 16), 256, 0, stream>>>(tagemb, 512, dWih, DEC_IN, tagp, G4, nullptr, nullptr, 512);
  // encoder scan (persistent, register-resident Whh)
  encoder_persistent<<<256, 256, 0, stream>>>(xg_f, xg_b, Whh_f, Whh_b, mask, hencT, outbuf, eslots, eflags);
  // projo[bt,d] = sum_e attn_W[d,e]*output[bt,e]   (M=2048, N=1024, K=1024)
  gemm_nt<<<dim3(16, 16), 256, 0, stream>>>(outbuf, H2, attnW, H2, projo, H2, nullptr, nullptr, H2);
  // basep = aligned @ dec_Wih[:,1536:]^T + dbih + dbhh   (M=2048, N=4096, K=1024)
  gemm_nt<<<dim3(64, 16), 256, 0, stream>>>(outbuf, H2, dWih + 1536, DEC_IN, basep, G4, dbih, dbhh, H2);
  // persistent decoder (WB-free barriers, write-through state)
  decoder_persistent<<<256, 256, 160000, stream>>>(basep, tagp, dWhh, dWih, Wout, bout,
                                                   projo, outbuf, mask, hT, ctxT, hrow,
                                                   argslot, dslots, dflags, out);
}

// Round 12
// 4757.086 us; speedup vs baseline: 2.7600x; 1.0471x over previous
//
#include <hip/hip_runtime.h>

#define B   32
#define T   64
#define D   512
#define H   512
#define H2  1024
#define G4  4096
#define V   2048
#define DEC_IN 2560

__device__ __forceinline__ float sigm(float x) { return 1.f / (1.f + expf(-x)); }

__device__ __forceinline__ unsigned fenc(float f) {
  unsigned u = __float_as_uint(f);
  return (u & 0x80000000u) ? ~u : (u | 0x80000000u);
}

__device__ __forceinline__ void st_wt(float* p, float v) {       // write-through (L3-visible on retire)
  __hip_atomic_store(p, v, __ATOMIC_RELAXED, __HIP_MEMORY_SCOPE_AGENT);
}

// ---- store-based grid barrier, WB-free (R11-proven) ----
__device__ __forceinline__ void pbar(unsigned* slots, unsigned* flags, int myid, int nblk) {
  __syncthreads();   // drains each wave's vmcnt -> all write-through stores L3-visible
  if (threadIdx.x == 0)
    __hip_atomic_store(slots + myid, 1u, __ATOMIC_RELAXED, __HIP_MEMORY_SCOPE_AGENT);
  if (myid == 0) {
    for (int s = threadIdx.x; s < nblk; s += 256) {
      while (!__hip_atomic_load(slots + s, __ATOMIC_RELAXED, __HIP_MEMORY_SCOPE_AGENT))
        __builtin_amdgcn_s_sleep(1);
    }
    __syncthreads();
    if (threadIdx.x < 16)
      __hip_atomic_store(flags + threadIdx.x*16, 1u, __ATOMIC_RELAXED, __HIP_MEMORY_SCOPE_AGENT);
  }
  if (threadIdx.x == 0) {
    unsigned* f = flags + (myid & 15)*16;
    while (!__hip_atomic_load(f, __ATOMIC_RELAXED, __HIP_MEMORY_SCOPE_AGENT))
      __builtin_amdgcn_s_sleep(1);
    (void)__hip_atomic_load(f, __ATOMIC_ACQUIRE, __HIP_MEMORY_SCOPE_AGENT);  // L2 INV only
  }
  __syncthreads();
}

// ---------------- generic fp32 GEMM ----------------
__global__ __launch_bounds__(256) void gemm_nt(
    const float* __restrict__ A, int lda,
    const float* __restrict__ W, int ldw,
    float* __restrict__ C, int ldc,
    const float* __restrict__ bias0, const float* __restrict__ bias1,
    int K)
{
  __shared__ float As[16][132];
  __shared__ float Ws[16][68];
  const int tid = threadIdx.x;
  const int nb = blockIdx.x * 64;
  const int mb = blockIdx.y * 128;
  const int tx = tid & 15;
  const int ty = tid >> 4;
  float acc[8][4] = {};

  const int am = tid >> 1, ak = (tid & 1) * 8;
  const int wn = tid >> 2, wk = (tid & 3) * 4;
  const float* aptr = A + (size_t)(mb + am) * lda + ak;
  const float* wptr = W + (size_t)(nb + wn) * ldw + wk;

  for (int k0 = 0; k0 < K; k0 += 16) {
    float4 u = *(const float4*)(aptr + k0);
    float4 v = *(const float4*)(aptr + k0 + 4);
    float4 w = *(const float4*)(wptr + k0);
    As[ak+0][am] = u.x; As[ak+1][am] = u.y; As[ak+2][am] = u.z; As[ak+3][am] = u.w;
    As[ak+4][am] = v.x; As[ak+5][am] = v.y; As[ak+6][am] = v.z; As[ak+7][am] = v.w;
    Ws[wk+0][wn] = w.x; Ws[wk+1][wn] = w.y; Ws[wk+2][wn] = w.z; Ws[wk+3][wn] = w.w;
    __syncthreads();
    #pragma unroll
    for (int k = 0; k < 16; ++k) {
      float4 a0 = *(const float4*)&As[k][ty*8];
      float4 a1 = *(const float4*)&As[k][ty*8+4];
      float4 wv = *(const float4*)&Ws[k][tx*4];
      float av[8] = {a0.x,a0.y,a0.z,a0.w,a1.x,a1.y,a1.z,a1.w};
      #pragma unroll
      for (int i = 0; i < 8; ++i) {
        acc[i][0] += av[i]*wv.x; acc[i][1] += av[i]*wv.y;
        acc[i][2] += av[i]*wv.z; acc[i][3] += av[i]*wv.w;
      }
    }
    __syncthreads();
  }
  float b4[4];
  #pragma unroll
  for (int j = 0; j < 4; ++j) {
    float bv = 0.f;
    if (bias0) bv += bias0[nb + tx*4 + j];
    if (bias1) bv += bias1[nb + tx*4 + j];
    b4[j] = bv;
  }
  #pragma unroll
  for (int i = 0; i < 8; ++i) {
    float4 o;
    o.x = acc[i][0] + b4[0]; o.y = acc[i][1] + b4[1];
    o.z = acc[i][2] + b4[2]; o.w = acc[i][3] + b4[3];
    *(float4*)&C[(size_t)(mb + ty*8 + i) * ldc + nb + tx*4] = o;
  }
}

// ---------------- distributed attention: block (ab, aslice) -> ctx slice ----------------
__device__ void attend_slice(int ab, int aslice, const float* __restrict__ hvec,
                             float* __restrict__ ctxdst,
                             const float* __restrict__ outbuf, const float* __restrict__ projo,
                             const int* __restrict__ mask, float* scratch, int tid)
{
  float* scp = scratch;        // 256
  float* scv = scratch + 256;  // 64
  float* p2  = scratch + 320;  // 128
  const int tq = tid >> 2, dq = tid & 3;
  const float4* hv = (const float4*)(hvec + dq*256);
  const float4* pv = (const float4*)(projo + (size_t)(ab*T + tq)*H2 + dq*256);
  float p = 0.f;
  #pragma unroll 8
  for (int k4 = 0; k4 < 64; ++k4) {
    float4 a = hv[k4], q = pv[k4];
    p += a.x*q.x + a.y*q.y + a.z*q.z + a.w*q.w;
  }
  scp[tid] = p;
  __syncthreads();
  if (tid < 64) {
    float v = scp[tid*4] + scp[tid*4+1] + scp[tid*4+2] + scp[tid*4+3];
    float mx = v;
    #pragma unroll
    for (int d = 32; d; d >>= 1) mx = fmaxf(mx, __shfl_xor(mx, d, 64));
    float e = expf(v - mx);
    float sm = e;
    #pragma unroll
    for (int d = 32; d; d >>= 1) sm += __shfl_xor(sm, d, 64);
    scv[tid] = e * (1.f / sm) * (float)mask[ab*T + tid];
  }
  __syncthreads();
  {
    const int dl = tid & 127, th = tid >> 7;
    const int dg = aslice*128 + dl;
    float acc = 0.f;
    #pragma unroll 8
    for (int q = 0; q < 32; ++q) {
      int tt = th*32 + q;
      acc += scv[tt] * outbuf[(size_t)(ab*T + tt)*H2 + dg];
    }
    if (th == 1) p2[dl] = acc;
    __syncthreads();
    if (th == 0) st_wt(&ctxdst[dg*32 + ab], acc + p2[dl]);
  }
}

// ---------------- persistent encoder ----------
__global__ __launch_bounds__(256, 1) void encoder_persistent(
    const float* __restrict__ xg_f, const float* __restrict__ xg_b,
    const float* __restrict__ Whh_f, const float* __restrict__ Whh_b,
    const int* __restrict__ mask,
    float* __restrict__ hencT,    // [dir][2][512][32]
    float* __restrict__ outbuf,
    unsigned* __restrict__ eslots, unsigned* __restrict__ eflags)
{
  __shared__ float S_lds[2][128*36];
  __shared__ float pacc[2048];
  __shared__ float g_lds[512];
  const int blk = blockIdx.x, tid = threadIdx.x;
  const int lane = tid & 63, wv = tid >> 6;
  const int dir = blk >> 7, nd = blk & 127;
  const int hibase = nd * 4;
  const int jj = tid & 7, kk = tid >> 3;
  const float* xg  = dir ? xg_b : xg_f;
  const float* Whh = dir ? Whh_b : Whh_f;
  float* hbase = hencT + dir * 32768;

  float wge[2][16];
  #pragma unroll
  for (int p = 0; p < 2; ++p) {
    int jl = jj*2 + p;
    int j = (jl>>2)*512 + hibase + (jl&3);
    #pragma unroll
    for (int sc = 0; sc < 4; ++sc)
      #pragma unroll
      for (int i = 0; i < 4; ++i)
        wge[p][sc*4+i] = Whh[(size_t)j*512 + sc*128 + i*32 + kk];
  }
  float c_reg = 0.f;
  const int kr = tid >> 1, bh = (tid & 1) * 16;

  for (int tt = 0; tt < 64; ++tt) {
    const int t = dir ? (63 - tt) : tt;
    const float* hc = hbase + (tt & 1) * 16384;
    float* hn = hbase + ((tt + 1) & 1) * 16384;

    float a0[32], a1[32];
    #pragma unroll
    for (int q = 0; q < 32; ++q) { a0[q] = 0.f; a1[q] = 0.f; }

    float4 rr0, rr1, rr2, rr3;
    {
      const float4* p = (const float4*)(hc + kr*32 + bh);
      rr0 = p[0]; rr1 = p[1]; rr2 = p[2]; rr3 = p[3];
      float* d = &S_lds[0][kr*36 + bh];
      *(float4*)d = rr0; *(float4*)(d+4) = rr1; *(float4*)(d+8) = rr2; *(float4*)(d+12) = rr3;
    }
    __syncthreads();
    #pragma unroll
    for (int sc = 0; sc < 4; ++sc) {
      if (sc < 3) {
        const float4* p = (const float4*)(hc + (sc+1)*4096 + kr*32 + bh);
        rr0 = p[0]; rr1 = p[1]; rr2 = p[2]; rr3 = p[3];
      }
      const float* Sb = &S_lds[sc & 1][0];
      #pragma unroll
      for (int i = 0; i < 4; ++i) {
        const float* sp = Sb + (i*32 + kk)*36;
        float w0 = wge[0][sc*4+i], w1 = wge[1][sc*4+i];
        #pragma unroll
        for (int q = 0; q < 8; ++q) {
          float4 s4 = *(const float4*)(sp + q*4);
          a0[q*4+0] += w0*s4.x; a0[q*4+1] += w0*s4.y; a0[q*4+2] += w0*s4.z; a0[q*4+3] += w0*s4.w;
          a1[q*4+0] += w1*s4.x; a1[q*4+1] += w1*s4.y; a1[q*4+2] += w1*s4.z; a1[q*4+3] += w1*s4.w;
        }
      }
      if (sc < 3) {
        float* d = &S_lds[(sc+1) & 1][kr*36 + bh];
        *(float4*)d = rr0; *(float4*)(d+4) = rr1; *(float4*)(d+8) = rr2; *(float4*)(d+12) = rr3;
      }
      __syncthreads();
    }
    #pragma unroll
    for (int dd = 8; dd <= 32; dd <<= 1) {
      #pragma unroll
      for (int q = 0; q < 32; ++q) {
        a0[q] += __shfl_down(a0[q], dd, 64);
        a1[q] += __shfl_down(a1[q], dd, 64);
      }
    }
    if (lane < 8) {
      float* pw = &pacc[wv*512 + lane*64];
      #pragma unroll
      for (int q = 0; q < 32; ++q) { pw[q] = a0[q]; pw[32+q] = a1[q]; }
    }
    __syncthreads();
    #pragma unroll
    for (int r = 0; r < 2; ++r) {
      int o = tid + r*256;
      int jl = o >> 5, b = o & 31;
      int off = (jl>>1)*64 + (jl&1)*32 + b;
      float v = pacc[off] + pacc[512+off] + pacc[1024+off] + pacc[1536+off];
      v += xg[(size_t)(b*T + t)*2048 + (jl>>2)*512 + hibase + (jl&3)];
      g_lds[jl*32 + b] = v;
    }
    __syncthreads();
    if (tid < 128) {
      int hil = tid >> 5, b = tid & 31;
      float gi = g_lds[(0*4+hil)*32 + b];
      float gf = g_lds[(1*4+hil)*32 + b];
      float gg = g_lds[(2*4+hil)*32 + b];
      float go = g_lds[(3*4+hil)*32 + b];
      c_reg = sigm(gf)*c_reg + sigm(gi)*tanhf(gg);
      float h = sigm(go)*tanhf(c_reg);
      int hi = hibase + hil;
      st_wt(&hn[hi*32 + b], h);
      st_wt(&outbuf[(size_t)(b*T + t)*H2 + dir*512 + hi], h * (float)mask[b*T + t]);
    }
    pbar(eslots + (dir*64 + tt)*128, eflags + (dir*64 + tt)*256, nd, 128);
  }
}

// ---- decoder macros: wave-private staging (NO __syncthreads in K-loops) ----
#define GROW1(lr) (8*wv + ((lr) < 8 ? (lr) : 24 + (lr)))
#define GROW2(lr) (16*wv + (lr))
#define SLDG(qq, s) { int krr = (s)*64 + GROW1(lrow); \
  const float* bs = (krr < 1024) ? (hTc + krr*32) : (ctxc + (krr-1024)*32); \
  qq##a = *(const float4*)(bs + scol2); qq##b = *(const float4*)(bs + scol2 + 4); }
#define SLDS(qq, s) { int krr = (s)*64 + GROW2(lrow); \
  const float* bs = (krr < 1024) ? (hTn + krr*32) : (ctxc + (krr-1024)*32); \
  qq##a = *(const float4*)(bs + scol2); qq##b = *(const float4*)(bs + scol2 + 4); }
#define STW(qq, BUF) { float* d = Sw + (BUF)*576 + lrow*36 + scol2; \
  *(float4*)d = qq##a; *(float4*)(d+4) = qq##b; }
#define COMPG(sl, BUF) { const float* Sb = Sw + (BUF)*576; \
  _Pragma("unroll") for (int i = 0; i < 2; ++i) { \
    float w0 = Wg[jl0*2052 + (sl)*64 + i*32 + kkg]; \
    float w1 = Wg[jl1*2052 + (sl)*64 + i*32 + kkg]; \
    const float* sp = Sb + (i*8 + kkl)*36; \
    _Pragma("unroll") for (int q = 0; q < 8; ++q) { \
      float4 s4 = *(const float4*)(sp + q*4); \
      a0[q*4+0] += w0*s4.x; a0[q*4+1] += w0*s4.y; a0[q*4+2] += w0*s4.z; a0[q*4+3] += w0*s4.w; \
      a1[q*4+0] += w1*s4.x; a1[q*4+1] += w1*s4.y; a1[q*4+2] += w1*s4.z; a1[q*4+3] += w1*s4.w; } } }
#define COMPS(sl, BUF) { const float* sp = Sw + (BUF)*576 + lrow*36; \
  float w0 = ws0[sl], w1 = ws1[sl]; \
  _Pragma("unroll") for (int q = 0; q < 8; ++q) { \
    float4 s4 = *(const float4*)(sp + q*4); \
    a0[q*4+0] += w0*s4.x; a0[q*4+1] += w0*s4.y; a0[q*4+2] += w0*s4.z; a0[q*4+3] += w0*s4.w; \
    a1[q*4+0] += w1*s4.x; a1[q*4+1] += w1*s4.y; a1[q*4+2] += w1*s4.z; a1[q*4+3] += w1*s4.w; } }

// ---------------- persistent decoder: wave-private K-loops, XCD-localized attend --------
// Dynamic LDS (floats): Wg 16x2052=32832 | S2 4x2x576=4608 | pacc 2048 | g_lds 512 = 160000 B
__global__ __launch_bounds__(256, 1) void decoder_persistent(
    const float* __restrict__ basep, const float* __restrict__ tagp,
    const float* __restrict__ dWhh,  const float* __restrict__ dWih,
    const float* __restrict__ Wout,  const float* __restrict__ bout,
    const float* __restrict__ projo, const float* __restrict__ outbuf,
    const int* __restrict__ mask,
    float* __restrict__ hT,          // [2][1024][32]
    float* __restrict__ ctxT,        // [2][1024][32]
    float* __restrict__ hrow,        // [32][1024]
    unsigned long long* __restrict__ argslot,
    unsigned* __restrict__ dslots, unsigned* __restrict__ dflags,
    float* __restrict__ out)
{
  extern __shared__ float dyn[];
  float* Wg    = dyn;           // 32832
  float* S2    = dyn + 32832;   // 4608 (wave-private: wv*1152 + buf*576)
  float* pacc  = dyn + 37440;   // 2048
  float* g_lds = dyn + 39488;   // 512

  const int blk = blockIdx.x, tid = threadIdx.x;
  const int lane = tid & 63, wv = tid >> 6;
  const int hibase = blk * 4;
  const int jj = lane & 7, kkl = lane >> 3;
  const int kkg = 8*wv + kkl;
  const int jl0 = jj*2, jl1 = jj*2 + 1;
  const int vv = tid & 3, kq = tid >> 2;
  const int vbase = blk * 8;
  const int lrow = lane >> 2, scol2 = (lane & 3) * 8;
  // XCD-localized attend mapping: blocks {ab + 32*aslice} share blk%8 == ab%8 -> same XCD,
  // so the 8 slice-blocks of batch row ab share one L2's projo[ab] panel.
  const int ab = blk & 31, aslice = blk >> 5;
  float* Sw = S2 + wv*1152;

  // ---- preload gates weights into LDS (once) ----
  for (int jl = 0; jl < 16; ++jl) {
    int j = (jl>>2)*1024 + hibase + (jl&3);
    #pragma unroll
    for (int r = 0; r < 2; ++r) {
      int c = tid*4 + r*1024;
      float4 w;
      if (c < 1024) w = *(const float4*)(dWhh + (size_t)j*1024 + c);
      else          w = *(const float4*)(dWih + (size_t)j*2560 + 512 + (c - 1024));
      *(float4*)&Wg[jl*2052 + c] = w;
    }
  }
  // ---- scores weights in registers (64 floats/thread) ----
  float ws0[32], ws1[32];
  {
    int v0 = vbase + vv*2;
    #pragma unroll
    for (int s2 = 0; s2 < 32; ++s2) {
      ws0[s2] = Wout[(size_t)(v0+0)*2048 + s2*64 + kq];
      ws1[s2] = Wout[(size_t)(v0+1)*2048 + s2*64 + kq];
    }
  }

  float c_reg = 0.f;
  int bslot = 0;

  // ---- prologue: ctx(0) = attend(last_output), distributed over all 256 blocks ----
  {
    int len = -1;
    for (int i = 0; i < T; ++i) len += mask[ab*T + i];
    attend_slice(ab, aslice, outbuf + (size_t)(ab*T + len)*H2, ctxT,
                 outbuf, projo, mask, pacc, tid);
  }
  pbar(dslots + (bslot)*256, dflags + (bslot)*256, blk, 256); bslot++;

  for (int t = 0; t < T; ++t) {
    const int cur = t & 1, nxt = cur ^ 1;
    const float* hTc  = hT + cur*32768;
    float*       hTn  = hT + nxt*32768;
    const float* ctxc = ctxT + cur*32768;
    float*       ctxn = ctxT + nxt*32768;

    // prefetch per-thread external gate contributions (base + tag embed proj)
    const int b_own = tid & 31;
    const int jlA = tid >> 5, jlB = jlA + 8;
    const int jA = (jlA>>2)*1024 + hibase + (jlA&3);
    const int jB = (jlB>>2)*1024 + hibase + (jlB&3);
    float extA = basep[(size_t)(b_own*T + t)*G4 + jA];
    float extB = basep[(size_t)(b_own*T + t)*G4 + jB];
    if (t > 0) {
      unsigned long long sl64 = __hip_atomic_load(&argslot[((t+2)%3)*32 + b_own],
                                                  __ATOMIC_RELAXED, __HIP_MEMORY_SCOPE_AGENT);
      unsigned tg = ~(unsigned)sl64;
      extA += tagp[(size_t)tg*G4 + jA];
      extB += tagp[(size_t)tg*G4 + jB];
    }

    // ===== phase 1: gates (K=2048: h | ctx), wave-private staging, no K-loop syncs =====
    float a0[32], a1[32];
    #pragma unroll
    for (int q = 0; q < 32; ++q) { a0[q] = 0.f; a1[q] = 0.f; }
    {
      float4 q0a,q0b,q1a,q1b,q2a,q2b,q3a,q3b;
      SLDG(q0, 0) SLDG(q1, 1) SLDG(q2, 2) SLDG(q3, 3)
      STW(q0, 0)
      for (int g = 0; g < 8; ++g) {
        const int sl = g*4;
        if (sl+4 < 32) SLDG(q0, sl+4)
        COMPG(sl, 0)
        STW(q1, 1)
        if (sl+5 < 32) SLDG(q1, sl+5)
        COMPG(sl+1, 1)
        STW(q2, 0)
        if (sl+6 < 32) SLDG(q2, sl+6)
        COMPG(sl+2, 0)
        STW(q3, 1)
        if (sl+7 < 32) SLDG(q3, sl+7)
        COMPG(sl+3, 1)
        if (sl+4 < 32) STW(q0, 0)
      }
    }
    #pragma unroll
    for (int dd = 8; dd <= 32; dd <<= 1) {
      #pragma unroll
      for (int q = 0; q < 32; ++q) {
        a0[q] += __shfl_down(a0[q], dd, 64);
        a1[q] += __shfl_down(a1[q], dd, 64);
      }
    }
    if (lane < 8) {
      float* pw = &pacc[wv*512 + lane*64];
      #pragma unroll
      for (int q = 0; q < 32; ++q) { pw[q] = a0[q]; pw[32+q] = a1[q]; }
    }
    __syncthreads();
    #pragma unroll
    for (int r = 0; r < 2; ++r) {
      int o = tid + r*256;
      int jl = o >> 5, b = o & 31;
      int off = (jl>>1)*64 + (jl&1)*32 + b;
      float vsum = pacc[off] + pacc[512+off] + pacc[1024+off] + pacc[1536+off];
      vsum += (r == 0) ? extA : extB;
      g_lds[jl*32 + b] = vsum;
    }
    __syncthreads();
    if (tid < 128) {
      int hil = tid >> 5, b = tid & 31;
      float gi = g_lds[(0*4+hil)*32 + b];
      float gf = g_lds[(1*4+hil)*32 + b];
      float gg = g_lds[(2*4+hil)*32 + b];
      float go = g_lds[(3*4+hil)*32 + b];
      c_reg = sigm(gf)*c_reg + sigm(gi)*tanhf(gg);
      float h = sigm(go)*tanhf(c_reg);
      int hi = hibase + hil;
      st_wt(&hTn[hi*32 + b], h);
      st_wt(&hrow[b*1024 + hi], h);
    }
    pbar(dslots + (bslot)*256, dflags + (bslot)*256, blk, 256); bslot++;

    // ===== phase 2: scores (K=2048: h_new | ctx_old), wave-private staging =====
    #pragma unroll
    for (int q = 0; q < 32; ++q) { a0[q] = 0.f; a1[q] = 0.f; }
    {
      float4 q0a,q0b,q1a,q1b,q2a,q2b,q3a,q3b;
      SLDS(q0, 0) SLDS(q1, 1) SLDS(q2, 2) SLDS(q3, 3)
      STW(q0, 0)
      #pragma unroll
      for (int g = 0; g < 8; ++g) {
        const int sl = g*4;
        if (sl+4 < 32) SLDS(q0, sl+4)
        COMPS(sl, 0)
        STW(q1, 1)
        if (sl+5 < 32) SLDS(q1, sl+5)
        COMPS(sl+1, 1)
        STW(q2, 0)
        if (sl+6 < 32) SLDS(q2, sl+6)
        COMPS(sl+2, 0)
        STW(q3, 1)
        if (sl+7 < 32) SLDS(q3, sl+7)
        COMPS(sl+3, 1)
        if (sl+4 < 32) STW(q0, 0)
      }
    }
    #pragma unroll
    for (int dd = 4; dd <= 32; dd <<= 1) {
      #pragma unroll
      for (int q = 0; q < 32; ++q) {
        a0[q] += __shfl_down(a0[q], dd, 64);
        a1[q] += __shfl_down(a1[q], dd, 64);
      }
    }
    if (lane < 4) {
      float* pw = &pacc[wv*256 + lane*64];
      #pragma unroll
      for (int q = 0; q < 32; ++q) { pw[q] = a0[q]; pw[32+q] = a1[q]; }
    }
    __syncthreads();
    {
      int vl = tid & 7, b = tid >> 3;
      int off = (vl>>1)*64 + (vl&1)*32 + b;
      float s = pacc[off] + pacc[256+off] + pacc[512+off] + pacc[768+off];
      s += bout[vbase + vl];
      st_wt(&out[(size_t)(b*T + t)*V + vbase + vl], s);
      g_lds[vl*32 + b] = s;
    }
    __syncthreads();
    if (tid < 32) {
      int b = tid;
      float best = g_lds[b]; int bi = 0;
      #pragma unroll
      for (int vl = 1; vl < 8; ++vl) {
        float s = g_lds[vl*32 + b];
        if (s > best) { best = s; bi = vl; }
      }
      unsigned long long e = ((unsigned long long)fenc(best) << 32)
                           | (unsigned long long)(unsigned)(~(unsigned)(vbase + bi));
      atomicMax(&argslot[(t%3)*32 + b], e);
    } else if (blk == 0 && tid >= 32 && tid < 64) {
      __hip_atomic_store(&argslot[((t+1)%3)*32 + (tid - 32)], 0ull,
                         __ATOMIC_RELAXED, __HIP_MEMORY_SCOPE_AGENT);
    }
    if (t < 63) {
      __syncthreads();
      attend_slice(ab, aslice, hrow + ab*1024, ctxn, outbuf, projo, mask, pacc, tid);
    }
    pbar(dslots + (bslot)*256, dflags + (bslot)*256, blk, 256); bslot++;
  }
}

// ---------------- host launch ----------------
extern "C" void kernel_launch(void* const* d_in, const int* in_sizes, int n_in,
                              void* d_out, int out_size, void* d_ws, size_t ws_size,
                              hipStream_t stream)
{
  (void)in_sizes; (void)n_in; (void)out_size; (void)ws_size;
  const float* emb    = (const float*)d_in[0];
  const int*   mask   = (const int*)d_in[1];
  const float* Wih_f  = (const float*)d_in[2];
  const float* Whh_f  = (const float*)d_in[3];
  const float* bih_f  = (const float*)d_in[4];
  const float* bhh_f  = (const float*)d_in[5];
  const float* Wih_b  = (const float*)d_in[6];
  const float* Whh_b  = (const float*)d_in[7];
  const float* bih_b  = (const float*)d_in[8];
  const float* bhh_b  = (const float*)d_in[9];
  const float* attnW  = (const float*)d_in[10];
  const float* tagemb = (const float*)d_in[12];
  const float* dWih   = (const float*)d_in[13];
  const float* dWhh   = (const float*)d_in[14];
  const float* dbih   = (const float*)d_in[15];
  const float* dbhh   = (const float*)d_in[16];
  const float* Wout   = (const float*)d_in[17];
  const float* bout   = (const float*)d_in[18];
  float* out = (float*)d_out;

  float* ws = (float*)d_ws;
  float* xg_f   = ws + 0;          // 4194304
  float* xg_b   = ws + 4194304;    // 4194304
  float* outbuf = ws + 8388608;    // 2097152
  float* projo  = ws + 10485760;   // 2097152
  float* basep  = ws + 12582912;   // 8388608
  float* tagp   = ws + 20971520;   // 8388608
  // --- zeroed state block ---
  float* hT     = ws + 29360128;   // 65536  [2][1024][32]
  float* ctxT   = ws + 29425664;   // 65536  [2][1024][32]
  float* hrow   = ws + 29491200;   // 32768
  float* hencT  = ws + 29523968;   // 65536  [2][2][512][32]
  unsigned long long* argslot = (unsigned long long*)(ws + 29589504);  // 96 u64 (192 fl)
  unsigned* dslots = (unsigned*)(ws + 29589696);   // 129*256 = 33024 u32
  unsigned* dflags = (unsigned*)(ws + 29622720);   // 129*256 = 33024 u32
  unsigned* eslots = (unsigned*)(ws + 29655744);   // 128*128 = 16384 u32
  unsigned* eflags = (unsigned*)(ws + 29672128);   // 128*256 = 32768 u32
  // end: 29704896 floats

  // allow 160000 B dynamic LDS for the decoder
  (void)hipFuncSetAttribute((const void*)decoder_persistent,
                            hipFuncAttributeMaxDynamicSharedMemorySize, 160000);

  // zero all persistent-kernel state every call (graph-replay deterministic)
  hipMemsetAsync((void*)(ws + 29360128), 0, (size_t)(29704896 - 29360128) * sizeof(float), stream);

  // xg = emb @ Wih^T + bih + bhh   (M=2048, N=2048, K=512)
  gemm_nt<<<dim3(32, 16), 256, 0, stream>>>(emb, 512, Wih_f, 512, xg_f, 2048, bih_f, bhh_f, 512);
  gemm_nt<<<dim3(32, 16), 256, 0, stream>>>(emb, 512, Wih_b, 512, xg_b, 2048, bih_b, bhh_b, 512);
  // tagp = tag_embed @ dec_Wih[:, :512]^T   (M=2048, N=4096, K=512)
  gemm_nt<<<dim3(64, 16), 256, 0, stream>>>(tagemb, 512, dWih, DEC_IN, tagp, G4, nullptr, nullptr, 512);
  // encoder scan (persistent, register-resident Whh)
  encoder_persistent<<<256, 256, 0, stream>>>(xg_f, xg_b, Whh_f, Whh_b, mask, hencT, outbuf, eslots, eflags);
  // projo[bt,d] = sum_e attn_W[d,e]*output[bt,e]   (M=2048, N=1024, K=1024)
  gemm_nt<<<dim3(16, 16), 256, 0, stream>>>(outbuf, H2, attnW, H2, projo, H2, nullptr, nullptr, H2);
  // basep = aligned @ dec_Wih[:,1536:]^T + dbih + dbhh   (M=2048, N=4096, K=1024)
  gemm_nt<<<dim3(64, 16), 256, 0, stream>>>(outbuf, H2, dWih + 1536, DEC_IN, basep, G4, dbih, dbhh, H2);
  // persistent decoder (XCD-localized attend)
  decoder_persistent<<<256, 256, 160000, stream>>>(basep, tagp, dWhh, dWih, Wout, bout,
                                                   projo, outbuf, mask, hT, ctxT, hrow,
                                                   argslot, dslots, dflags, out);
}

// Round 13
// 4728.736 us; speedup vs baseline: 2.7765x; 1.0060x over previous
//
#include <hip/hip_runtime.h>

#define B   32
#define T   64
#define D   512
#define H   512
#define H2  1024
#define G4  4096
#define V   2048
#define DEC_IN 2560

__device__ __forceinline__ float sigm(float x) { return 1.f / (1.f + expf(-x)); }

__device__ __forceinline__ unsigned fenc(float f) {
  unsigned u = __float_as_uint(f);
  return (u & 0x80000000u) ? ~u : (u | 0x80000000u);
}

__device__ __forceinline__ void st_wt(float* p, float v) {       // write-through (L3-visible on retire)
  __hip_atomic_store(p, v, __ATOMIC_RELAXED, __HIP_MEMORY_SCOPE_AGENT);
}

// ---- store-based grid barrier, WB-free (R11-proven) ----
__device__ __forceinline__ void pbar(unsigned* slots, unsigned* flags, int myid, int nblk) {
  __syncthreads();   // drains each wave's vmcnt -> all write-through stores L3-visible
  if (threadIdx.x == 0)
    __hip_atomic_store(slots + myid, 1u, __ATOMIC_RELAXED, __HIP_MEMORY_SCOPE_AGENT);
  if (myid == 0) {
    for (int s = threadIdx.x; s < nblk; s += 256) {
      while (!__hip_atomic_load(slots + s, __ATOMIC_RELAXED, __HIP_MEMORY_SCOPE_AGENT))
        __builtin_amdgcn_s_sleep(1);
    }
    __syncthreads();
    if (threadIdx.x < 16)
      __hip_atomic_store(flags + threadIdx.x*16, 1u, __ATOMIC_RELAXED, __HIP_MEMORY_SCOPE_AGENT);
  }
  if (threadIdx.x == 0) {
    unsigned* f = flags + (myid & 15)*16;
    while (!__hip_atomic_load(f, __ATOMIC_RELAXED, __HIP_MEMORY_SCOPE_AGENT))
      __builtin_amdgcn_s_sleep(1);
    (void)__hip_atomic_load(f, __ATOMIC_ACQUIRE, __HIP_MEMORY_SCOPE_AGENT);  // L2 INV only
  }
  __syncthreads();
}

// ---------------- fp32 GEMM: 128x128 tile, 8x8 micro-tile, BK=8 ----------------
// C[m,n] = sum_k A[m,k]*W[n,k] + bias0[n] + bias1[n]; grid = (N/128, M/128)
__global__ __launch_bounds__(256) void gemm_nt(
    const float* __restrict__ A, int lda,
    const float* __restrict__ W, int ldw,
    float* __restrict__ C, int ldc,
    const float* __restrict__ bias0, const float* __restrict__ bias1,
    int K)
{
  __shared__ float As[8][132];
  __shared__ float Bs[8][132];
  const int tid = threadIdx.x;
  const int nb = blockIdx.x * 128;
  const int mb = blockIdx.y * 128;
  const int tx = tid & 15;    // n: tx*8
  const int ty = tid >> 4;    // m: ty*8
  float acc[8][8] = {};

  const int am = tid >> 1, ak = (tid & 1) * 4;
  const float* aptr = A + (size_t)(mb + am) * lda + ak;
  const float* bptr = W + (size_t)(nb + am) * ldw + ak;

  for (int k0 = 0; k0 < K; k0 += 8) {
    float4 av = *(const float4*)(aptr + k0);
    float4 bv = *(const float4*)(bptr + k0);
    As[ak+0][am] = av.x; As[ak+1][am] = av.y; As[ak+2][am] = av.z; As[ak+3][am] = av.w;
    Bs[ak+0][am] = bv.x; Bs[ak+1][am] = bv.y; Bs[ak+2][am] = bv.z; Bs[ak+3][am] = bv.w;
    __syncthreads();
    #pragma unroll
    for (int k = 0; k < 8; ++k) {
      float4 a0 = *(const float4*)&As[k][ty*8];
      float4 a1 = *(const float4*)&As[k][ty*8+4];
      float4 b0 = *(const float4*)&Bs[k][tx*8];
      float4 b1 = *(const float4*)&Bs[k][tx*8+4];
      float avv[8] = {a0.x,a0.y,a0.z,a0.w,a1.x,a1.y,a1.z,a1.w};
      float bvv[8] = {b0.x,b0.y,b0.z,b0.w,b1.x,b1.y,b1.z,b1.w};
      #pragma unroll
      for (int i = 0; i < 8; ++i)
        #pragma unroll
        for (int j = 0; j < 8; ++j)
          acc[i][j] += avv[i]*bvv[j];
    }
    __syncthreads();
  }
  float b8[8];
  #pragma unroll
  for (int j = 0; j < 8; ++j) {
    float bvv = 0.f;
    if (bias0) bvv += bias0[nb + tx*8 + j];
    if (bias1) bvv += bias1[nb + tx*8 + j];
    b8[j] = bvv;
  }
  #pragma unroll
  for (int i = 0; i < 8; ++i) {
    float4 o0, o1;
    o0.x = acc[i][0]+b8[0]; o0.y = acc[i][1]+b8[1]; o0.z = acc[i][2]+b8[2]; o0.w = acc[i][3]+b8[3];
    o1.x = acc[i][4]+b8[4]; o1.y = acc[i][5]+b8[5]; o1.z = acc[i][6]+b8[6]; o1.w = acc[i][7]+b8[7];
    size_t idx = (size_t)(mb + ty*8 + i) * ldc + nb + tx*8;
    *(float4*)&C[idx]     = o0;
    *(float4*)&C[idx + 4] = o1;
  }
}

// ---------------- distributed attention: block (ab, aslice) -> ctx slice ----------------
__device__ void attend_slice(int ab, int aslice, const float* __restrict__ hvec,
                             float* __restrict__ ctxdst,
                             const float* __restrict__ outbuf, const float* __restrict__ projo,
                             const int* __restrict__ mask, float* scratch, int tid)
{
  float* scp = scratch;        // 256
  float* scv = scratch + 256;  // 64
  float* p2  = scratch + 320;  // 128
  const int tq = tid >> 2, dq = tid & 3;
  const float4* hv = (const float4*)(hvec + dq*256);
  const float4* pv = (const float4*)(projo + (size_t)(ab*T + tq)*H2 + dq*256);
  float p = 0.f;
  #pragma unroll 8
  for (int k4 = 0; k4 < 64; ++k4) {
    float4 a = hv[k4], q = pv[k4];
    p += a.x*q.x + a.y*q.y + a.z*q.z + a.w*q.w;
  }
  scp[tid] = p;
  __syncthreads();
  if (tid < 64) {
    float v = scp[tid*4] + scp[tid*4+1] + scp[tid*4+2] + scp[tid*4+3];
    float mx = v;
    #pragma unroll
    for (int d = 32; d; d >>= 1) mx = fmaxf(mx, __shfl_xor(mx, d, 64));
    float e = expf(v - mx);
    float sm = e;
    #pragma unroll
    for (int d = 32; d; d >>= 1) sm += __shfl_xor(sm, d, 64);
    scv[tid] = e * (1.f / sm) * (float)mask[ab*T + tid];
  }
  __syncthreads();
  {
    const int dl = tid & 127, th = tid >> 7;
    const int dg = aslice*128 + dl;
    float acc = 0.f;
    #pragma unroll 8
    for (int q = 0; q < 32; ++q) {
      int tt = th*32 + q;
      acc += scv[tt] * outbuf[(size_t)(ab*T + tt)*H2 + dg];
    }
    if (th == 1) p2[dl] = acc;
    __syncthreads();
    if (th == 0) st_wt(&ctxdst[dg*32 + ab], acc + p2[dl]);
  }
}

// ---------------- persistent encoder: wave-private staging, no K-loop syncs ----------
__global__ __launch_bounds__(256, 1) void encoder_persistent(
    const float* __restrict__ xg_f, const float* __restrict__ xg_b,
    const float* __restrict__ Whh_f, const float* __restrict__ Whh_b,
    const int* __restrict__ mask,
    float* __restrict__ hencT,    // [dir][2][512][32]
    float* __restrict__ outbuf,
    unsigned* __restrict__ eslots, unsigned* __restrict__ eflags)
{
  __shared__ float S_lds[9216];   // wave-private: wv*2304 + buf*1152, rows stride 36
  __shared__ float pacc[2048];
  __shared__ float g_lds[512];
  const int blk = blockIdx.x, tid = threadIdx.x;
  const int lane = tid & 63, wv = tid >> 6;
  const int dir = blk >> 7, nd = blk & 127;
  const int hibase = nd * 4;
  const int jj = tid & 7, kk = tid >> 3;        // kk = 8*wv + (lane>>3)
  const int kkl = lane >> 3;
  const float* xg  = dir ? xg_b : xg_f;
  const float* Whh = dir ? Whh_b : Whh_f;
  float* hbase = hencT + dir * 32768;
  float* Sw = S_lds + wv*2304;

  float wge[2][16];
  #pragma unroll
  for (int p = 0; p < 2; ++p) {
    int jl = jj*2 + p;
    int j = (jl>>2)*512 + hibase + (jl&3);
    #pragma unroll
    for (int sc = 0; sc < 4; ++sc)
      #pragma unroll
      for (int i = 0; i < 4; ++i)
        wge[p][sc*4+i] = Whh[(size_t)j*512 + sc*128 + i*32 + kk];
  }
  float c_reg = 0.f;
  // wave-private staging map: local row lr (0..31) <-> global slice row (lr>>3)*32 + 8*wv + (lr&7)
  const int lr = lane >> 1, halfc = (lane & 1) * 16;
  const int grow = (lr >> 3)*32 + 8*wv + (lr & 7);

  for (int tt = 0; tt < 64; ++tt) {
    const int t = dir ? (63 - tt) : tt;
    const float* hc = hbase + (tt & 1) * 16384;
    float* hn = hbase + ((tt + 1) & 1) * 16384;

    float a0[32], a1[32];
    #pragma unroll
    for (int q = 0; q < 32; ++q) { a0[q] = 0.f; a1[q] = 0.f; }

    float4 r0, r1, r2, r3;
    {
      const float4* p = (const float4*)(hc + grow*32 + halfc);
      r0 = p[0]; r1 = p[1]; r2 = p[2]; r3 = p[3];
      float* d = Sw + lr*36 + halfc;
      *(float4*)d = r0; *(float4*)(d+4) = r1; *(float4*)(d+8) = r2; *(float4*)(d+12) = r3;
    }
    #pragma unroll
    for (int sc = 0; sc < 4; ++sc) {
      if (sc < 3) {
        const float4* p = (const float4*)(hc + ((sc+1)*128 + grow)*32 + halfc);
        r0 = p[0]; r1 = p[1]; r2 = p[2]; r3 = p[3];
      }
      const float* Sb = Sw + (sc & 1)*1152;
      #pragma unroll
      for (int i = 0; i < 4; ++i) {
        const float* sp = Sb + (i*8 + kkl)*36;
        float w0 = wge[0][sc*4+i], w1 = wge[1][sc*4+i];
        #pragma unroll
        for (int q = 0; q < 8; ++q) {
          float4 s4 = *(const float4*)(sp + q*4);
          a0[q*4+0] += w0*s4.x; a0[q*4+1] += w0*s4.y; a0[q*4+2] += w0*s4.z; a0[q*4+3] += w0*s4.w;
          a1[q*4+0] += w1*s4.x; a1[q*4+1] += w1*s4.y; a1[q*4+2] += w1*s4.z; a1[q*4+3] += w1*s4.w;
        }
      }
      if (sc < 3) {
        float* d = Sw + ((sc+1) & 1)*1152 + lr*36 + halfc;
        *(float4*)d = r0; *(float4*)(d+4) = r1; *(float4*)(d+8) = r2; *(float4*)(d+12) = r3;
      }
    }
    #pragma unroll
    for (int dd = 8; dd <= 32; dd <<= 1) {
      #pragma unroll
      for (int q = 0; q < 32; ++q) {
        a0[q] += __shfl_down(a0[q], dd, 64);
        a1[q] += __shfl_down(a1[q], dd, 64);
      }
    }
    if (lane < 8) {
      float* pw = &pacc[wv*512 + lane*64];
      #pragma unroll
      for (int q = 0; q < 32; ++q) { pw[q] = a0[q]; pw[32+q] = a1[q]; }
    }
    __syncthreads();
    #pragma unroll
    for (int r = 0; r < 2; ++r) {
      int o = tid + r*256;
      int jl = o >> 5, b = o & 31;
      int off = (jl>>1)*64 + (jl&1)*32 + b;
      float v = pacc[off] + pacc[512+off] + pacc[1024+off] + pacc[1536+off];
      v += xg[(size_t)(b*T + t)*2048 + (jl>>2)*512 + hibase + (jl&3)];
      g_lds[jl*32 + b] = v;
    }
    __syncthreads();
    if (tid < 128) {
      int hil = tid >> 5, b = tid & 31;
      float gi = g_lds[(0*4+hil)*32 + b];
      float gf = g_lds[(1*4+hil)*32 + b];
      float gg = g_lds[(2*4+hil)*32 + b];
      float go = g_lds[(3*4+hil)*32 + b];
      c_reg = sigm(gf)*c_reg + sigm(gi)*tanhf(gg);
      float h = sigm(go)*tanhf(c_reg);
      int hi = hibase + hil;
      st_wt(&hn[hi*32 + b], h);
      st_wt(&outbuf[(size_t)(b*T + t)*H2 + dir*512 + hi], h * (float)mask[b*T + t]);
    }
    pbar(eslots + (dir*64 + tt)*128, eflags + (dir*64 + tt)*256, nd, 128);
  }
}

// ---- decoder macros: wave-private staging (NO __syncthreads in K-loops) ----
#define GROW1(lr) (8*wv + ((lr) < 8 ? (lr) : 24 + (lr)))
#define GROW2(lr) (16*wv + (lr))
#define SLDG(qq, s) { int krr = (s)*64 + GROW1(lrow); \
  const float* bs = (krr < 1024) ? (hTc + krr*32) : (ctxc + (krr-1024)*32); \
  qq##a = *(const float4*)(bs + scol2); qq##b = *(const float4*)(bs + scol2 + 4); }
#define SLDS(qq, s) { int krr = (s)*64 + GROW2(lrow); \
  const float* bs = (krr < 1024) ? (hTn + krr*32) : (ctxc + (krr-1024)*32); \
  qq##a = *(const float4*)(bs + scol2); qq##b = *(const float4*)(bs + scol2 + 4); }
#define STW(qq, BUF) { float* d = Sw + (BUF)*576 + lrow*36 + scol2; \
  *(float4*)d = qq##a; *(float4*)(d+4) = qq##b; }
#define COMPG(sl, BUF) { const float* Sb = Sw + (BUF)*576; \
  _Pragma("unroll") for (int i = 0; i < 2; ++i) { \
    float w0 = Wg[jl0*2052 + (sl)*64 + i*32 + kkg]; \
    float w1 = Wg[jl1*2052 + (sl)*64 + i*32 + kkg]; \
    const float* sp = Sb + (i*8 + kkl)*36; \
    _Pragma("unroll") for (int q = 0; q < 8; ++q) { \
      float4 s4 = *(const float4*)(sp + q*4); \
      a0[q*4+0] += w0*s4.x; a0[q*4+1] += w0*s4.y; a0[q*4+2] += w0*s4.z; a0[q*4+3] += w0*s4.w; \
      a1[q*4+0] += w1*s4.x; a1[q*4+1] += w1*s4.y; a1[q*4+2] += w1*s4.z; a1[q*4+3] += w1*s4.w; } } }
#define COMPS(sl, BUF) { const float* sp = Sw + (BUF)*576 + lrow*36; \
  float w0 = ws0[sl], w1 = ws1[sl]; \
  _Pragma("unroll") for (int q = 0; q < 8; ++q) { \
    float4 s4 = *(const float4*)(sp + q*4); \
    a0[q*4+0] += w0*s4.x; a0[q*4+1] += w0*s4.y; a0[q*4+2] += w0*s4.z; a0[q*4+3] += w0*s4.w; \
    a1[q*4+0] += w1*s4.x; a1[q*4+1] += w1*s4.y; a1[q*4+2] += w1*s4.z; a1[q*4+3] += w1*s4.w; } }

// ---------------- persistent decoder: wave-private K-loops, XCD-localized attend --------
// Dynamic LDS (floats): Wg 16x2052=32832 | S2 4x2x576=4608 | pacc 2048 | g_lds 512 = 160000 B
__global__ __launch_bounds__(256, 1) void decoder_persistent(
    const float* __restrict__ basep, const float* __restrict__ tagp,
    const float* __restrict__ dWhh,  const float* __restrict__ dWih,
    const float* __restrict__ Wout,  const float* __restrict__ bout,
    const float* __restrict__ projo, const float* __restrict__ outbuf,
    const int* __restrict__ mask,
    float* __restrict__ hT,          // [2][1024][32]
    float* __restrict__ ctxT,        // [2][1024][32]
    float* __restrict__ hrow,        // [32][1024]
    unsigned long long* __restrict__ argslot,
    unsigned* __restrict__ dslots, unsigned* __restrict__ dflags,
    float* __restrict__ out)
{
  extern __shared__ float dyn[];
  float* Wg    = dyn;           // 32832
  float* S2    = dyn + 32832;   // 4608 (wave-private: wv*1152 + buf*576)
  float* pacc  = dyn + 37440;   // 2048
  float* g_lds = dyn + 39488;   // 512

  const int blk = blockIdx.x, tid = threadIdx.x;
  const int lane = tid & 63, wv = tid >> 6;
  const int hibase = blk * 4;
  const int jj = lane & 7, kkl = lane >> 3;
  const int kkg = 8*wv + kkl;
  const int jl0 = jj*2, jl1 = jj*2 + 1;
  const int vv = tid & 3, kq = tid >> 2;
  const int vbase = blk * 8;
  const int lrow = lane >> 2, scol2 = (lane & 3) * 8;
  // XCD-localized attend mapping: blocks {ab + 32*aslice} share blk%8 == ab%8 -> same XCD
  const int ab = blk & 31, aslice = blk >> 5;
  float* Sw = S2 + wv*1152;

  // ---- preload gates weights into LDS (once) ----
  for (int jl = 0; jl < 16; ++jl) {
    int j = (jl>>2)*1024 + hibase + (jl&3);
    #pragma unroll
    for (int r = 0; r < 2; ++r) {
      int c = tid*4 + r*1024;
      float4 w;
      if (c < 1024) w = *(const float4*)(dWhh + (size_t)j*1024 + c);
      else          w = *(const float4*)(dWih + (size_t)j*2560 + 512 + (c - 1024));
      *(float4*)&Wg[jl*2052 + c] = w;
    }
  }
  // ---- scores weights in registers (64 floats/thread) ----
  float ws0[32], ws1[32];
  {
    int v0 = vbase + vv*2;
    #pragma unroll
    for (int s2 = 0; s2 < 32; ++s2) {
      ws0[s2] = Wout[(size_t)(v0+0)*2048 + s2*64 + kq];
      ws1[s2] = Wout[(size_t)(v0+1)*2048 + s2*64 + kq];
    }
  }

  float c_reg = 0.f;
  int bslot = 0;

  // ---- prologue: ctx(0) = attend(last_output), distributed over all 256 blocks ----
  {
    int len = -1;
    for (int i = 0; i < T; ++i) len += mask[ab*T + i];
    attend_slice(ab, aslice, outbuf + (size_t)(ab*T + len)*H2, ctxT,
                 outbuf, projo, mask, pacc, tid);
  }
  pbar(dslots + (bslot)*256, dflags + (bslot)*256, blk, 256); bslot++;

  for (int t = 0; t < T; ++t) {
    const int cur = t & 1, nxt = cur ^ 1;
    const float* hTc  = hT + cur*32768;
    float*       hTn  = hT + nxt*32768;
    const float* ctxc = ctxT + cur*32768;
    float*       ctxn = ctxT + nxt*32768;

    // prefetch per-thread external gate contributions (base + tag embed proj)
    const int b_own = tid & 31;
    const int jlA = tid >> 5, jlB = jlA + 8;
    const int jA = (jlA>>2)*1024 + hibase + (jlA&3);
    const int jB = (jlB>>2)*1024 + hibase + (jlB&3);
    float extA = basep[(size_t)(b_own*T + t)*G4 + jA];
    float extB = basep[(size_t)(b_own*T + t)*G4 + jB];
    if (t > 0) {
      unsigned long long sl64 = __hip_atomic_load(&argslot[((t+2)%3)*32 + b_own],
                                                  __ATOMIC_RELAXED, __HIP_MEMORY_SCOPE_AGENT);
      unsigned tg = ~(unsigned)sl64;
      extA += tagp[(size_t)tg*G4 + jA];
      extB += tagp[(size_t)tg*G4 + jB];
    }

    // ===== phase 1: gates (K=2048: h | ctx), wave-private staging, no K-loop syncs =====
    float a0[32], a1[32];
    #pragma unroll
    for (int q = 0; q < 32; ++q) { a0[q] = 0.f; a1[q] = 0.f; }
    {
      float4 q0a,q0b,q1a,q1b,q2a,q2b,q3a,q3b;
      SLDG(q0, 0) SLDG(q1, 1) SLDG(q2, 2) SLDG(q3, 3)
      STW(q0, 0)
      for (int g = 0; g < 8; ++g) {
        const int sl = g*4;
        if (sl+4 < 32) SLDG(q0, sl+4)
        COMPG(sl, 0)
        STW(q1, 1)
        if (sl+5 < 32) SLDG(q1, sl+5)
        COMPG(sl+1, 1)
        STW(q2, 0)
        if (sl+6 < 32) SLDG(q2, sl+6)
        COMPG(sl+2, 0)
        STW(q3, 1)
        if (sl+7 < 32) SLDG(q3, sl+7)
        COMPG(sl+3, 1)
        if (sl+4 < 32) STW(q0, 0)
      }
    }
    #pragma unroll
    for (int dd = 8; dd <= 32; dd <<= 1) {
      #pragma unroll
      for (int q = 0; q < 32; ++q) {
        a0[q] += __shfl_down(a0[q], dd, 64);
        a1[q] += __shfl_down(a1[q], dd, 64);
      }
    }
    if (lane < 8) {
      float* pw = &pacc[wv*512 + lane*64];
      #pragma unroll
      for (int q = 0; q < 32; ++q) { pw[q] = a0[q]; pw[32+q] = a1[q]; }
    }
    __syncthreads();
    #pragma unroll
    for (int r = 0; r < 2; ++r) {
      int o = tid + r*256;
      int jl = o >> 5, b = o & 31;
      int off = (jl>>1)*64 + (jl&1)*32 + b;
      float vsum = pacc[off] + pacc[512+off] + pacc[1024+off] + pacc[1536+off];
      vsum += (r == 0) ? extA : extB;
      g_lds[jl*32 + b] = vsum;
    }
    __syncthreads();
    if (tid < 128) {
      int hil = tid >> 5, b = tid & 31;
      float gi = g_lds[(0*4+hil)*32 + b];
      float gf = g_lds[(1*4+hil)*32 + b];
      float gg = g_lds[(2*4+hil)*32 + b];
      float go = g_lds[(3*4+hil)*32 + b];
      c_reg = sigm(gf)*c_reg + sigm(gi)*tanhf(gg);
      float h = sigm(go)*tanhf(c_reg);
      int hi = hibase + hil;
      st_wt(&hTn[hi*32 + b], h);
      st_wt(&hrow[b*1024 + hi], h);
    }
    pbar(dslots + (bslot)*256, dflags + (bslot)*256, blk, 256); bslot++;

    // ===== phase 2: scores (K=2048: h_new | ctx_old), wave-private staging =====
    #pragma unroll
    for (int q = 0; q < 32; ++q) { a0[q] = 0.f; a1[q] = 0.f; }
    {
      float4 q0a,q0b,q1a,q1b,q2a,q2b,q3a,q3b;
      SLDS(q0, 0) SLDS(q1, 1) SLDS(q2, 2) SLDS(q3, 3)
      STW(q0, 0)
      #pragma unroll
      for (int g = 0; g < 8; ++g) {
        const int sl = g*4;
        if (sl+4 < 32) SLDS(q0, sl+4)
        COMPS(sl, 0)
        STW(q1, 1)
        if (sl+5 < 32) SLDS(q1, sl+5)
        COMPS(sl+1, 1)
        STW(q2, 0)
        if (sl+6 < 32) SLDS(q2, sl+6)
        COMPS(sl+2, 0)
        STW(q3, 1)
        if (sl+7 < 32) SLDS(q3, sl+7)
        COMPS(sl+3, 1)
        if (sl+4 < 32) STW(q0, 0)
      }
    }
    #pragma unroll
    for (int dd = 4; dd <= 32; dd <<= 1) {
      #pragma unroll
      for (int q = 0; q < 32; ++q) {
        a0[q] += __shfl_down(a0[q], dd, 64);
        a1[q] += __shfl_down(a1[q], dd, 64);
      }
    }
    if (lane < 4) {
      float* pw = &pacc[wv*256 + lane*64];
      #pragma unroll
      for (int q = 0; q < 32; ++q) { pw[q] = a0[q]; pw[32+q] = a1[q]; }
    }
    __syncthreads();
    {
      int vl = tid & 7, b = tid >> 3;
      int off = (vl>>1)*64 + (vl&1)*32 + b;
      float s = pacc[off] + pacc[256+off] + pacc[512+off] + pacc[768+off];
      s += bout[vbase + vl];
      st_wt(&out[(size_t)(b*T + t)*V + vbase + vl], s);
      g_lds[vl*32 + b] = s;
    }
    __syncthreads();
    if (tid < 32) {
      int b = tid;
      float best = g_lds[b]; int bi = 0;
      #pragma unroll
      for (int vl = 1; vl < 8; ++vl) {
        float s = g_lds[vl*32 + b];
        if (s > best) { best = s; bi = vl; }
      }
      unsigned long long e = ((unsigned long long)fenc(best) << 32)
                           | (unsigned long long)(unsigned)(~(unsigned)(vbase + bi));
      atomicMax(&argslot[(t%3)*32 + b], e);
    } else if (blk == 0 && tid >= 32 && tid < 64) {
      __hip_atomic_store(&argslot[((t+1)%3)*32 + (tid - 32)], 0ull,
                         __ATOMIC_RELAXED, __HIP_MEMORY_SCOPE_AGENT);
    }
    if (t < 63) {
      __syncthreads();
      attend_slice(ab, aslice, hrow + ab*1024, ctxn, outbuf, projo, mask, pacc, tid);
    }
    pbar(dslots + (bslot)*256, dflags + (bslot)*256, blk, 256); bslot++;
  }
}

// ---------------- host launch ----------------
extern "C" void kernel_launch(void* const* d_in, const int* in_sizes, int n_in,
                              void* d_out, int out_size, void* d_ws, size_t ws_size,
                              hipStream_t stream)
{
  (void)in_sizes; (void)n_in; (void)out_size; (void)ws_size;
  const float* emb    = (const float*)d_in[0];
  const int*   mask   = (const int*)d_in[1];
  const float* Wih_f  = (const float*)d_in[2];
  const float* Whh_f  = (const float*)d_in[3];
  const float* bih_f  = (const float*)d_in[4];
  const float* bhh_f  = (const float*)d_in[5];
  const float* Wih_b  = (const float*)d_in[6];
  const float* Whh_b  = (const float*)d_in[7];
  const float* bih_b  = (const float*)d_in[8];
  const float* bhh_b  = (const float*)d_in[9];
  const float* attnW  = (const float*)d_in[10];
  const float* tagemb = (const float*)d_in[12];
  const float* dWih   = (const float*)d_in[13];
  const float* dWhh   = (const float*)d_in[14];
  const float* dbih   = (const float*)d_in[15];
  const float* dbhh   = (const float*)d_in[16];
  const float* Wout   = (const float*)d_in[17];
  const float* bout   = (const float*)d_in[18];
  float* out = (float*)d_out;

  float* ws = (float*)d_ws;
  float* xg_f   = ws + 0;          // 4194304
  float* xg_b   = ws + 4194304;    // 4194304
  float* outbuf = ws + 8388608;    // 2097152
  float* projo  = ws + 10485760;   // 2097152
  float* basep  = ws + 12582912;   // 8388608
  float* tagp   = ws + 20971520;   // 8388608
  // --- zeroed state block ---
  float* hT     = ws + 29360128;   // 65536  [2][1024][32]
  float* ctxT   = ws + 29425664;   // 65536  [2][1024][32]
  float* hrow   = ws + 29491200;   // 32768
  float* hencT  = ws + 29523968;   // 65536  [2][2][512][32]
  unsigned long long* argslot = (unsigned long long*)(ws + 29589504);  // 96 u64 (192 fl)
  unsigned* dslots = (unsigned*)(ws + 29589696);   // 129*256 = 33024 u32
  unsigned* dflags = (unsigned*)(ws + 29622720);   // 129*256 = 33024 u32
  unsigned* eslots = (unsigned*)(ws + 29655744);   // 128*128 = 16384 u32
  unsigned* eflags = (unsigned*)(ws + 29672128);   // 128*256 = 32768 u32
  // end: 29704896 floats

  // allow 160000 B dynamic LDS for the decoder
  (void)hipFuncSetAttribute((const void*)decoder_persistent,
                            hipFuncAttributeMaxDynamicSharedMemorySize, 160000);

  // zero all persistent-kernel state every call (graph-replay deterministic)
  hipMemsetAsync((void*)(ws + 29360128), 0, (size_t)(29704896 - 29360128) * sizeof(float), stream);

  // xg = emb @ Wih^T + bih + bhh   (M=2048, N=2048, K=512)
  gemm_nt<<<dim3(16, 16), 256, 0, stream>>>(emb, 512, Wih_f, 512, xg_f, 2048, bih_f, bhh_f, 512);
  gemm_nt<<<dim3(16, 16), 256, 0, stream>>>(emb, 512, Wih_b, 512, xg_b, 2048, bih_b, bhh_b, 512);
  // tagp = tag_embed @ dec_Wih[:, :512]^T   (M=2048, N=4096, K=512)
  gemm_nt<<<dim3(32, 16), 256, 0, stream>>>(tagemb, 512, dWih, DEC_IN, tagp, G4, nullptr, nullptr, 512);
  // encoder scan (persistent, register-resident Whh, wave-private staging)
  encoder_persistent<<<256, 256, 0, stream>>>(xg_f, xg_b, Whh_f, Whh_b, mask, hencT, outbuf, eslots, eflags);
  // projo[bt,d] = sum_e attn_W[d,e]*output[bt,e]   (M=2048, N=1024, K=1024)
  gemm_nt<<<dim3(8, 16), 256, 0, stream>>>(outbuf, H2, attnW, H2, projo, H2, nullptr, nullptr, H2);
  // basep = aligned @ dec_Wih[:,1536:]^T + dbih + dbhh   (M=2048, N=4096, K=1024)
  gemm_nt<<<dim3(32, 16), 256, 0, stream>>>(outbuf, H2, dWih + 1536, DEC_IN, basep, G4, dbih, dbhh, H2);
  // persistent decoder (unchanged from R12)
  decoder_persistent<<<256, 256, 160000, stream>>>(basep, tagp, dWhh, dWih, Wout, bout,
                                                   projo, outbuf, mask, hT, ctxT, hrow,
                                                   argslot, dslots, dflags, out);
}

// Round 14
// 4548.406 us; speedup vs baseline: 2.8866x; 1.0396x over previous
//
#include <hip/hip_runtime.h>

#define B   32
#define T   64
#define D   512
#define H   512
#define H2  1024
#define G4  4096
#define V   2048
#define DEC_IN 2560

__device__ __forceinline__ float sigm(float x) { return 1.f / (1.f + expf(-x)); }

__device__ __forceinline__ unsigned fenc(float f) {
  unsigned u = __float_as_uint(f);
  return (u & 0x80000000u) ? ~u : (u | 0x80000000u);
}

__device__ __forceinline__ void st_wt(float* p, float v) {       // write-through (L3-visible on retire)
  __hip_atomic_store(p, v, __ATOMIC_RELAXED, __HIP_MEMORY_SCOPE_AGENT);
}

// ---- store-based grid barrier WITH acquire (encoder: reused state buffers need L2 INV) ----
__device__ __forceinline__ void pbar(unsigned* slots, unsigned* flags, int myid, int nblk) {
  __syncthreads();
  if (threadIdx.x == 0)
    __hip_atomic_store(slots + myid, 1u, __ATOMIC_RELAXED, __HIP_MEMORY_SCOPE_AGENT);
  if (myid == 0) {
    for (int s = threadIdx.x; s < nblk; s += 256) {
      while (!__hip_atomic_load(slots + s, __ATOMIC_RELAXED, __HIP_MEMORY_SCOPE_AGENT))
        __builtin_amdgcn_s_sleep(1);
    }
    __syncthreads();
    if (threadIdx.x < 16)
      __hip_atomic_store(flags + threadIdx.x*16, 1u, __ATOMIC_RELAXED, __HIP_MEMORY_SCOPE_AGENT);
  }
  if (threadIdx.x == 0) {
    unsigned* f = flags + (myid & 15)*16;
    while (!__hip_atomic_load(f, __ATOMIC_RELAXED, __HIP_MEMORY_SCOPE_AGENT))
      __builtin_amdgcn_s_sleep(1);
    (void)__hip_atomic_load(f, __ATOMIC_ACQUIRE, __HIP_MEMORY_SCOPE_AGENT);
  }
  __syncthreads();
}

// ---- INV-free barrier (decoder: all cross-step state uses step-unique addresses,
// writes are write-through; read-only data stays L2-resident across the whole kernel) ----
__device__ __forceinline__ void pbar_na(unsigned* slots, unsigned* flags, int myid, int nblk) {
  __syncthreads();   // drains vmcnt -> write-through stores L3-visible before arrival
  if (threadIdx.x == 0)
    __hip_atomic_store(slots + myid, 1u, __ATOMIC_RELAXED, __HIP_MEMORY_SCOPE_AGENT);
  if (myid == 0) {
    for (int s = threadIdx.x; s < nblk; s += 256) {
      while (!__hip_atomic_load(slots + s, __ATOMIC_RELAXED, __HIP_MEMORY_SCOPE_AGENT))
        __builtin_amdgcn_s_sleep(1);
    }
    __syncthreads();
    if (threadIdx.x < 16)
      __hip_atomic_store(flags + threadIdx.x*16, 1u, __ATOMIC_RELAXED, __HIP_MEMORY_SCOPE_AGENT);
  }
  if (threadIdx.x == 0) {
    unsigned* f = flags + (myid & 15)*16;
    while (!__hip_atomic_load(f, __ATOMIC_RELAXED, __HIP_MEMORY_SCOPE_AGENT))
      __builtin_amdgcn_s_sleep(1);
  }
  __syncthreads();
}

// ---------------- fp32 GEMM: 128x128 tile, 8x8 micro-tile, BK=8 ----------------
__global__ __launch_bounds__(256) void gemm_nt(
    const float* __restrict__ A, int lda,
    const float* __restrict__ W, int ldw,
    float* __restrict__ C, int ldc,
    const float* __restrict__ bias0, const float* __restrict__ bias1,
    int K)
{
  __shared__ float As[8][132];
  __shared__ float Bs[8][132];
  const int tid = threadIdx.x;
  const int nb = blockIdx.x * 128;
  const int mb = blockIdx.y * 128;
  const int tx = tid & 15;
  const int ty = tid >> 4;
  float acc[8][8] = {};

  const int am = tid >> 1, ak = (tid & 1) * 4;
  const float* aptr = A + (size_t)(mb + am) * lda + ak;
  const float* bptr = W + (size_t)(nb + am) * ldw + ak;

  for (int k0 = 0; k0 < K; k0 += 8) {
    float4 av = *(const float4*)(aptr + k0);
    float4 bv = *(const float4*)(bptr + k0);
    As[ak+0][am] = av.x; As[ak+1][am] = av.y; As[ak+2][am] = av.z; As[ak+3][am] = av.w;
    Bs[ak+0][am] = bv.x; Bs[ak+1][am] = bv.y; Bs[ak+2][am] = bv.z; Bs[ak+3][am] = bv.w;
    __syncthreads();
    #pragma unroll
    for (int k = 0; k < 8; ++k) {
      float4 a0 = *(const float4*)&As[k][ty*8];
      float4 a1 = *(const float4*)&As[k][ty*8+4];
      float4 b0 = *(const float4*)&Bs[k][tx*8];
      float4 b1 = *(const float4*)&Bs[k][tx*8+4];
      float avv[8] = {a0.x,a0.y,a0.z,a0.w,a1.x,a1.y,a1.z,a1.w};
      float bvv[8] = {b0.x,b0.y,b0.z,b0.w,b1.x,b1.y,b1.z,b1.w};
      #pragma unroll
      for (int i = 0; i < 8; ++i)
        #pragma unroll
        for (int j = 0; j < 8; ++j)
          acc[i][j] += avv[i]*bvv[j];
    }
    __syncthreads();
  }
  float b8[8];
  #pragma unroll
  for (int j = 0; j < 8; ++j) {
    float bvv = 0.f;
    if (bias0) bvv += bias0[nb + tx*8 + j];
    if (bias1) bvv += bias1[nb + tx*8 + j];
    b8[j] = bvv;
  }
  #pragma unroll
  for (int i = 0; i < 8; ++i) {
    float4 o0, o1;
    o0.x = acc[i][0]+b8[0]; o0.y = acc[i][1]+b8[1]; o0.z = acc[i][2]+b8[2]; o0.w = acc[i][3]+b8[3];
    o1.x = acc[i][4]+b8[4]; o1.y = acc[i][5]+b8[5]; o1.z = acc[i][6]+b8[6]; o1.w = acc[i][7]+b8[7];
    size_t idx = (size_t)(mb + ty*8 + i) * ldc + nb + tx*8;
    *(float4*)&C[idx]     = o0;
    *(float4*)&C[idx + 4] = o1;
  }
}

// ---------------- distributed attention: block (ab, aslice) -> ctx slice ----------------
__device__ void attend_slice(int ab, int aslice, const float* __restrict__ hvec,
                             float* __restrict__ ctxdst,
                             const float* __restrict__ outbuf, const float* __restrict__ projo,
                             const int* __restrict__ mask, float* scratch, int tid)
{
  float* scp = scratch;        // 256
  float* scv = scratch + 256;  // 64
  float* p2  = scratch + 320;  // 128
  const int tq = tid >> 2, dq = tid & 3;
  const float4* hv = (const float4*)(hvec + dq*256);
  const float4* pv = (const float4*)(projo + (size_t)(ab*T + tq)*H2 + dq*256);
  float p = 0.f;
  #pragma unroll 8
  for (int k4 = 0; k4 < 64; ++k4) {
    float4 a = hv[k4], q = pv[k4];
    p += a.x*q.x + a.y*q.y + a.z*q.z + a.w*q.w;
  }
  scp[tid] = p;
  __syncthreads();
  if (tid < 64) {
    float v = scp[tid*4] + scp[tid*4+1] + scp[tid*4+2] + scp[tid*4+3];
    float mx = v;
    #pragma unroll
    for (int d = 32; d; d >>= 1) mx = fmaxf(mx, __shfl_xor(mx, d, 64));
    float e = expf(v - mx);
    float sm = e;
    #pragma unroll
    for (int d = 32; d; d >>= 1) sm += __shfl_xor(sm, d, 64);
    scv[tid] = e * (1.f / sm) * (float)mask[ab*T + tid];
  }
  __syncthreads();
  {
    const int dl = tid & 127, th = tid >> 7;
    const int dg = aslice*128 + dl;
    float acc = 0.f;
    #pragma unroll 8
    for (int q = 0; q < 32; ++q) {
      int tt = th*32 + q;
      acc += scv[tt] * outbuf[(size_t)(ab*T + tt)*H2 + dg];
    }
    if (th == 1) p2[dl] = acc;
    __syncthreads();
    if (th == 0) st_wt(&ctxdst[dg*32 + ab], acc + p2[dl]);
  }
}

// ---------------- persistent encoder (R13, unchanged) ----------
__global__ __launch_bounds__(256, 1) void encoder_persistent(
    const float* __restrict__ xg_f, const float* __restrict__ xg_b,
    const float* __restrict__ Whh_f, const float* __restrict__ Whh_b,
    const int* __restrict__ mask,
    float* __restrict__ hencT,    // [dir][2][512][32]
    float* __restrict__ outbuf,
    unsigned* __restrict__ eslots, unsigned* __restrict__ eflags)
{
  __shared__ float S_lds[9216];   // wave-private: wv*2304 + buf*1152, rows stride 36
  __shared__ float pacc[2048];
  __shared__ float g_lds[512];
  const int blk = blockIdx.x, tid = threadIdx.x;
  const int lane = tid & 63, wv = tid >> 6;
  const int dir = blk >> 7, nd = blk & 127;
  const int hibase = nd * 4;
  const int jj = tid & 7, kk = tid >> 3;
  const int kkl = lane >> 3;
  const float* xg  = dir ? xg_b : xg_f;
  const float* Whh = dir ? Whh_b : Whh_f;
  float* hbase = hencT + dir * 32768;
  float* Sw = S_lds + wv*2304;

  float wge[2][16];
  #pragma unroll
  for (int p = 0; p < 2; ++p) {
    int jl = jj*2 + p;
    int j = (jl>>2)*512 + hibase + (jl&3);
    #pragma unroll
    for (int sc = 0; sc < 4; ++sc)
      #pragma unroll
      for (int i = 0; i < 4; ++i)
        wge[p][sc*4+i] = Whh[(size_t)j*512 + sc*128 + i*32 + kk];
  }
  float c_reg = 0.f;
  const int lr = lane >> 1, halfc = (lane & 1) * 16;
  const int grow = (lr >> 3)*32 + 8*wv + (lr & 7);

  for (int tt = 0; tt < 64; ++tt) {
    const int t = dir ? (63 - tt) : tt;
    const float* hc = hbase + (tt & 1) * 16384;
    float* hn = hbase + ((tt + 1) & 1) * 16384;

    float a0[32], a1[32];
    #pragma unroll
    for (int q = 0; q < 32; ++q) { a0[q] = 0.f; a1[q] = 0.f; }

    float4 r0, r1, r2, r3;
    {
      const float4* p = (const float4*)(hc + grow*32 + halfc);
      r0 = p[0]; r1 = p[1]; r2 = p[2]; r3 = p[3];
      float* d = Sw + lr*36 + halfc;
      *(float4*)d = r0; *(float4*)(d+4) = r1; *(float4*)(d+8) = r2; *(float4*)(d+12) = r3;
    }
    #pragma unroll
    for (int sc = 0; sc < 4; ++sc) {
      if (sc < 3) {
        const float4* p = (const float4*)(hc + ((sc+1)*128 + grow)*32 + halfc);
        r0 = p[0]; r1 = p[1]; r2 = p[2]; r3 = p[3];
      }
      const float* Sb = Sw + (sc & 1)*1152;
      #pragma unroll
      for (int i = 0; i < 4; ++i) {
        const float* sp = Sb + (i*8 + kkl)*36;
        float w0 = wge[0][sc*4+i], w1 = wge[1][sc*4+i];
        #pragma unroll
        for (int q = 0; q < 8; ++q) {
          float4 s4 = *(const float4*)(sp + q*4);
          a0[q*4+0] += w0*s4.x; a0[q*4+1] += w0*s4.y; a0[q*4+2] += w0*s4.z; a0[q*4+3] += w0*s4.w;
          a1[q*4+0] += w1*s4.x; a1[q*4+1] += w1*s4.y; a1[q*4+2] += w1*s4.z; a1[q*4+3] += w1*s4.w;
        }
      }
      if (sc < 3) {
        float* d = Sw + ((sc+1) & 1)*1152 + lr*36 + halfc;
        *(float4*)d = r0; *(float4*)(d+4) = r1; *(float4*)(d+8) = r2; *(float4*)(d+12) = r3;
      }
    }
    #pragma unroll
    for (int dd = 8; dd <= 32; dd <<= 1) {
      #pragma unroll
      for (int q = 0; q < 32; ++q) {
        a0[q] += __shfl_down(a0[q], dd, 64);
        a1[q] += __shfl_down(a1[q], dd, 64);
      }
    }
    if (lane < 8) {
      float* pw = &pacc[wv*512 + lane*64];
      #pragma unroll
      for (int q = 0; q < 32; ++q) { pw[q] = a0[q]; pw[32+q] = a1[q]; }
    }
    __syncthreads();
    #pragma unroll
    for (int r = 0; r < 2; ++r) {
      int o = tid + r*256;
      int jl = o >> 5, b = o & 31;
      int off = (jl>>1)*64 + (jl&1)*32 + b;
      float v = pacc[off] + pacc[512+off] + pacc[1024+off] + pacc[1536+off];
      v += xg[(size_t)(b*T + t)*2048 + (jl>>2)*512 + hibase + (jl&3)];
      g_lds[jl*32 + b] = v;
    }
    __syncthreads();
    if (tid < 128) {
      int hil = tid >> 5, b = tid & 31;
      float gi = g_lds[(0*4+hil)*32 + b];
      float gf = g_lds[(1*4+hil)*32 + b];
      float gg = g_lds[(2*4+hil)*32 + b];
      float go = g_lds[(3*4+hil)*32 + b];
      c_reg = sigm(gf)*c_reg + sigm(gi)*tanhf(gg);
      float h = sigm(go)*tanhf(c_reg);
      int hi = hibase + hil;
      st_wt(&hn[hi*32 + b], h);
      st_wt(&outbuf[(size_t)(b*T + t)*H2 + dir*512 + hi], h * (float)mask[b*T + t]);
    }
    pbar(eslots + (dir*64 + tt)*128, eflags + (dir*64 + tt)*256, nd, 128);
  }
}

// ---- decoder macros: wave-private staging (NO __syncthreads in K-loops) ----
#define GROW1(lr) (8*wv + ((lr) < 8 ? (lr) : 24 + (lr)))
#define GROW2(lr) (16*wv + (lr))
#define SLDG(qq, s) { int krr = (s)*64 + GROW1(lrow); \
  const float* bs = (krr < 1024) ? (hTc + krr*32) : (ctxc + (krr-1024)*32); \
  qq##a = *(const float4*)(bs + scol2); qq##b = *(const float4*)(bs + scol2 + 4); }
#define SLDS(qq, s) { int krr = (s)*64 + GROW2(lrow); \
  const float* bs = (krr < 1024) ? (hTn + krr*32) : (ctxc + (krr-1024)*32); \
  qq##a = *(const float4*)(bs + scol2); qq##b = *(const float4*)(bs + scol2 + 4); }
#define STW(qq, BUF) { float* d = Sw + (BUF)*576 + lrow*36 + scol2; \
  *(float4*)d = qq##a; *(float4*)(d+4) = qq##b; }
#define COMPG(sl, BUF) { const float* Sb = Sw + (BUF)*576; \
  _Pragma("unroll") for (int i = 0; i < 2; ++i) { \
    float w0 = Wg[jl0*2052 + (sl)*64 + i*32 + kkg]; \
    float w1 = Wg[jl1*2052 + (sl)*64 + i*32 + kkg]; \
    const float* sp = Sb + (i*8 + kkl)*36; \
    _Pragma("unroll") for (int q = 0; q < 8; ++q) { \
      float4 s4 = *(const float4*)(sp + q*4); \
      a0[q*4+0] += w0*s4.x; a0[q*4+1] += w0*s4.y; a0[q*4+2] += w0*s4.z; a0[q*4+3] += w0*s4.w; \
      a1[q*4+0] += w1*s4.x; a1[q*4+1] += w1*s4.y; a1[q*4+2] += w1*s4.z; a1[q*4+3] += w1*s4.w; } } }
#define COMPS(sl, BUF) { const float* sp = Sw + (BUF)*576 + lrow*36; \
  float w0 = ws0[sl], w1 = ws1[sl]; \
  _Pragma("unroll") for (int q = 0; q < 8; ++q) { \
    float4 s4 = *(const float4*)(sp + q*4); \
    a0[q*4+0] += w0*s4.x; a0[q*4+1] += w0*s4.y; a0[q*4+2] += w0*s4.z; a0[q*4+3] += w0*s4.w; \
    a1[q*4+0] += w1*s4.x; a1[q*4+1] += w1*s4.y; a1[q*4+2] += w1*s4.z; a1[q*4+3] += w1*s4.w; } }

// ---------------- persistent decoder: rotating state buffers, INV-free barriers ----------
// State rotates through step-unique addresses -> no stale-L2 hazard -> no acquire needed,
// read-only buffers (projo/outbuf/basep/tagp/Wout) stay L2-resident across all 64 steps.
// Dynamic LDS (floats): Wg 16x2052=32832 | S2 4x2x576=4608 | pacc 2048 | g_lds 512 = 160000 B
__global__ __launch_bounds__(256, 1) void decoder_persistent(
    const float* __restrict__ basep, const float* __restrict__ tagp,
    const float* __restrict__ dWhh,  const float* __restrict__ dWih,
    const float* __restrict__ Wout,  const float* __restrict__ bout,
    const float* __restrict__ projo, const float* __restrict__ outbuf,
    const int* __restrict__ mask,
    float* __restrict__ hbufs,       // [64][1024][32] rotating h (transposed)
    float* __restrict__ cbufs,       // [65][1024][32] rotating ctx (transposed)
    float* __restrict__ rbufs,       // [64][32][1024] rotating h (row-major)
    const float* __restrict__ zeroh, // [1024][32] zeros (h(-1))
    unsigned long long* __restrict__ argslot,
    unsigned* __restrict__ dslots, unsigned* __restrict__ dflags,
    float* __restrict__ out)
{
  extern __shared__ float dyn[];
  float* Wg    = dyn;           // 32832
  float* S2    = dyn + 32832;   // 4608 (wave-private: wv*1152 + buf*576)
  float* pacc  = dyn + 37440;   // 2048
  float* g_lds = dyn + 39488;   // 512

  const int blk = blockIdx.x, tid = threadIdx.x;
  const int lane = tid & 63, wv = tid >> 6;
  const int hibase = blk * 4;
  const int jj = lane & 7, kkl = lane >> 3;
  const int kkg = 8*wv + kkl;
  const int jl0 = jj*2, jl1 = jj*2 + 1;
  const int vv = tid & 3, kq = tid >> 2;
  const int vbase = blk * 8;
  const int lrow = lane >> 2, scol2 = (lane & 3) * 8;
  // XCD-localized attend mapping (R12-proven)
  const int ab = blk & 31, aslice = blk >> 5;
  float* Sw = S2 + wv*1152;

  // ---- preload gates weights into LDS (once) ----
  for (int jl = 0; jl < 16; ++jl) {
    int j = (jl>>2)*1024 + hibase + (jl&3);
    #pragma unroll
    for (int r = 0; r < 2; ++r) {
      int c = tid*4 + r*1024;
      float4 w;
      if (c < 1024) w = *(const float4*)(dWhh + (size_t)j*1024 + c);
      else          w = *(const float4*)(dWih + (size_t)j*2560 + 512 + (c - 1024));
      *(float4*)&Wg[jl*2052 + c] = w;
    }
  }
  // ---- scores weights in registers (64 floats/thread) ----
  float ws0[32], ws1[32];
  {
    int v0 = vbase + vv*2;
    #pragma unroll
    for (int s2 = 0; s2 < 32; ++s2) {
      ws0[s2] = Wout[(size_t)(v0+0)*2048 + s2*64 + kq];
      ws1[s2] = Wout[(size_t)(v0+1)*2048 + s2*64 + kq];
    }
  }

  float c_reg = 0.f;
  int bslot = 0;

  // ---- prologue: ctx(0) = attend(last_output) -> cbufs[0] ----
  {
    int len = -1;
    for (int i = 0; i < T; ++i) len += mask[ab*T + i];
    attend_slice(ab, aslice, outbuf + (size_t)(ab*T + len)*H2, cbufs,
                 outbuf, projo, mask, pacc, tid);
  }
  pbar_na(dslots + (bslot)*256, dflags + (bslot)*256, blk, 256); bslot++;

  for (int t = 0; t < T; ++t) {
    const float* hTc  = (t == 0) ? zeroh : (hbufs + (size_t)(t-1)*32768);
    float*       hTn  = hbufs + (size_t)t*32768;
    const float* ctxc = cbufs + (size_t)t*32768;
    float*       ctxn = cbufs + (size_t)(t+1)*32768;
    float*       hrw  = rbufs + (size_t)t*32768;

    // prefetch per-thread external gate contributions (base + tag embed proj)
    const int b_own = tid & 31;
    const int jlA = tid >> 5, jlB = jlA + 8;
    const int jA = (jlA>>2)*1024 + hibase + (jlA&3);
    const int jB = (jlB>>2)*1024 + hibase + (jlB&3);
    float extA = basep[(size_t)(b_own*T + t)*G4 + jA];
    float extB = basep[(size_t)(b_own*T + t)*G4 + jB];
    if (t > 0) {
      unsigned long long sl64 = __hip_atomic_load(&argslot[((t+2)%3)*32 + b_own],
                                                  __ATOMIC_RELAXED, __HIP_MEMORY_SCOPE_AGENT);
      unsigned tg = ~(unsigned)sl64;
      extA += tagp[(size_t)tg*G4 + jA];
      extB += tagp[(size_t)tg*G4 + jB];
    }

    // ===== phase 1: gates (K=2048: h | ctx), wave-private staging, no K-loop syncs =====
    float a0[32], a1[32];
    #pragma unroll
    for (int q = 0; q < 32; ++q) { a0[q] = 0.f; a1[q] = 0.f; }
    {
      float4 q0a,q0b,q1a,q1b,q2a,q2b,q3a,q3b;
      SLDG(q0, 0) SLDG(q1, 1) SLDG(q2, 2) SLDG(q3, 3)
      STW(q0, 0)
      for (int g = 0; g < 8; ++g) {
        const int sl = g*4;
        if (sl+4 < 32) SLDG(q0, sl+4)
        COMPG(sl, 0)
        STW(q1, 1)
        if (sl+5 < 32) SLDG(q1, sl+5)
        COMPG(sl+1, 1)
        STW(q2, 0)
        if (sl+6 < 32) SLDG(q2, sl+6)
        COMPG(sl+2, 0)
        STW(q3, 1)
        if (sl+7 < 32) SLDG(q3, sl+7)
        COMPG(sl+3, 1)
        if (sl+4 < 32) STW(q0, 0)
      }
    }
    #pragma unroll
    for (int dd = 8; dd <= 32; dd <<= 1) {
      #pragma unroll
      for (int q = 0; q < 32; ++q) {
        a0[q] += __shfl_down(a0[q], dd, 64);
        a1[q] += __shfl_down(a1[q], dd, 64);
      }
    }
    if (lane < 8) {
      float* pw = &pacc[wv*512 + lane*64];
      #pragma unroll
      for (int q = 0; q < 32; ++q) { pw[q] = a0[q]; pw[32+q] = a1[q]; }
    }
    __syncthreads();
    #pragma unroll
    for (int r = 0; r < 2; ++r) {
      int o = tid + r*256;
      int jl = o >> 5, b = o & 31;
      int off = (jl>>1)*64 + (jl&1)*32 + b;
      float vsum = pacc[off] + pacc[512+off] + pacc[1024+off] + pacc[1536+off];
      vsum += (r == 0) ? extA : extB;
      g_lds[jl*32 + b] = vsum;
    }
    __syncthreads();
    if (tid < 128) {
      int hil = tid >> 5, b = tid & 31;
      float gi = g_lds[(0*4+hil)*32 + b];
      float gf = g_lds[(1*4+hil)*32 + b];
      float gg = g_lds[(2*4+hil)*32 + b];
      float go = g_lds[(3*4+hil)*32 + b];
      c_reg = sigm(gf)*c_reg + sigm(gi)*tanhf(gg);
      float h = sigm(go)*tanhf(c_reg);
      int hi = hibase + hil;
      st_wt(&hTn[hi*32 + b], h);
      st_wt(&hrw[b*1024 + hi], h);
    }
    pbar_na(dslots + (bslot)*256, dflags + (bslot)*256, blk, 256); bslot++;

    // ===== phase 2: scores (K=2048: h_new | ctx_old), wave-private staging =====
    #pragma unroll
    for (int q = 0; q < 32; ++q) { a0[q] = 0.f; a1[q] = 0.f; }
    {
      float4 q0a,q0b,q1a,q1b,q2a,q2b,q3a,q3b;
      SLDS(q0, 0) SLDS(q1, 1) SLDS(q2, 2) SLDS(q3, 3)
      STW(q0, 0)
      #pragma unroll
      for (int g = 0; g < 8; ++g) {
        const int sl = g*4;
        if (sl+4 < 32) SLDS(q0, sl+4)
        COMPS(sl, 0)
        STW(q1, 1)
        if (sl+5 < 32) SLDS(q1, sl+5)
        COMPS(sl+1, 1)
        STW(q2, 0)
        if (sl+6 < 32) SLDS(q2, sl+6)
        COMPS(sl+2, 0)
        STW(q3, 1)
        if (sl+7 < 32) SLDS(q3, sl+7)
        COMPS(sl+3, 1)
        if (sl+4 < 32) STW(q0, 0)
      }
    }
    #pragma unroll
    for (int dd = 4; dd <= 32; dd <<= 1) {
      #pragma unroll
      for (int q = 0; q < 32; ++q) {
        a0[q] += __shfl_down(a0[q], dd, 64);
        a1[q] += __shfl_down(a1[q], dd, 64);
      }
    }
    if (lane < 4) {
      float* pw = &pacc[wv*256 + lane*64];
      #pragma unroll
      for (int q = 0; q < 32; ++q) { pw[q] = a0[q]; pw[32+q] = a1[q]; }
    }
    __syncthreads();
    {
      int vl = tid & 7, b = tid >> 3;
      int off = (vl>>1)*64 + (vl&1)*32 + b;
      float s = pacc[off] + pacc[256+off] + pacc[512+off] + pacc[768+off];
      s += bout[vbase + vl];
      st_wt(&out[(size_t)(b*T + t)*V + vbase + vl], s);
      g_lds[vl*32 + b] = s;
    }
    __syncthreads();
    if (tid < 32) {
      int b = tid;
      float best = g_lds[b]; int bi = 0;
      #pragma unroll
      for (int vl = 1; vl < 8; ++vl) {
        float s = g_lds[vl*32 + b];
        if (s > best) { best = s; bi = vl; }
      }
      unsigned long long e = ((unsigned long long)fenc(best) << 32)
                           | (unsigned long long)(unsigned)(~(unsigned)(vbase + bi));
      atomicMax(&argslot[(t%3)*32 + b], e);
    } else if (blk == 0 && tid >= 32 && tid < 64) {
      __hip_atomic_store(&argslot[((t+1)%3)*32 + (tid - 32)], 0ull,
                         __ATOMIC_RELAXED, __HIP_MEMORY_SCOPE_AGENT);
    }
    if (t < 63) {
      __syncthreads();
      attend_slice(ab, aslice, hrw + ab*1024, ctxn, outbuf, projo, mask, pacc, tid);
    }
    pbar_na(dslots + (bslot)*256, dflags + (bslot)*256, blk, 256); bslot++;
  }
}

// ---------------- host launch ----------------
extern "C" void kernel_launch(void* const* d_in, const int* in_sizes, int n_in,
                              void* d_out, int out_size, void* d_ws, size_t ws_size,
                              hipStream_t stream)
{
  (void)in_sizes; (void)n_in; (void)out_size; (void)ws_size;
  const float* emb    = (const float*)d_in[0];
  const int*   mask   = (const int*)d_in[1];
  const float* Wih_f  = (const float*)d_in[2];
  const float* Whh_f  = (const float*)d_in[3];
  const float* bih_f  = (const float*)d_in[4];
  const float* bhh_f  = (const float*)d_in[5];
  const float* Wih_b  = (const float*)d_in[6];
  const float* Whh_b  = (const float*)d_in[7];
  const float* bih_b  = (const float*)d_in[8];
  const float* bhh_b  = (const float*)d_in[9];
  const float* attnW  = (const float*)d_in[10];
  const float* tagemb = (const float*)d_in[12];
  const float* dWih   = (const float*)d_in[13];
  const float* dWhh   = (const float*)d_in[14];
  const float* dbih   = (const float*)d_in[15];
  const float* dbhh   = (const float*)d_in[16];
  const float* Wout   = (const float*)d_in[17];
  const float* bout   = (const float*)d_in[18];
  float* out = (float*)d_out;

  float* ws = (float*)d_ws;
  // xg region (ws+0 .. ws+8388607): used by GEMMs+encoder, then RECYCLED by the decoder
  // as rotating state buffers (decoder runs strictly after encoder in stream order).
  float* xg_f   = ws + 0;          // 4194304
  float* xg_b   = ws + 4194304;    // 4194304
  float* hbufs  = ws + 0;          // 64*32768 = 2097152   (decoder h rotation)
  float* cbufs  = ws + 2097152;    // 65*32768 = 2129920   (decoder ctx rotation)
  float* rbufs  = ws + 4227072;    // 64*32768 = 2097152   (decoder hrow rotation)
  float* outbuf = ws + 8388608;    // 2097152
  float* projo  = ws + 10485760;   // 2097152
  float* basep  = ws + 12582912;   // 8388608
  float* tagp   = ws + 20971520;   // 8388608
  // --- zeroed state block ---
  float* zeroh  = ws + 29360128;   // 32768 zeros (h(-1))
  float* hencT  = ws + 29523968;   // 65536  [2][2][512][32]
  unsigned long long* argslot = (unsigned long long*)(ws + 29589504);  // 96 u64 (192 fl)
  unsigned* dslots = (unsigned*)(ws + 29589696);   // 129*256 = 33024 u32
  unsigned* dflags = (unsigned*)(ws + 29622720);   // 129*256 = 33024 u32
  unsigned* eslots = (unsigned*)(ws + 29655744);   // 128*128 = 16384 u32
  unsigned* eflags = (unsigned*)(ws + 29672128);   // 128*256 = 32768 u32
  // end: 29704896 floats

  // allow 160000 B dynamic LDS for the decoder
  (void)hipFuncSetAttribute((const void*)decoder_persistent,
                            hipFuncAttributeMaxDynamicSharedMemorySize, 160000);

  // zero all persistent-kernel state every call (graph-replay deterministic)
  hipMemsetAsync((void*)(ws + 29360128), 0, (size_t)(29704896 - 29360128) * sizeof(float), stream);

  // xg = emb @ Wih^T + bih + bhh   (M=2048, N=2048, K=512)
  gemm_nt<<<dim3(16, 16), 256, 0, stream>>>(emb, 512, Wih_f, 512, xg_f, 2048, bih_f, bhh_f, 512);
  gemm_nt<<<dim3(16, 16), 256, 0, stream>>>(emb, 512, Wih_b, 512, xg_b, 2048, bih_b, bhh_b, 512);
  // tagp = tag_embed @ dec_Wih[:, :512]^T   (M=2048, N=4096, K=512)
  gemm_nt<<<dim3(32, 16), 256, 0, stream>>>(tagemb, 512, dWih, DEC_IN, tagp, G4, nullptr, nullptr, 512);
  // encoder scan (persistent, register-resident Whh, wave-private staging)
  encoder_persistent<<<256, 256, 0, stream>>>(xg_f, xg_b, Whh_f, Whh_b, mask, hencT, outbuf, eslots, eflags);
  // projo[bt,d] = sum_e attn_W[d,e]*output[bt,e]   (M=2048, N=1024, K=1024)
  gemm_nt<<<dim3(8, 16), 256, 0, stream>>>(outbuf, H2, attnW, H2, projo, H2, nullptr, nullptr, H2);
  // basep = aligned @ dec_Wih[:,1536:]^T + dbih + dbhh   (M=2048, N=4096, K=1024)
  gemm_nt<<<dim3(32, 16), 256, 0, stream>>>(outbuf, H2, dWih + 1536, DEC_IN, basep, G4, dbih, dbhh, H2);
  // persistent decoder (rotating state, INV-free barriers)
  decoder_persistent<<<256, 256, 160000, stream>>>(basep, tagp, dWhh, dWih, Wout, bout,
                                                   projo, outbuf, mask, hbufs, cbufs, rbufs, zeroh,
                                                   argslot, dslots, dflags, out);
}

// Round 15
// 4415.533 us; speedup vs baseline: 2.9735x; 1.0301x over previous
//
#include <hip/hip_runtime.h>

#define B   32
#define T   64
#define D   512
#define H   512
#define H2  1024
#define G4  4096
#define V   2048
#define DEC_IN 2560

__device__ __forceinline__ float sigm(float x) { return 1.f / (1.f + expf(-x)); }

__device__ __forceinline__ unsigned fenc(float f) {
  unsigned u = __float_as_uint(f);
  return (u & 0x80000000u) ? ~u : (u | 0x80000000u);
}

__device__ __forceinline__ void st_wt(float* p, float v) {       // write-through (L3-visible on retire)
  __hip_atomic_store(p, v, __ATOMIC_RELAXED, __HIP_MEMORY_SCOPE_AGENT);
}

// ---- INV-free store-based grid barrier (R14-proven): all cross-step state uses
// step-unique addresses + write-through stores -> no acquire needed; read-only data
// stays L2-resident across the whole persistent kernel. ----
__device__ __forceinline__ void pbar_na(unsigned* slots, unsigned* flags, int myid, int nblk) {
  __syncthreads();   // drains vmcnt -> write-through stores L3-visible before arrival
  if (threadIdx.x == 0)
    __hip_atomic_store(slots + myid, 1u, __ATOMIC_RELAXED, __HIP_MEMORY_SCOPE_AGENT);
  if (myid == 0) {
    for (int s = threadIdx.x; s < nblk; s += 256) {
      while (!__hip_atomic_load(slots + s, __ATOMIC_RELAXED, __HIP_MEMORY_SCOPE_AGENT))
        __builtin_amdgcn_s_sleep(1);
    }
    __syncthreads();
    if (threadIdx.x < 16)
      __hip_atomic_store(flags + threadIdx.x*16, 1u, __ATOMIC_RELAXED, __HIP_MEMORY_SCOPE_AGENT);
  }
  if (threadIdx.x == 0) {
    unsigned* f = flags + (myid & 15)*16;
    while (!__hip_atomic_load(f, __ATOMIC_RELAXED, __HIP_MEMORY_SCOPE_AGENT))
      __builtin_amdgcn_s_sleep(1);
  }
  __syncthreads();
}

// ---------------- fp32 GEMM: 128x128 tile, 8x8 micro-tile, BK=8, dbuf global loads ------
__global__ __launch_bounds__(256) void gemm_nt(
    const float* __restrict__ A, int lda,
    const float* __restrict__ W, int ldw,
    float* __restrict__ C, int ldc,
    const float* __restrict__ bias0, const float* __restrict__ bias1,
    int K)
{
  __shared__ float As[8][132];
  __shared__ float Bs[8][132];
  const int tid = threadIdx.x;
  const int nb = blockIdx.x * 128;
  const int mb = blockIdx.y * 128;
  const int tx = tid & 15;
  const int ty = tid >> 4;
  float acc[8][8] = {};

  const int am = tid >> 1, ak = (tid & 1) * 4;
  const float* aptr = A + (size_t)(mb + am) * lda + ak;
  const float* bptr = W + (size_t)(nb + am) * ldw + ak;

  float4 av = *(const float4*)(aptr);
  float4 bv = *(const float4*)(bptr);
  for (int k0 = 0; k0 < K; k0 += 8) {
    As[ak+0][am] = av.x; As[ak+1][am] = av.y; As[ak+2][am] = av.z; As[ak+3][am] = av.w;
    Bs[ak+0][am] = bv.x; Bs[ak+1][am] = bv.y; Bs[ak+2][am] = bv.z; Bs[ak+3][am] = bv.w;
    __syncthreads();
    float4 avn = av, bvn = bv;
    if (k0 + 8 < K) {      // issue next tile's loads early; latency hides under FMAs
      avn = *(const float4*)(aptr + k0 + 8);
      bvn = *(const float4*)(bptr + k0 + 8);
    }
    #pragma unroll
    for (int k = 0; k < 8; ++k) {
      float4 a0 = *(const float4*)&As[k][ty*8];
      float4 a1 = *(const float4*)&As[k][ty*8+4];
      float4 b0 = *(const float4*)&Bs[k][tx*8];
      float4 b1 = *(const float4*)&Bs[k][tx*8+4];
      float avv[8] = {a0.x,a0.y,a0.z,a0.w,a1.x,a1.y,a1.z,a1.w};
      float bvv[8] = {b0.x,b0.y,b0.z,b0.w,b1.x,b1.y,b1.z,b1.w};
      #pragma unroll
      for (int i = 0; i < 8; ++i)
        #pragma unroll
        for (int j = 0; j < 8; ++j)
          acc[i][j] += avv[i]*bvv[j];
    }
    __syncthreads();
    av = avn; bv = bvn;
  }
  float b8[8];
  #pragma unroll
  for (int j = 0; j < 8; ++j) {
    float bvv = 0.f;
    if (bias0) bvv += bias0[nb + tx*8 + j];
    if (bias1) bvv += bias1[nb + tx*8 + j];
    b8[j] = bvv;
  }
  #pragma unroll
  for (int i = 0; i < 8; ++i) {
    float4 o0, o1;
    o0.x = acc[i][0]+b8[0]; o0.y = acc[i][1]+b8[1]; o0.z = acc[i][2]+b8[2]; o0.w = acc[i][3]+b8[3];
    o1.x = acc[i][4]+b8[4]; o1.y = acc[i][5]+b8[5]; o1.z = acc[i][6]+b8[6]; o1.w = acc[i][7]+b8[7];
    size_t idx = (size_t)(mb + ty*8 + i) * ldc + nb + tx*8;
    *(float4*)&C[idx]     = o0;
    *(float4*)&C[idx + 4] = o1;
  }
}

// ---------------- distributed attention: block (ab, aslice) -> ctx slice ----------------
__device__ void attend_slice(int ab, int aslice, const float* __restrict__ hvec,
                             float* __restrict__ ctxdst,
                             const float* __restrict__ outbuf, const float* __restrict__ projo,
                             const int* __restrict__ mask, float* scratch, int tid)
{
  float* scp = scratch;        // 256
  float* scv = scratch + 256;  // 64
  float* p2  = scratch + 320;  // 128
  const int tq = tid >> 2, dq = tid & 3;
  const float4* hv = (const float4*)(hvec + dq*256);
  const float4* pv = (const float4*)(projo + (size_t)(ab*T + tq)*H2 + dq*256);
  float p = 0.f;
  #pragma unroll 8
  for (int k4 = 0; k4 < 64; ++k4) {
    float4 a = hv[k4], q = pv[k4];
    p += a.x*q.x + a.y*q.y + a.z*q.z + a.w*q.w;
  }
  scp[tid] = p;
  __syncthreads();
  if (tid < 64) {
    float v = scp[tid*4] + scp[tid*4+1] + scp[tid*4+2] + scp[tid*4+3];
    float mx = v;
    #pragma unroll
    for (int d = 32; d; d >>= 1) mx = fmaxf(mx, __shfl_xor(mx, d, 64));
    float e = expf(v - mx);
    float sm = e;
    #pragma unroll
    for (int d = 32; d; d >>= 1) sm += __shfl_xor(sm, d, 64);
    scv[tid] = e * (1.f / sm) * (float)mask[ab*T + tid];
  }
  __syncthreads();
  {
    const int dl = tid & 127, th = tid >> 7;
    const int dg = aslice*128 + dl;
    float acc = 0.f;
    #pragma unroll 8
    for (int q = 0; q < 32; ++q) {
      int tt = th*32 + q;
      acc += scv[tt] * outbuf[(size_t)(ab*T + tt)*H2 + dg];
    }
    if (th == 1) p2[dl] = acc;
    __syncthreads();
    if (th == 0) st_wt(&ctxdst[dg*32 + ab], acc + p2[dl]);
  }
}

// ---------------- persistent encoder: rotating h buffers, INV-free barriers ----------
__global__ __launch_bounds__(256, 1) void encoder_persistent(
    const float* __restrict__ xg_f, const float* __restrict__ xg_b,
    const float* __restrict__ Whh_f, const float* __restrict__ Whh_b,
    const int* __restrict__ mask,
    float* __restrict__ hebufs,      // [2][64][512][32] rotating h
    const float* __restrict__ zeroh, // zeros (h(-1))
    float* __restrict__ outbuf,
    unsigned* __restrict__ eslots, unsigned* __restrict__ eflags)
{
  __shared__ float S_lds[9216];   // wave-private: wv*2304 + buf*1152, rows stride 36
  __shared__ float pacc[2048];
  __shared__ float g_lds[512];
  const int blk = blockIdx.x, tid = threadIdx.x;
  const int lane = tid & 63, wv = tid >> 6;
  const int dir = blk >> 7, nd = blk & 127;
  const int hibase = nd * 4;
  const int jj = tid & 7, kk = tid >> 3;
  const int kkl = lane >> 3;
  const float* xg  = dir ? xg_b : xg_f;
  const float* Whh = dir ? Whh_b : Whh_f;
  float* hebase = hebufs + (size_t)dir * 1048576;
  float* Sw = S_lds + wv*2304;

  float wge[2][16];
  #pragma unroll
  for (int p = 0; p < 2; ++p) {
    int jl = jj*2 + p;
    int j = (jl>>2)*512 + hibase + (jl&3);
    #pragma unroll
    for (int sc = 0; sc < 4; ++sc)
      #pragma unroll
      for (int i = 0; i < 4; ++i)
        wge[p][sc*4+i] = Whh[(size_t)j*512 + sc*128 + i*32 + kk];
  }
  float c_reg = 0.f;
  const int lr = lane >> 1, halfc = (lane & 1) * 16;
  const int grow = (lr >> 3)*32 + 8*wv + (lr & 7);

  for (int tt = 0; tt < 64; ++tt) {
    const int t = dir ? (63 - tt) : tt;
    const float* hc = tt ? (hebase + (size_t)(tt-1)*16384) : zeroh;
    float* hn = hebase + (size_t)tt*16384;

    float a0[32], a1[32];
    #pragma unroll
    for (int q = 0; q < 32; ++q) { a0[q] = 0.f; a1[q] = 0.f; }

    float4 r0, r1, r2, r3;
    {
      const float4* p = (const float4*)(hc + grow*32 + halfc);
      r0 = p[0]; r1 = p[1]; r2 = p[2]; r3 = p[3];
      float* d = Sw + lr*36 + halfc;
      *(float4*)d = r0; *(float4*)(d+4) = r1; *(float4*)(d+8) = r2; *(float4*)(d+12) = r3;
    }
    #pragma unroll
    for (int sc = 0; sc < 4; ++sc) {
      if (sc < 3) {
        const float4* p = (const float4*)(hc + ((sc+1)*128 + grow)*32 + halfc);
        r0 = p[0]; r1 = p[1]; r2 = p[2]; r3 = p[3];
      }
      const float* Sb = Sw + (sc & 1)*1152;
      #pragma unroll
      for (int i = 0; i < 4; ++i) {
        const float* sp = Sb + (i*8 + kkl)*36;
        float w0 = wge[0][sc*4+i], w1 = wge[1][sc*4+i];
        #pragma unroll
        for (int q = 0; q < 8; ++q) {
          float4 s4 = *(const float4*)(sp + q*4);
          a0[q*4+0] += w0*s4.x; a0[q*4+1] += w0*s4.y; a0[q*4+2] += w0*s4.z; a0[q*4+3] += w0*s4.w;
          a1[q*4+0] += w1*s4.x; a1[q*4+1] += w1*s4.y; a1[q*4+2] += w1*s4.z; a1[q*4+3] += w1*s4.w;
        }
      }
      if (sc < 3) {
        float* d = Sw + ((sc+1) & 1)*1152 + lr*36 + halfc;
        *(float4*)d = r0; *(float4*)(d+4) = r1; *(float4*)(d+8) = r2; *(float4*)(d+12) = r3;
      }
    }
    #pragma unroll
    for (int dd = 8; dd <= 32; dd <<= 1) {
      #pragma unroll
      for (int q = 0; q < 32; ++q) {
        a0[q] += __shfl_down(a0[q], dd, 64);
        a1[q] += __shfl_down(a1[q], dd, 64);
      }
    }
    if (lane < 8) {
      float* pw = &pacc[wv*512 + lane*64];
      #pragma unroll
      for (int q = 0; q < 32; ++q) { pw[q] = a0[q]; pw[32+q] = a1[q]; }
    }
    __syncthreads();
    #pragma unroll
    for (int r = 0; r < 2; ++r) {
      int o = tid + r*256;
      int jl = o >> 5, b = o & 31;
      int off = (jl>>1)*64 + (jl&1)*32 + b;
      float v = pacc[off] + pacc[512+off] + pacc[1024+off] + pacc[1536+off];
      v += xg[(size_t)(b*T + t)*2048 + (jl>>2)*512 + hibase + (jl&3)];
      g_lds[jl*32 + b] = v;
    }
    __syncthreads();
    if (tid < 128) {
      int hil = tid >> 5, b = tid & 31;
      float gi = g_lds[(0*4+hil)*32 + b];
      float gf = g_lds[(1*4+hil)*32 + b];
      float gg = g_lds[(2*4+hil)*32 + b];
      float go = g_lds[(3*4+hil)*32 + b];
      c_reg = sigm(gf)*c_reg + sigm(gi)*tanhf(gg);
      float h = sigm(go)*tanhf(c_reg);
      int hi = hibase + hil;
      st_wt(&hn[hi*32 + b], h);
      st_wt(&outbuf[(size_t)(b*T + t)*H2 + dir*512 + hi], h * (float)mask[b*T + t]);
    }
    pbar_na(eslots + (dir*64 + tt)*128, eflags + (dir*64 + tt)*256, nd, 128);
  }
}

// ---- decoder macros: wave-private staging (NO __syncthreads in K-loops) ----
#define GROW1(lr) (8*wv + ((lr) < 8 ? (lr) : 24 + (lr)))
#define GROW2(lr) (16*wv + (lr))
#define SLDG(qq, s) { int krr = (s)*64 + GROW1(lrow); \
  const float* bs = (krr < 1024) ? (hTc + krr*32) : (ctxc + (krr-1024)*32); \
  qq##a = *(const float4*)(bs + scol2); qq##b = *(const float4*)(bs + scol2 + 4); }
#define SLDS(qq, s) { int krr = (s)*64 + GROW2(lrow); \
  const float* bs = (krr < 1024) ? (hTn + krr*32) : (ctxc + (krr-1024)*32); \
  qq##a = *(const float4*)(bs + scol2); qq##b = *(const float4*)(bs + scol2 + 4); }
#define STW(qq, BUF) { float* d = Sw + (BUF)*576 + lrow*36 + scol2; \
  *(float4*)d = qq##a; *(float4*)(d+4) = qq##b; }
#define COMPG(sl, BUF) { const float* Sb = Sw + (BUF)*576; \
  _Pragma("unroll") for (int i = 0; i < 2; ++i) { \
    float w0 = Wg[jl0*2052 + (sl)*64 + i*32 + kkg]; \
    float w1 = Wg[jl1*2052 + (sl)*64 + i*32 + kkg]; \
    const float* sp = Sb + (i*8 + kkl)*36; \
    _Pragma("unroll") for (int q = 0; q < 8; ++q) { \
      float4 s4 = *(const float4*)(sp + q*4); \
      a0[q*4+0] += w0*s4.x; a0[q*4+1] += w0*s4.y; a0[q*4+2] += w0*s4.z; a0[q*4+3] += w0*s4.w; \
      a1[q*4+0] += w1*s4.x; a1[q*4+1] += w1*s4.y; a1[q*4+2] += w1*s4.z; a1[q*4+3] += w1*s4.w; } } }
#define COMPS(sl, BUF) { const float* sp = Sw + (BUF)*576 + lrow*36; \
  float w0 = ws0[sl], w1 = ws1[sl]; \
  _Pragma("unroll") for (int q = 0; q < 8; ++q) { \
    float4 s4 = *(const float4*)(sp + q*4); \
    a0[q*4+0] += w0*s4.x; a0[q*4+1] += w0*s4.y; a0[q*4+2] += w0*s4.z; a0[q*4+3] += w0*s4.w; \
    a1[q*4+0] += w1*s4.x; a1[q*4+1] += w1*s4.y; a1[q*4+2] += w1*s4.z; a1[q*4+3] += w1*s4.w; } }

// ---------------- persistent decoder (R14, unchanged): rotating state, INV-free ---------
// Dynamic LDS (floats): Wg 16x2052=32832 | S2 4x2x576=4608 | pacc 2048 | g_lds 512 = 160000 B
__global__ __launch_bounds__(256, 1) void decoder_persistent(
    const float* __restrict__ basep, const float* __restrict__ tagp,
    const float* __restrict__ dWhh,  const float* __restrict__ dWih,
    const float* __restrict__ Wout,  const float* __restrict__ bout,
    const float* __restrict__ projo, const float* __restrict__ outbuf,
    const int* __restrict__ mask,
    float* __restrict__ hbufs,       // [64][1024][32] rotating h (transposed)
    float* __restrict__ cbufs,       // [65][1024][32] rotating ctx (transposed)
    float* __restrict__ rbufs,       // [64][32][1024] rotating h (row-major)
    const float* __restrict__ zeroh, // [1024][32] zeros (h(-1))
    unsigned long long* __restrict__ argslot,
    unsigned* __restrict__ dslots, unsigned* __restrict__ dflags,
    float* __restrict__ out)
{
  extern __shared__ float dyn[];
  float* Wg    = dyn;           // 32832
  float* S2    = dyn + 32832;   // 4608 (wave-private: wv*1152 + buf*576)
  float* pacc  = dyn + 37440;   // 2048
  float* g_lds = dyn + 39488;   // 512

  const int blk = blockIdx.x, tid = threadIdx.x;
  const int lane = tid & 63, wv = tid >> 6;
  const int hibase = blk * 4;
  const int jj = lane & 7, kkl = lane >> 3;
  const int kkg = 8*wv + kkl;
  const int jl0 = jj*2, jl1 = jj*2 + 1;
  const int vv = tid & 3, kq = tid >> 2;
  const int vbase = blk * 8;
  const int lrow = lane >> 2, scol2 = (lane & 3) * 8;
  const int ab = blk & 31, aslice = blk >> 5;   // XCD-localized attend mapping
  float* Sw = S2 + wv*1152;

  // ---- preload gates weights into LDS (once) ----
  for (int jl = 0; jl < 16; ++jl) {
    int j = (jl>>2)*1024 + hibase + (jl&3);
    #pragma unroll
    for (int r = 0; r < 2; ++r) {
      int c = tid*4 + r*1024;
      float4 w;
      if (c < 1024) w = *(const float4*)(dWhh + (size_t)j*1024 + c);
      else          w = *(const float4*)(dWih + (size_t)j*2560 + 512 + (c - 1024));
      *(float4*)&Wg[jl*2052 + c] = w;
    }
  }
  // ---- scores weights in registers (64 floats/thread) ----
  float ws0[32], ws1[32];
  {
    int v0 = vbase + vv*2;
    #pragma unroll
    for (int s2 = 0; s2 < 32; ++s2) {
      ws0[s2] = Wout[(size_t)(v0+0)*2048 + s2*64 + kq];
      ws1[s2] = Wout[(size_t)(v0+1)*2048 + s2*64 + kq];
    }
  }

  float c_reg = 0.f;
  int bslot = 0;

  // ---- prologue: ctx(0) = attend(last_output) -> cbufs[0] ----
  {
    int len = -1;
    for (int i = 0; i < T; ++i) len += mask[ab*T + i];
    attend_slice(ab, aslice, outbuf + (size_t)(ab*T + len)*H2, cbufs,
                 outbuf, projo, mask, pacc, tid);
  }
  pbar_na(dslots + (bslot)*256, dflags + (bslot)*256, blk, 256); bslot++;

  for (int t = 0; t < T; ++t) {
    const float* hTc  = (t == 0) ? zeroh : (hbufs + (size_t)(t-1)*32768);
    float*       hTn  = hbufs + (size_t)t*32768;
    const float* ctxc = cbufs + (size_t)t*32768;
    float*       ctxn = cbufs + (size_t)(t+1)*32768;
    float*       hrw  = rbufs + (size_t)t*32768;

    const int b_own = tid & 31;
    const int jlA = tid >> 5, jlB = jlA + 8;
    const int jA = (jlA>>2)*1024 + hibase + (jlA&3);
    const int jB = (jlB>>2)*1024 + hibase + (jlB&3);
    float extA = basep[(size_t)(b_own*T + t)*G4 + jA];
    float extB = basep[(size_t)(b_own*T + t)*G4 + jB];
    if (t > 0) {
      unsigned long long sl64 = __hip_atomic_load(&argslot[((t+2)%3)*32 + b_own],
                                                  __ATOMIC_RELAXED, __HIP_MEMORY_SCOPE_AGENT);
      unsigned tg = ~(unsigned)sl64;
      extA += tagp[(size_t)tg*G4 + jA];
      extB += tagp[(size_t)tg*G4 + jB];
    }

    // ===== phase 1: gates (K=2048: h | ctx), wave-private staging, no K-loop syncs =====
    float a0[32], a1[32];
    #pragma unroll
    for (int q = 0; q < 32; ++q) { a0[q] = 0.f; a1[q] = 0.f; }
    {
      float4 q0a,q0b,q1a,q1b,q2a,q2b,q3a,q3b;
      SLDG(q0, 0) SLDG(q1, 1) SLDG(q2, 2) SLDG(q3, 3)
      STW(q0, 0)
      for (int g = 0; g < 8; ++g) {
        const int sl = g*4;
        if (sl+4 < 32) SLDG(q0, sl+4)
        COMPG(sl, 0)
        STW(q1, 1)
        if (sl+5 < 32) SLDG(q1, sl+5)
        COMPG(sl+1, 1)
        STW(q2, 0)
        if (sl+6 < 32) SLDG(q2, sl+6)
        COMPG(sl+2, 0)
        STW(q3, 1)
        if (sl+7 < 32) SLDG(q3, sl+7)
        COMPG(sl+3, 1)
        if (sl+4 < 32) STW(q0, 0)
      }
    }
    #pragma unroll
    for (int dd = 8; dd <= 32; dd <<= 1) {
      #pragma unroll
      for (int q = 0; q < 32; ++q) {
        a0[q] += __shfl_down(a0[q], dd, 64);
        a1[q] += __shfl_down(a1[q], dd, 64);
      }
    }
    if (lane < 8) {
      float* pw = &pacc[wv*512 + lane*64];
      #pragma unroll
      for (int q = 0; q < 32; ++q) { pw[q] = a0[q]; pw[32+q] = a1[q]; }
    }
    __syncthreads();
    #pragma unroll
    for (int r = 0; r < 2; ++r) {
      int o = tid + r*256;
      int jl = o >> 5, b = o & 31;
      int off = (jl>>1)*64 + (jl&1)*32 + b;
      float vsum = pacc[off] + pacc[512+off] + pacc[1024+off] + pacc[1536+off];
      vsum += (r == 0) ? extA : extB;
      g_lds[jl*32 + b] = vsum;
    }
    __syncthreads();
    if (tid < 128) {
      int hil = tid >> 5, b = tid & 31;
      float gi = g_lds[(0*4+hil)*32 + b];
      float gf = g_lds[(1*4+hil)*32 + b];
      float gg = g_lds[(2*4+hil)*32 + b];
      float go = g_lds[(3*4+hil)*32 + b];
      c_reg = sigm(gf)*c_reg + sigm(gi)*tanhf(gg);
      float h = sigm(go)*tanhf(c_reg);
      int hi = hibase + hil;
      st_wt(&hTn[hi*32 + b], h);
      st_wt(&hrw[b*1024 + hi], h);
    }
    pbar_na(dslots + (bslot)*256, dflags + (bslot)*256, blk, 256); bslot++;

    // ===== phase 2: scores (K=2048: h_new | ctx_old), wave-private staging =====
    #pragma unroll
    for (int q = 0; q < 32; ++q) { a0[q] = 0.f; a1[q] = 0.f; }
    {
      float4 q0a,q0b,q1a,q1b,q2a,q2b,q3a,q3b;
      SLDS(q0, 0) SLDS(q1, 1) SLDS(q2, 2) SLDS(q3, 3)
      STW(q0, 0)
      #pragma unroll
      for (int g = 0; g < 8; ++g) {
        const int sl = g*4;
        if (sl+4 < 32) SLDS(q0, sl+4)
        COMPS(sl, 0)
        STW(q1, 1)
        if (sl+5 < 32) SLDS(q1, sl+5)
        COMPS(sl+1, 1)
        STW(q2, 0)
        if (sl+6 < 32) SLDS(q2, sl+6)
        COMPS(sl+2, 0)
        STW(q3, 1)
        if (sl+7 < 32) SLDS(q3, sl+7)
        COMPS(sl+3, 1)
        if (sl+4 < 32) STW(q0, 0)
      }
    }
    #pragma unroll
    for (int dd = 4; dd <= 32; dd <<= 1) {
      #pragma unroll
      for (int q = 0; q < 32; ++q) {
        a0[q] += __shfl_down(a0[q], dd, 64);
        a1[q] += __shfl_down(a1[q], dd, 64);
      }
    }
    if (lane < 4) {
      float* pw = &pacc[wv*256 + lane*64];
      #pragma unroll
      for (int q = 0; q < 32; ++q) { pw[q] = a0[q]; pw[32+q] = a1[q]; }
    }
    __syncthreads();
    {
      int vl = tid & 7, b = tid >> 3;
      int off = (vl>>1)*64 + (vl&1)*32 + b;
      float s = pacc[off] + pacc[256+off] + pacc[512+off] + pacc[768+off];
      s += bout[vbase + vl];
      st_wt(&out[(size_t)(b*T + t)*V + vbase + vl], s);
      g_lds[vl*32 + b] = s;
    }
    __syncthreads();
    if (tid < 32) {
      int b = tid;
      float best = g_lds[b]; int bi = 0;
      #pragma unroll
      for (int vl = 1; vl < 8; ++vl) {
        float s = g_lds[vl*32 + b];
        if (s > best) { best = s; bi = vl; }
      }
      unsigned long long e = ((unsigned long long)fenc(best) << 32)
                           | (unsigned long long)(unsigned)(~(unsigned)(vbase + bi));
      atomicMax(&argslot[(t%3)*32 + b], e);
    } else if (blk == 0 && tid >= 32 && tid < 64) {
      __hip_atomic_store(&argslot[((t+1)%3)*32 + (tid - 32)], 0ull,
                         __ATOMIC_RELAXED, __HIP_MEMORY_SCOPE_AGENT);
    }
    if (t < 63) {
      __syncthreads();
      attend_slice(ab, aslice, hrw + ab*1024, ctxn, outbuf, projo, mask, pacc, tid);
    }
    pbar_na(dslots + (bslot)*256, dflags + (bslot)*256, blk, 256); bslot++;
  }
}

// ---------------- host launch ----------------
extern "C" void kernel_launch(void* const* d_in, const int* in_sizes, int n_in,
                              void* d_out, int out_size, void* d_ws, size_t ws_size,
                              hipStream_t stream)
{
  (void)in_sizes; (void)n_in; (void)out_size; (void)ws_size;
  const float* emb    = (const float*)d_in[0];
  const int*   mask   = (const int*)d_in[1];
  const float* Wih_f  = (const float*)d_in[2];
  const float* Whh_f  = (const float*)d_in[3];
  const float* bih_f  = (const float*)d_in[4];
  const float* bhh_f  = (const float*)d_in[5];
  const float* Wih_b  = (const float*)d_in[6];
  const float* Whh_b  = (const float*)d_in[7];
  const float* bih_b  = (const float*)d_in[8];
  const float* bhh_b  = (const float*)d_in[9];
  const float* attnW  = (const float*)d_in[10];
  const float* tagemb = (const float*)d_in[12];
  const float* dWih   = (const float*)d_in[13];
  const float* dWhh   = (const float*)d_in[14];
  const float* dbih   = (const float*)d_in[15];
  const float* dbhh   = (const float*)d_in[16];
  const float* Wout   = (const float*)d_in[17];
  const float* bout   = (const float*)d_in[18];
  float* out = (float*)d_out;

  float* ws = (float*)d_ws;
  // Region reuse across the pipeline (stream order guarantees no overlap in time):
  //  - xg region (ws+0..8388607): GEMMs 1-2 write, encoder reads; then decoder recycles
  //    it as rotating state (hbufs/cbufs/rbufs).
  //  - basep region (ws+12582912..): encoder recycles it as rotating h (hebufs); then
  //    the basep GEMM overwrites it before the decoder reads basep.
  float* xg_f   = ws + 0;          // 4194304
  float* xg_b   = ws + 4194304;    // 4194304
  float* hbufs  = ws + 0;          // 64*32768 = 2097152   (decoder h rotation)
  float* cbufs  = ws + 2097152;    // 65*32768 = 2129920   (decoder ctx rotation)
  float* rbufs  = ws + 4227072;    // 64*32768 = 2097152   (decoder hrow rotation)
  float* outbuf = ws + 8388608;    // 2097152
  float* projo  = ws + 10485760;   // 2097152
  float* basep  = ws + 12582912;   // 8388608
  float* hebufs = ws + 12582912;   // 2*64*16384 = 2097152 (encoder h rotation, pre-basep)
  float* tagp   = ws + 20971520;   // 8388608
  // --- zeroed state block ---
  float* zeroh  = ws + 29360128;   // 32768 zeros (h(-1) for both kernels)
  unsigned long long* argslot = (unsigned long long*)(ws + 29589504);  // 96 u64 (192 fl)
  unsigned* dslots = (unsigned*)(ws + 29589696);   // 129*256 = 33024 u32
  unsigned* dflags = (unsigned*)(ws + 29622720);   // 129*256 = 33024 u32
  unsigned* eslots = (unsigned*)(ws + 29655744);   // 128*128 = 16384 u32
  unsigned* eflags = (unsigned*)(ws + 29672128);   // 128*256 = 32768 u32
  // end: 29704896 floats

  // allow 160000 B dynamic LDS for the decoder
  (void)hipFuncSetAttribute((const void*)decoder_persistent,
                            hipFuncAttributeMaxDynamicSharedMemorySize, 160000);

  // zero all persistent-kernel state every call (graph-replay deterministic)
  hipMemsetAsync((void*)(ws + 29360128), 0, (size_t)(29704896 - 29360128) * sizeof(float), stream);

  // xg = emb @ Wih^T + bih + bhh   (M=2048, N=2048, K=512)
  gemm_nt<<<dim3(16, 16), 256, 0, stream>>>(emb, 512, Wih_f, 512, xg_f, 2048, bih_f, bhh_f, 512);
  gemm_nt<<<dim3(16, 16), 256, 0, stream>>>(emb, 512, Wih_b, 512, xg_b, 2048, bih_b, bhh_b, 512);
  // tagp = tag_embed @ dec_Wih[:, :512]^T   (M=2048, N=4096, K=512)
  gemm_nt<<<dim3(32, 16), 256, 0, stream>>>(tagemb, 512, dWih, DEC_IN, tagp, G4, nullptr, nullptr, 512);
  // encoder scan (rotating h, INV-free barriers)
  encoder_persistent<<<256, 256, 0, stream>>>(xg_f, xg_b, Whh_f, Whh_b, mask,
                                              hebufs, zeroh, outbuf, eslots, eflags);
  // projo[bt,d] = sum_e attn_W[d,e]*output[bt,e]   (M=2048, N=1024, K=1024)
  gemm_nt<<<dim3(8, 16), 256, 0, stream>>>(outbuf, H2, attnW, H2, projo, H2, nullptr, nullptr, H2);
  // basep = aligned @ dec_Wih[:,1536:]^T + dbih + dbhh   (M=2048, N=4096, K=1024)
  // (overwrites the encoder's hebufs scratch — encoder already complete)
  gemm_nt<<<dim3(32, 16), 256, 0, stream>>>(outbuf, H2, dWih + 1536, DEC_IN, basep, G4, dbih, dbhh, H2);
  // persistent decoder (R14, unchanged)
  decoder_persistent<<<256, 256, 160000, stream>>>(basep, tagp, dWhh, dWih, Wout, bout,
                                                   projo, outbuf, mask, hbufs, cbufs, rbufs, zeroh,
                                                   argslot, dslots, dflags, out);
}